// Round 5
// baseline (839.235 us; speedup 1.0000x reference)
//
#include <hip/hip_runtime.h>
#include <math.h>

#define V_   8
#define H_   256
#define W_   256
#define L_   32
#define HID_ 64
#define NC_  64
#define NF_  64
#define R_   1024
#define IND_ 41              // 3 + 32 + 3 + 3
#define HW_  (H_*W_)

// ---------------------------------------------------------------- P = K @ E
__global__ void k_computeP(const float* __restrict__ Km,
                           const float* __restrict__ Em,
                           float* __restrict__ Pm) {
    int t = threadIdx.x;
    if (t >= V_ * 12) return;
    int v = t / 12, e = t - v * 12, row = e >> 2, col = e & 3;
    float acc = 0.f;
    #pragma unroll
    for (int k = 0; k < 3; ++k)
        acc += Km[v * 9 + row * 3 + k] * Em[v * 12 + k * 4 + col];
    Pm[v * 12 + row * 4 + col] = acc;
}

// ------------------------------------------- transpose weights, contiguous rows
// layout: [cW1T 64x48 @0][cW2T 64x64 @3072][fW1T @7168][fW2T @10240]  (14336 fl)
__global__ void k_packW(const float* __restrict__ W1c, const float* __restrict__ W2c,
                        const float* __restrict__ W1f, const float* __restrict__ W2f,
                        float* __restrict__ out) {
    int t = threadIdx.x + blockIdx.x * blockDim.x;
    if (t < 64 * 48) {                      // zero-pad W1T rows (48 per row)
        int j = t / 48, k = t - j * 48;
        float a = (k < IND_) ? W1c[k * 64 + j] : 0.f;
        float b = (k < IND_) ? W1f[k * 64 + j] : 0.f;
        out[j * 48 + k]        = a;
        out[7168 + j * 48 + k] = b;
    }
    if (t < 64 * 64) {
        int j = t >> 6, k = t & 63;
        out[3072  + j * 64 + k] = W2c[k * 64 + j];
        out[10240 + j * 64 + k] = W2f[k * 64 + j];
    }
}

// ---------------- pack ALL 64 feature channels to pixel-major [V][HW][64]
__global__ __launch_bounds__(256) void k_packF64(const float* __restrict__ fea,
                                                 float* __restrict__ pk) {
    __shared__ float tile[64][65];
    const int xb = blockIdx.x * 64, y = blockIdx.y, v = blockIdx.z;
    const int t = threadIdx.x;
    #pragma unroll
    for (int step = 0; step < 16; ++step) {
        int c = step * 4 + (t >> 6);
        int x = t & 63;
        tile[c][x] = fea[((size_t)(v * 2 * L_ + c)) * HW_ + y * W_ + xb + x];
    }
    __syncthreads();
    #pragma unroll
    for (int step = 0; step < 16; ++step) {
        int x = step * 4 + (t >> 6);
        int c = t & 63;
        pk[((size_t)v * HW_ + y * W_ + xb + x) * 64 + c] = tile[c][x];
    }
}

// -------------------------- pack 32 feature channels to pixel-major [V][HW][32]
__global__ __launch_bounds__(256) void k_packF32(const float* __restrict__ fea,
                                                 float* __restrict__ pk, int FS) {
    __shared__ float tile[32][65];
    const int xb = blockIdx.x * 64, y = blockIdx.y, v = blockIdx.z;
    const int t = threadIdx.x;
    #pragma unroll
    for (int step = 0; step < 8; ++step) {
        int c = step * 4 + (t >> 6);
        int x = t & 63;
        tile[c][x] = fea[((size_t)(v * 2 * L_ + FS + c)) * HW_ + y * W_ + xb + x];
    }
    __syncthreads();
    #pragma unroll
    for (int step = 0; step < 8; ++step) {
        int x = step * 8 + (t >> 5);
        int c = t & 31;
        pk[((size_t)v * HW_ + y * W_ + xb + x) * 32 + c] = tile[c][x];
    }
}

// ------------------------------------------------------------- MLP kernel
// lane = (point, view): 8 points x 8 views per wave. Weights wave-uniform
// (scalar operands). Layer1 fully unrolled; layer2 runtime j-loop, 8 rows/iter.
// PKS: pk row stride (64 = all channels packed, 32 = per-pass pack, 0 = unpacked)
// PKOFF: channel offset within the packed row.
template <int S, int FS, bool FINE, int PKS, int PKOFF>
__global__ __launch_bounds__(256) void k_mlp(
    const float* __restrict__ ray, const float* __restrict__ Pm,
    const float* __restrict__ cam, const float* __restrict__ shp,
    const float* __restrict__ msk, const float* __restrict__ img,
    const float* __restrict__ fea, const float* __restrict__ pk,
    const float* __restrict__ WT1, const float* __restrict__ WT2,
    const float* __restrict__ W1, const float* __restrict__ b1,
    const float* __restrict__ W2, const float* __restrict__ b2,
    const float* __restrict__ Wd, const float* __restrict__ bd,
    const float* __restrict__ Wb, const float* __restrict__ bb,
    const float* __restrict__ deptharr,
    float* __restrict__ odens, float* __restrict__ orgb) {

    const int tid = blockIdx.x * 256 + threadIdx.x;
    const int v   = tid & 7;            // view for this lane
    const int P   = tid >> 3;           // point-sample id
    const int r   = P / S, s = P - r * S;

    const float ox = ray[r*8+0], oy = ray[r*8+1], oz = ray[r*8+2];
    const float dx = ray[r*8+3], dy = ray[r*8+4], dz = ray[r*8+5];
    const float nv = ray[r*8+6], fv = ray[r*8+7];

    float depth;
    if (FINE) depth = deptharr[P];
    else      depth = nv + (fv - nv) * ((s + 0.5f) / (float)S);

    const float px = ox + dx*depth, py = oy + dy*depth, pz = oz + dz*depth;
    const float dn = sqrtf(dx*dx + dy*dy + dz*dz);
    const float rdx = -dx/dn, rdy = -dy/dn, rdz = -dz/dn;

    // ---- projection for this lane's view ----
    const float* Pv = Pm + v * 12;
    float q0 = Pv[0]*px + Pv[1]*py + Pv[2]*pz  + Pv[3];
    float q1 = Pv[4]*px + Pv[5]*py + Pv[6]*pz  + Pv[7];
    float q2 = Pv[8]*px + Pv[9]*py + Pv[10]*pz + Pv[11];
    float inv = 1.0f / (q2 + 1e-6f);
    float u = q0 * inv, w = q1 * inv;
    float gx = 2.0f * (u / shp[v*2+1]) - 1.0f;
    float gy = 2.0f * (w / shp[v*2+0]) - 1.0f;
    float sx = (gx + 1.0f) * ((float)W_ * 0.5f) - 0.5f;
    float sy = (gy + 1.0f) * ((float)H_ * 0.5f) - 0.5f;
    float x0f = floorf(sx), y0f = floorf(sy);
    float fx = sx - x0f, fy = sy - y0f;

    int offp[4]; float wt[4];
    {
        float xs[2] = {x0f, x0f + 1.f}, ys[2] = {y0f, y0f + 1.f};
        float wxs[2] = {1.f - fx, fx},  wys[2] = {1.f - fy, fy};
        #pragma unroll
        for (int t = 0; t < 4; ++t) {
            float xf = xs[t & 1], yf = ys[t >> 1];
            bool val = (xf >= 0.f) && (xf <= (float)(W_-1)) &&
                       (yf >= 0.f) && (yf <= (float)(H_-1));
            int xi = (int)fminf(fmaxf(xf, 0.f), (float)(W_-1));
            int yi = (int)fminf(fmaxf(yf, 0.f), (float)(H_-1));
            offp[t] = yi * W_ + xi;
            wt[t] = wxs[t & 1] * wys[t >> 1] * (val ? 1.f : 0.f);
        }
    }

    // mask sample
    const float* mb = msk + v * HW_;
    float msample = wt[0]*mb[offp[0]] + wt[1]*mb[offp[1]]
                  + wt[2]*mb[offp[2]] + wt[3]*mb[offp[3]];
    // rgb sample
    float rv0 = 0.f, rv1 = 0.f, rv2 = 0.f;
    {
        const float* ib = img + (v * 3) * HW_;
        #pragma unroll
        for (int t = 0; t < 4; ++t) {
            rv0 += wt[t] * ib[offp[t]];
            rv1 += wt[t] * ib[HW_ + offp[t]];
            rv2 += wt[t] * ib[2 * HW_ + offp[t]];
        }
    }
    // source dir
    float sdx = cam[v*3+0]-px, sdy = cam[v*3+1]-py, sdz = cam[v*3+2]-pz;
    float snv = sqrtf(sdx*sdx + sdy*sdy + sdz*sdz);
    sdx /= snv; sdy /= snv; sdz /= snv;

    // ---- build x[41] (lane-local, statically indexed) ----
    float x[IND_];
    x[0] = rv0; x[1] = rv1; x[2] = rv2;
    #pragma unroll
    for (int i = 3; i < 35; ++i) x[i] = 0.f;
    if (PKS > 0) {
        #pragma unroll
        for (int t = 0; t < 4; ++t) {
            const float4* fp = (const float4*)(pk + ((size_t)v * HW_ + offp[t]) * PKS + PKOFF);
            float wtt = wt[t];
            #pragma unroll
            for (int k4 = 0; k4 < 8; ++k4) {
                float4 f = fp[k4];
                x[3+k4*4+0] += wtt * f.x;
                x[3+k4*4+1] += wtt * f.y;
                x[3+k4*4+2] += wtt * f.z;
                x[3+k4*4+3] += wtt * f.w;
            }
        }
    } else {
        #pragma unroll
        for (int k = 0; k < 32; ++k) {
            const float* fb = fea + (size_t)(v * (2*L_) + FS + k) * HW_;
            x[3+k] = wt[0]*fb[offp[0]] + wt[1]*fb[offp[1]]
                   + wt[2]*fb[offp[2]] + wt[3]*fb[offp[3]];
        }
    }
    x[35] = sdx; x[36] = sdy; x[37] = sdz;
    x[38] = rdx; x[39] = rdy; x[40] = rdz;

    // ---- layer 1 (fully unrolled; static x/h1 indices) ----
    float h1[HID_];
    #pragma unroll
    for (int j = 0; j < HID_; ++j) {
        float a0 = 0.f, a1 = 0.f, a2 = 0.f, a3 = 0.f;
        if (PKS > 0) {
            const float* wr = WT1 + j * 48;
            #pragma unroll
            for (int k = 0; k < 40; k += 4) {
                a0 += x[k+0] * wr[k+0];
                a1 += x[k+1] * wr[k+1];
                a2 += x[k+2] * wr[k+2];
                a3 += x[k+3] * wr[k+3];
            }
            a0 += x[40] * wr[40];
        } else {
            #pragma unroll
            for (int k = 0; k < IND_; ++k) a0 += x[k] * W1[k * HID_ + j];
        }
        h1[j] = fmaxf(b1[j] + ((a0 + a1) + (a2 + a3)), 0.f);
    }

    // ---- layer 2 + pooling: runtime j-loop, 8 rows/iter ----
    float lg = bb[0];
    float A = 0.f, B = 0.f, C = 0.f;
    #pragma unroll 1
    for (int j = 0; j < HID_; j += 8) {
        float hh[8];
        #pragma unroll
        for (int jj = 0; jj < 8; ++jj) {
            float a0 = 0.f, a1 = 0.f, a2 = 0.f, a3 = 0.f;
            if (PKS > 0) {
                const float* wr = WT2 + (j + jj) * 64;
                #pragma unroll
                for (int k = 0; k < HID_; k += 4) {
                    a0 += h1[k+0] * wr[k+0];
                    a1 += h1[k+1] * wr[k+1];
                    a2 += h1[k+2] * wr[k+2];
                    a3 += h1[k+3] * wr[k+3];
                }
            } else {
                #pragma unroll
                for (int k = 0; k < HID_; ++k) a0 += h1[k] * W2[k * HID_ + (j + jj)];
            }
            hh[jj] = fmaxf(b2[j + jj] + ((a0 + a1) + (a2 + a3)), 0.f);
        }
        #pragma unroll
        for (int jj = 0; jj < 8; ++jj) {
            float h = hh[jj];
            lg += h * Wb[j + jj];
            A  += h * Wd[j + jj];
            float hw = h * Wd[HID_ + j + jj];
            B  += h * hw;
            float sj = h;
            sj += __shfl_xor(sj, 1); sj += __shfl_xor(sj, 2); sj += __shfl_xor(sj, 4);
            C  += sj * sj * Wd[HID_ + j + jj];
        }
    }
    // reduce A, B over the 8 view-lanes
    A += __shfl_xor(A, 1); A += __shfl_xor(A, 2); A += __shfl_xor(A, 4);
    B += __shfl_xor(B, 1); B += __shfl_xor(B, 2); B += __shfl_xor(B, 4);
    // density = sum_j Wd_j*mean_j + Wd'_j*(mean(h^2)_j - mean_j^2) + bd
    float density = A * 0.125f + B * 0.125f - C * (1.0f / 64.0f) + bd[0];

    // hull: sum of mask samples over views
    float hs = msample;
    hs += __shfl_xor(hs, 1); hs += __shfl_xor(hs, 2); hs += __shfl_xor(hs, 4);
    bool hull = hs > ((float)V_ - 0.001f);

    // softmax blend over views
    float mx = lg;
    mx = fmaxf(mx, __shfl_xor(mx, 1));
    mx = fmaxf(mx, __shfl_xor(mx, 2));
    mx = fmaxf(mx, __shfl_xor(mx, 4));
    float e = expf(lg - mx);
    float es = e;
    es += __shfl_xor(es, 1); es += __shfl_xor(es, 2); es += __shfl_xor(es, 4);
    float br = e * rv0, bg = e * rv1, bbl = e * rv2;
    br  += __shfl_xor(br, 1);  br  += __shfl_xor(br, 2);  br  += __shfl_xor(br, 4);
    bg  += __shfl_xor(bg, 1);  bg  += __shfl_xor(bg, 2);  bg  += __shfl_xor(bg, 4);
    bbl += __shfl_xor(bbl, 1); bbl += __shfl_xor(bbl, 2); bbl += __shfl_xor(bbl, 4);

    if (v == 0) {
        float is = 1.0f / es;
        odens[P]      = hull ? density  : 0.f;
        orgb[P*3 + 0] = hull ? br  * is : 0.f;
        orgb[P*3 + 1] = hull ? bg  * is : 0.f;
        orgb[P*3 + 2] = hull ? bbl * is : 0.f;
    }
}

// ---------------------------------------- coarse composite + sample_pdf + merge
__global__ void k_comp_coarse(const float* __restrict__ ray,
                              const float* __restrict__ dens,
                              const float* __restrict__ rgb,
                              float* __restrict__ out,
                              float* __restrict__ fulld) {
    int r = blockIdx.x * blockDim.x + threadIdx.x;
    if (r >= R_) return;
    const float nv = ray[r*8+6], fv = ray[r*8+7];

    float wv[NC_];
    float T = 1.f, c0 = 0.f, c1 = 0.f, c2 = 0.f, cd = 0.f, ca = 0.f;
    for (int s = 0; s < NC_; ++s) {
        float d0 = nv + (fv - nv) * ((s + 0.5f) / NC_);
        float d1 = nv + (fv - nv) * ((s + 1.5f) / NC_);
        float delta = (s == NC_-1) ? 1e10f : (d1 - d0);
        float a = 1.f - expf(-fmaxf(dens[r*NC_+s], 0.f) * delta);
        float wi = a * T;
        wv[s] = wi;
        c0 += wi * rgb[(r*NC_+s)*3+0];
        c1 += wi * rgb[(r*NC_+s)*3+1];
        c2 += wi * rgb[(r*NC_+s)*3+2];
        cd += wi * d0; ca += wi;
        T *= (1.f - a + 1e-10f);
    }
    out[r*3+0] = c0; out[r*3+1] = c1; out[r*3+2] = c2;
    out[3072 + r] = cd;
    out[4096 + r] = ca;

    // ---- sample_pdf(mids, w[1:-1], NF) ----
    float tot = 0.f;
    for (int i = 0; i < 62; ++i) tot += wv[i+1] + 1e-5f;
    float cdf[63];
    cdf[0] = 0.f;
    float run = 0.f;
    for (int i = 0; i < 62; ++i) { run += (wv[i+1] + 1e-5f) / tot; cdf[i+1] = run; }

    float fd[NF_];
    int idx = 1;
    for (int i = 0; i < NF_; ++i) {
        float u = (i + 0.5f) / NF_;
        while (idx < 63 && cdf[idx] <= u) ++idx;
        int below = idx - 1;
        int above = (idx > 62) ? 62 : idx;
        float cA = cdf[below], cB = cdf[above];
        float b0 = nv + (fv - nv) * ((below + 1.0f) / NC_);
        float b1 = nv + (fv - nv) * ((above + 1.0f) / NC_);
        float dnm = cB - cA;
        dnm = (dnm < 1e-5f) ? 1.f : dnm;
        float t = (u - cA) / dnm;
        fd[i] = b0 + t * (b1 - b0);
    }
    float* fl = fulld + r * (NC_ + NF_);
    int a_ = 0, b_ = 0;
    for (int i = 0; i < NC_ + NF_; ++i) {
        float da = (a_ < NC_) ? nv + (fv - nv) * ((a_ + 0.5f) / NC_) : 3.0e38f;
        float db = (b_ < NF_) ? fd[b_] : 3.0e38f;
        if (da <= db) { fl[i] = da; ++a_; } else { fl[i] = db; ++b_; }
    }
}

// ---------------------------------------------------------- fine composite
__global__ void k_comp_fine(const float* __restrict__ fulld,
                            const float* __restrict__ dens,
                            const float* __restrict__ rgb,
                            float* __restrict__ out) {
    int r = blockIdx.x * blockDim.x + threadIdx.x;
    if (r >= R_) return;
    const int S = NC_ + NF_;
    const float* fl = fulld + r * S;
    float T = 1.f, c0 = 0.f, c1 = 0.f, c2 = 0.f, cd = 0.f, ca = 0.f;
    for (int s = 0; s < S; ++s) {
        float d0 = fl[s];
        float delta = (s == S-1) ? 1e10f : (fl[s+1] - d0);
        float a = 1.f - expf(-fmaxf(dens[r*S+s], 0.f) * delta);
        float wi = a * T;
        c0 += wi * rgb[(r*S+s)*3+0];
        c1 += wi * rgb[(r*S+s)*3+1];
        c2 += wi * rgb[(r*S+s)*3+2];
        cd += wi * d0; ca += wi;
        T *= (1.f - a + 1e-10f);
    }
    out[5120 + r*3+0] = c0; out[5120 + r*3+1] = c1; out[5120 + r*3+2] = c2;
    out[8192 + r] = cd;
    out[9216 + r] = ca;
}

// ------------------------------------------------------------------ launch
extern "C" void kernel_launch(void* const* d_in, const int* in_sizes, int n_in,
                              void* d_out, int out_size, void* d_ws, size_t ws_size,
                              hipStream_t stream) {
    const float* ray = (const float*)d_in[0];
    const float* Kin = (const float*)d_in[1];
    const float* Ein = (const float*)d_in[2];
    const float* cam = (const float*)d_in[3];
    const float* shp = (const float*)d_in[4];
    const float* msk = (const float*)d_in[5];
    const float* img = (const float*)d_in[6];
    const float* fea = (const float*)d_in[7];
    const float* cw[8]; for (int i = 0; i < 8; ++i) cw[i] = (const float*)d_in[8+i];
    const float* fw[8]; for (int i = 0; i < 8; ++i) fw[i] = (const float*)d_in[16+i];

    float* ws    = (float*)d_ws;
    float* Pm    = ws;                       // 96
    float* WT    = Pm + 96;                  // 14336
    float* cdens = WT + 14336;               // 65536
    float* crgb  = cdens + R_ * NC_;         // 196608
    float* fulld = crgb + R_ * NC_ * 3;      // 131072
    float* fdens = fulld + R_ * (NC_+NF_);   // 131072
    float* frgb  = fdens + R_ * (NC_+NF_);   // 393216
    float* pk    = frgb + R_ * (NC_+NF_) * 3;// pack buffer

    size_t base_floats = (size_t)(pk - ws);
    size_t need64 = (base_floats + (size_t)V_ * HW_ * 64 + 64) * sizeof(float);
    size_t need32 = (base_floats + (size_t)V_ * HW_ * 32 + 64) * sizeof(float);
    int mode = (ws_size >= need64) ? 2 : (ws_size >= need32) ? 1 : 0;

    float* outp  = (float*)d_out;

    k_computeP<<<1, 96, 0, stream>>>(Kin, Ein, Pm);

    if (mode == 2) {
        k_packW<<<16, 256, 0, stream>>>(cw[0], cw[2], fw[0], fw[2], WT);
        k_packF64<<<dim3(W_/64, H_, V_), 256, 0, stream>>>(fea, pk);

        k_mlp<NC_, 0, false, 64, 0><<<R_ * NC_ * 8 / 256, 256, 0, stream>>>(
            ray, Pm, cam, shp, msk, img, fea, pk, WT, WT + 3072,
            cw[0], cw[1], cw[2], cw[3], cw[4], cw[5], cw[6], cw[7],
            nullptr, cdens, crgb);

        k_comp_coarse<<<R_ / 256, 256, 0, stream>>>(ray, cdens, crgb, outp, fulld);

        k_mlp<NC_ + NF_, L_, true, 64, L_><<<R_ * (NC_+NF_) * 8 / 256, 256, 0, stream>>>(
            ray, Pm, cam, shp, msk, img, fea, pk, WT + 7168, WT + 10240,
            fw[0], fw[1], fw[2], fw[3], fw[4], fw[5], fw[6], fw[7],
            fulld, fdens, frgb);

        k_comp_fine<<<R_ / 256, 256, 0, stream>>>(fulld, fdens, frgb, outp);
    } else if (mode == 1) {
        k_packW<<<16, 256, 0, stream>>>(cw[0], cw[2], fw[0], fw[2], WT);
        k_packF32<<<dim3(W_/64, H_, V_), 256, 0, stream>>>(fea, pk, 0);

        k_mlp<NC_, 0, false, 32, 0><<<R_ * NC_ * 8 / 256, 256, 0, stream>>>(
            ray, Pm, cam, shp, msk, img, fea, pk, WT, WT + 3072,
            cw[0], cw[1], cw[2], cw[3], cw[4], cw[5], cw[6], cw[7],
            nullptr, cdens, crgb);

        k_comp_coarse<<<R_ / 256, 256, 0, stream>>>(ray, cdens, crgb, outp, fulld);

        k_packF32<<<dim3(W_/64, H_, V_), 256, 0, stream>>>(fea, pk, L_);

        k_mlp<NC_ + NF_, L_, true, 32, 0><<<R_ * (NC_+NF_) * 8 / 256, 256, 0, stream>>>(
            ray, Pm, cam, shp, msk, img, fea, pk, WT + 7168, WT + 10240,
            fw[0], fw[1], fw[2], fw[3], fw[4], fw[5], fw[6], fw[7],
            fulld, fdens, frgb);

        k_comp_fine<<<R_ / 256, 256, 0, stream>>>(fulld, fdens, frgb, outp);
    } else {
        k_mlp<NC_, 0, false, 0, 0><<<R_ * NC_ * 8 / 256, 256, 0, stream>>>(
            ray, Pm, cam, shp, msk, img, fea, nullptr, nullptr, nullptr,
            cw[0], cw[1], cw[2], cw[3], cw[4], cw[5], cw[6], cw[7],
            nullptr, cdens, crgb);

        k_comp_coarse<<<R_ / 256, 256, 0, stream>>>(ray, cdens, crgb, outp, fulld);

        k_mlp<NC_ + NF_, L_, true, 0, 0><<<R_ * (NC_+NF_) * 8 / 256, 256, 0, stream>>>(
            ray, Pm, cam, shp, msk, img, fea, nullptr, nullptr, nullptr,
            fw[0], fw[1], fw[2], fw[3], fw[4], fw[5], fw[6], fw[7],
            fulld, fdens, frgb);

        k_comp_fine<<<R_ / 256, 256, 0, stream>>>(fulld, fdens, frgb, outp);
    }
}

// Round 6
// 568.905 us; speedup vs baseline: 1.4752x; 1.4752x over previous
//
#include <hip/hip_runtime.h>
#include <math.h>

#define V_   8
#define H_   256
#define W_   256
#define L_   32
#define HID_ 64
#define NC_  64
#define NF_  64
#define R_   1024
#define IND_ 41              // 3 + 32 + 3 + 3
#define HW_  (H_*W_)

typedef float v2f __attribute__((ext_vector_type(2)));

// ---- cross-lane helpers: xor1/xor2 via DPP quad_perm (VALU), xor4 via shfl ----
template<int CTRL>
__device__ __forceinline__ float dpp_add(float x) {
    int m = __builtin_amdgcn_mov_dpp(__builtin_bit_cast(int, x), CTRL, 0xF, 0xF, true);
    return x + __builtin_bit_cast(float, m);
}
template<int CTRL>
__device__ __forceinline__ float dpp_max(float x) {
    int m = __builtin_amdgcn_mov_dpp(__builtin_bit_cast(int, x), CTRL, 0xF, 0xF, true);
    return fmaxf(x, __builtin_bit_cast(float, m));
}
// full sum / max over the 8-lane view group (lanes share tid>>3)
__device__ __forceinline__ float vsum8(float x) {
    x = dpp_add<0xB1>(x);           // xor 1 : quad_perm [1,0,3,2]
    x = dpp_add<0x4E>(x);           // xor 2 : quad_perm [2,3,0,1]
    x += __shfl_xor(x, 4, 64);      // xor 4
    return x;
}
__device__ __forceinline__ float vmax8(float x) {
    x = dpp_max<0xB1>(x);
    x = dpp_max<0x4E>(x);
    x = fmaxf(x, __shfl_xor(x, 4, 64));
    return x;
}

// ---------------------------------------------------------------- P = K @ E
__global__ void k_computeP(const float* __restrict__ Km,
                           const float* __restrict__ Em,
                           float* __restrict__ Pm) {
    int t = threadIdx.x;
    if (t >= V_ * 12) return;
    int v = t / 12, e = t - v * 12, row = e >> 2, col = e & 3;
    float acc = 0.f;
    #pragma unroll
    for (int k = 0; k < 3; ++k)
        acc += Km[v * 9 + row * 3 + k] * Em[v * 12 + k * 4 + col];
    Pm[v * 12 + row * 4 + col] = acc;
}

// ------------------------------------------- transpose weights, contiguous rows
// layout: [cW1T 64x48 @0][cW2T 64x64 @3072][fW1T @7168][fW2T @10240]  (14336 fl)
__global__ void k_packW(const float* __restrict__ W1c, const float* __restrict__ W2c,
                        const float* __restrict__ W1f, const float* __restrict__ W2f,
                        float* __restrict__ out) {
    int t = threadIdx.x + blockIdx.x * blockDim.x;
    if (t < 64 * 48) {                      // zero-pad W1T rows (48 per row)
        int j = t / 48, k = t - j * 48;
        float a = (k < IND_) ? W1c[k * 64 + j] : 0.f;
        float b = (k < IND_) ? W1f[k * 64 + j] : 0.f;
        out[j * 48 + k]        = a;
        out[7168 + j * 48 + k] = b;
    }
    if (t < 64 * 64) {
        int j = t >> 6, k = t & 63;
        out[3072  + j * 64 + k] = W2c[k * 64 + j];
        out[10240 + j * 64 + k] = W2f[k * 64 + j];
    }
}

// -------------------------- pack 32 feature channels to pixel-major [V][HW][32]
__global__ __launch_bounds__(256) void k_packF32(const float* __restrict__ fea,
                                                 float* __restrict__ pk, int FS) {
    __shared__ float tile[32][65];
    const int xb = blockIdx.x * 64, y = blockIdx.y, v = blockIdx.z;
    const int t = threadIdx.x;
    #pragma unroll
    for (int step = 0; step < 8; ++step) {
        int c = step * 4 + (t >> 6);
        int x = t & 63;
        tile[c][x] = fea[((size_t)(v * 2 * L_ + FS + c)) * HW_ + y * W_ + xb + x];
    }
    __syncthreads();
    #pragma unroll
    for (int step = 0; step < 8; ++step) {
        int x = step * 8 + (t >> 5);
        int c = t & 31;
        pk[((size_t)v * HW_ + y * W_ + xb + x) * 32 + c] = tile[c][x];
    }
}

// ------------------------------------------------------------- MLP kernel
// lane = (point, view): view = tid&7, point = tid>>3. Weights wave-uniform
// (scalar loads). Matvecs in packed fp32 (float2 -> v_pk_fma_f32).
// Layer1 fully unrolled; layer2 runtime j-loop, 4 rows/iter (I$-friendly).
template <int S, int FS, bool FINE, bool PACKED>
__global__ __launch_bounds__(256, 2) void k_mlp(
    const float* __restrict__ ray, const float* __restrict__ Pm,
    const float* __restrict__ cam, const float* __restrict__ shp,
    const float* __restrict__ msk, const float* __restrict__ img,
    const float* __restrict__ fea, const float* __restrict__ pk,
    const float* __restrict__ WT1, const float* __restrict__ WT2,
    const float* __restrict__ W1, const float* __restrict__ b1,
    const float* __restrict__ W2, const float* __restrict__ b2,
    const float* __restrict__ Wd, const float* __restrict__ bd,
    const float* __restrict__ Wb, const float* __restrict__ bb,
    const float* __restrict__ deptharr,
    float* __restrict__ odens, float* __restrict__ orgb) {

    const int tid = blockIdx.x * 256 + threadIdx.x;
    const int v   = tid & 7;            // view for this lane
    const int P   = tid >> 3;           // point-sample id
    const int r   = P / S, s = P - r * S;

    const float ox = ray[r*8+0], oy = ray[r*8+1], oz = ray[r*8+2];
    const float dx = ray[r*8+3], dy = ray[r*8+4], dz = ray[r*8+5];
    const float nv = ray[r*8+6], fv = ray[r*8+7];

    float depth;
    if (FINE) depth = deptharr[P];
    else      depth = nv + (fv - nv) * ((s + 0.5f) / (float)S);

    const float px = ox + dx*depth, py = oy + dy*depth, pz = oz + dz*depth;
    const float dn = sqrtf(dx*dx + dy*dy + dz*dz);
    const float rdx = -dx/dn, rdy = -dy/dn, rdz = -dz/dn;

    // ---- projection for this lane's view ----
    const float* Pv = Pm + v * 12;
    float q0 = Pv[0]*px + Pv[1]*py + Pv[2]*pz  + Pv[3];
    float q1 = Pv[4]*px + Pv[5]*py + Pv[6]*pz  + Pv[7];
    float q2 = Pv[8]*px + Pv[9]*py + Pv[10]*pz + Pv[11];
    float inv = 1.0f / (q2 + 1e-6f);
    float u = q0 * inv, w = q1 * inv;
    float gx = 2.0f * (u / shp[v*2+1]) - 1.0f;
    float gy = 2.0f * (w / shp[v*2+0]) - 1.0f;
    float sx = (gx + 1.0f) * ((float)W_ * 0.5f) - 0.5f;
    float sy = (gy + 1.0f) * ((float)H_ * 0.5f) - 0.5f;
    float x0f = floorf(sx), y0f = floorf(sy);
    float fx = sx - x0f, fy = sy - y0f;

    int offp[4]; float wt[4];
    {
        float xs[2] = {x0f, x0f + 1.f}, ys[2] = {y0f, y0f + 1.f};
        float wxs[2] = {1.f - fx, fx},  wys[2] = {1.f - fy, fy};
        #pragma unroll
        for (int t = 0; t < 4; ++t) {
            float xf = xs[t & 1], yf = ys[t >> 1];
            bool val = (xf >= 0.f) && (xf <= (float)(W_-1)) &&
                       (yf >= 0.f) && (yf <= (float)(H_-1));
            int xi = (int)fminf(fmaxf(xf, 0.f), (float)(W_-1));
            int yi = (int)fminf(fmaxf(yf, 0.f), (float)(H_-1));
            offp[t] = yi * W_ + xi;
            wt[t] = wxs[t & 1] * wys[t >> 1] * (val ? 1.f : 0.f);
        }
    }

    // mask sample
    const float* mb = msk + v * HW_;
    float msample = wt[0]*mb[offp[0]] + wt[1]*mb[offp[1]]
                  + wt[2]*mb[offp[2]] + wt[3]*mb[offp[3]];
    // rgb sample
    float rv0 = 0.f, rv1 = 0.f, rv2 = 0.f;
    {
        const float* ib = img + (v * 3) * HW_;
        #pragma unroll
        for (int t = 0; t < 4; ++t) {
            rv0 += wt[t] * ib[offp[t]];
            rv1 += wt[t] * ib[HW_ + offp[t]];
            rv2 += wt[t] * ib[2 * HW_ + offp[t]];
        }
    }
    // source dir
    float sdx = cam[v*3+0]-px, sdy = cam[v*3+1]-py, sdz = cam[v*3+2]-pz;
    float snv = sqrtf(sdx*sdx + sdy*sdy + sdz*sdz);
    sdx /= snv; sdy /= snv; sdz /= snv;

    // ---- build x[42] (lane-local, statically indexed; [41] = pad 0) ----
    float xx[42];
    xx[0] = rv0; xx[1] = rv1; xx[2] = rv2;
    #pragma unroll
    for (int i = 3; i < 35; ++i) xx[i] = 0.f;
    if (PACKED) {
        #pragma unroll
        for (int t = 0; t < 4; ++t) {
            const float4* fp = (const float4*)(pk + ((size_t)v * HW_ + offp[t]) * 32);
            float wtt = wt[t];
            #pragma unroll
            for (int k4 = 0; k4 < 8; ++k4) {
                float4 f = fp[k4];
                xx[3+k4*4+0] += wtt * f.x;
                xx[3+k4*4+1] += wtt * f.y;
                xx[3+k4*4+2] += wtt * f.z;
                xx[3+k4*4+3] += wtt * f.w;
            }
        }
    } else {
        #pragma unroll
        for (int k = 0; k < 32; ++k) {
            const float* fb = fea + (size_t)(v * (2*L_) + FS + k) * HW_;
            xx[3+k] = wt[0]*fb[offp[0]] + wt[1]*fb[offp[1]]
                    + wt[2]*fb[offp[2]] + wt[3]*fb[offp[3]];
        }
    }
    xx[35] = sdx; xx[36] = sdy; xx[37] = sdz;
    xx[38] = rdx; xx[39] = rdy; xx[40] = rdz;
    xx[41] = 0.f;

    v2f x2[21];
    #pragma unroll
    for (int i = 0; i < 21; ++i) x2[i] = (v2f){xx[2*i], xx[2*i+1]};

    // ---- layer 1 (fully unrolled; packed fp32; h stored as v2f pairs) ----
    v2f h2[32];
    #pragma unroll
    for (int j = 0; j < HID_; j += 2) {
        float hp[2];
        #pragma unroll
        for (int jj = 0; jj < 2; ++jj) {
            float a;
            if (PACKED) {
                const v2f* wr = (const v2f*)(WT1 + (j + jj) * 48);
                v2f a01 = {0.f, 0.f}, a23 = {0.f, 0.f};
                #pragma unroll
                for (int k = 0; k < 20; k += 2) {
                    a01 += x2[k]   * wr[k];
                    a23 += x2[k+1] * wr[k+1];
                }
                a01 += x2[20] * wr[20];       // covers x[40] + pad
                v2f as = a01 + a23;
                a = as.x + as.y;
            } else {
                a = 0.f;
                #pragma unroll
                for (int k = 0; k < IND_; ++k) a += xx[k] * W1[k * HID_ + (j + jj)];
            }
            hp[jj] = fmaxf(b1[j + jj] + a, 0.f);
        }
        h2[j >> 1] = (v2f){hp[0], hp[1]};
    }

    // ---- layer 2 + pooling: runtime j-loop, 4 rows/iter, packed fp32 ----
    float lg = bb[0];
    float A = 0.f, B = 0.f, C = 0.f;
    #pragma unroll 1
    for (int j = 0; j < HID_; j += 4) {
        float hh0, hh1, hh2, hh3;
        #pragma unroll
        for (int jj = 0; jj < 4; ++jj) {
            float a;
            if (PACKED) {
                const v2f* wr = (const v2f*)(WT2 + (j + jj) * 64);
                v2f a01 = {0.f, 0.f}, a23 = {0.f, 0.f};
                #pragma unroll
                for (int k = 0; k < 32; k += 2) {
                    a01 += h2[k]   * wr[k];
                    a23 += h2[k+1] * wr[k+1];
                }
                v2f as = a01 + a23;
                a = as.x + as.y;
            } else {
                a = 0.f;
                #pragma unroll
                for (int k = 0; k < 32; ++k) {
                    a += h2[k].x * W2[(2*k)   * HID_ + (j + jj)];
                    a += h2[k].y * W2[(2*k+1) * HID_ + (j + jj)];
                }
            }
            float hcur = fmaxf(b2[j + jj] + a, 0.f);
            if (jj == 0) hh0 = hcur; else if (jj == 1) hh1 = hcur;
            else if (jj == 2) hh2 = hcur; else hh3 = hcur;
        }
        #pragma unroll
        for (int jj = 0; jj < 4; ++jj) {
            float h = (jj == 0) ? hh0 : (jj == 1) ? hh1 : (jj == 2) ? hh2 : hh3;
            lg += h * Wb[j + jj];
            A  += h * Wd[j + jj];
            B  += h * h * Wd[HID_ + j + jj];
            float sj = vsum8(h);
            C  += sj * sj * Wd[HID_ + j + jj];
        }
    }
    // reduce A, B over the 8 view-lanes
    A = vsum8(A);
    B = vsum8(B);
    // density = sum_j Wd_j*mean_j + Wd'_j*(mean(h^2)_j - mean_j^2) + bd
    float density = A * 0.125f + B * 0.125f - C * (1.0f / 64.0f) + bd[0];

    // hull: sum of mask samples over views
    float hs = vsum8(msample);
    bool hull = hs > ((float)V_ - 0.001f);

    // softmax blend over views
    float mx = vmax8(lg);
    float e = expf(lg - mx);
    float es = vsum8(e);
    float br  = vsum8(e * rv0);
    float bg  = vsum8(e * rv1);
    float bbl = vsum8(e * rv2);

    if (v == 0) {
        float is = 1.0f / es;
        odens[P]      = hull ? density  : 0.f;
        orgb[P*3 + 0] = hull ? br  * is : 0.f;
        orgb[P*3 + 1] = hull ? bg  * is : 0.f;
        orgb[P*3 + 2] = hull ? bbl * is : 0.f;
    }
}

// ---------------------------------------- coarse composite + sample_pdf + merge
__global__ void k_comp_coarse(const float* __restrict__ ray,
                              const float* __restrict__ dens,
                              const float* __restrict__ rgb,
                              float* __restrict__ out,
                              float* __restrict__ fulld) {
    int r = blockIdx.x * blockDim.x + threadIdx.x;
    if (r >= R_) return;
    const float nv = ray[r*8+6], fv = ray[r*8+7];

    float wv[NC_];
    float T = 1.f, c0 = 0.f, c1 = 0.f, c2 = 0.f, cd = 0.f, ca = 0.f;
    for (int s = 0; s < NC_; ++s) {
        float d0 = nv + (fv - nv) * ((s + 0.5f) / NC_);
        float d1 = nv + (fv - nv) * ((s + 1.5f) / NC_);
        float delta = (s == NC_-1) ? 1e10f : (d1 - d0);
        float a = 1.f - expf(-fmaxf(dens[r*NC_+s], 0.f) * delta);
        float wi = a * T;
        wv[s] = wi;
        c0 += wi * rgb[(r*NC_+s)*3+0];
        c1 += wi * rgb[(r*NC_+s)*3+1];
        c2 += wi * rgb[(r*NC_+s)*3+2];
        cd += wi * d0; ca += wi;
        T *= (1.f - a + 1e-10f);
    }
    out[r*3+0] = c0; out[r*3+1] = c1; out[r*3+2] = c2;
    out[3072 + r] = cd;
    out[4096 + r] = ca;

    // ---- sample_pdf(mids, w[1:-1], NF) ----
    float tot = 0.f;
    for (int i = 0; i < 62; ++i) tot += wv[i+1] + 1e-5f;
    float cdf[63];
    cdf[0] = 0.f;
    float run = 0.f;
    for (int i = 0; i < 62; ++i) { run += (wv[i+1] + 1e-5f) / tot; cdf[i+1] = run; }

    float fd[NF_];
    int idx = 1;
    for (int i = 0; i < NF_; ++i) {
        float u = (i + 0.5f) / NF_;
        while (idx < 63 && cdf[idx] <= u) ++idx;
        int below = idx - 1;
        int above = (idx > 62) ? 62 : idx;
        float cA = cdf[below], cB = cdf[above];
        float b0 = nv + (fv - nv) * ((below + 1.0f) / NC_);
        float b1 = nv + (fv - nv) * ((above + 1.0f) / NC_);
        float dnm = cB - cA;
        dnm = (dnm < 1e-5f) ? 1.f : dnm;
        float t = (u - cA) / dnm;
        fd[i] = b0 + t * (b1 - b0);
    }
    float* fl = fulld + r * (NC_ + NF_);
    int a_ = 0, b_ = 0;
    for (int i = 0; i < NC_ + NF_; ++i) {
        float da = (a_ < NC_) ? nv + (fv - nv) * ((a_ + 0.5f) / NC_) : 3.0e38f;
        float db = (b_ < NF_) ? fd[b_] : 3.0e38f;
        if (da <= db) { fl[i] = da; ++a_; } else { fl[i] = db; ++b_; }
    }
}

// ---------------------------------------------------------- fine composite
__global__ void k_comp_fine(const float* __restrict__ fulld,
                            const float* __restrict__ dens,
                            const float* __restrict__ rgb,
                            float* __restrict__ out) {
    int r = blockIdx.x * blockDim.x + threadIdx.x;
    if (r >= R_) return;
    const int S = NC_ + NF_;
    const float* fl = fulld + r * S;
    float T = 1.f, c0 = 0.f, c1 = 0.f, c2 = 0.f, cd = 0.f, ca = 0.f;
    for (int s = 0; s < S; ++s) {
        float d0 = fl[s];
        float delta = (s == S-1) ? 1e10f : (fl[s+1] - d0);
        float a = 1.f - expf(-fmaxf(dens[r*S+s], 0.f) * delta);
        float wi = a * T;
        c0 += wi * rgb[(r*S+s)*3+0];
        c1 += wi * rgb[(r*S+s)*3+1];
        c2 += wi * rgb[(r*S+s)*3+2];
        cd += wi * d0; ca += wi;
        T *= (1.f - a + 1e-10f);
    }
    out[5120 + r*3+0] = c0; out[5120 + r*3+1] = c1; out[5120 + r*3+2] = c2;
    out[8192 + r] = cd;
    out[9216 + r] = ca;
}

// ------------------------------------------------------------------ launch
extern "C" void kernel_launch(void* const* d_in, const int* in_sizes, int n_in,
                              void* d_out, int out_size, void* d_ws, size_t ws_size,
                              hipStream_t stream) {
    const float* ray = (const float*)d_in[0];
    const float* Kin = (const float*)d_in[1];
    const float* Ein = (const float*)d_in[2];
    const float* cam = (const float*)d_in[3];
    const float* shp = (const float*)d_in[4];
    const float* msk = (const float*)d_in[5];
    const float* img = (const float*)d_in[6];
    const float* fea = (const float*)d_in[7];
    const float* cw[8]; for (int i = 0; i < 8; ++i) cw[i] = (const float*)d_in[8+i];
    const float* fw[8]; for (int i = 0; i < 8; ++i) fw[i] = (const float*)d_in[16+i];

    float* ws    = (float*)d_ws;
    float* Pm    = ws;                       // 96
    float* WT    = Pm + 96;                  // 14336
    float* cdens = WT + 14336;               // 65536
    float* crgb  = cdens + R_ * NC_;         // 196608
    float* fulld = crgb + R_ * NC_ * 3;      // 131072
    float* fdens = fulld + R_ * (NC_+NF_);   // 131072
    float* frgb  = fdens + R_ * (NC_+NF_);   // 393216
    float* pk    = frgb + R_ * (NC_+NF_) * 3;// V*HW*32 pack buffer

    size_t base_floats = (size_t)(pk - ws);
    size_t need32 = (base_floats + (size_t)V_ * HW_ * 32 + 64) * sizeof(float);
    bool packed = (ws_size >= need32);

    float* outp  = (float*)d_out;

    k_computeP<<<1, 96, 0, stream>>>(Kin, Ein, Pm);

    if (packed) {
        k_packW<<<16, 256, 0, stream>>>(cw[0], cw[2], fw[0], fw[2], WT);
        k_packF32<<<dim3(W_/64, H_, V_), 256, 0, stream>>>(fea, pk, 0);

        k_mlp<NC_, 0, false, true><<<R_ * NC_ * 8 / 256, 256, 0, stream>>>(
            ray, Pm, cam, shp, msk, img, fea, pk, WT, WT + 3072,
            cw[0], cw[1], cw[2], cw[3], cw[4], cw[5], cw[6], cw[7],
            nullptr, cdens, crgb);

        k_comp_coarse<<<R_ / 256, 256, 0, stream>>>(ray, cdens, crgb, outp, fulld);

        k_packF32<<<dim3(W_/64, H_, V_), 256, 0, stream>>>(fea, pk, L_);

        k_mlp<NC_ + NF_, L_, true, true><<<R_ * (NC_+NF_) * 8 / 256, 256, 0, stream>>>(
            ray, Pm, cam, shp, msk, img, fea, pk, WT + 7168, WT + 10240,
            fw[0], fw[1], fw[2], fw[3], fw[4], fw[5], fw[6], fw[7],
            fulld, fdens, frgb);

        k_comp_fine<<<R_ / 256, 256, 0, stream>>>(fulld, fdens, frgb, outp);
    } else {
        k_mlp<NC_, 0, false, false><<<R_ * NC_ * 8 / 256, 256, 0, stream>>>(
            ray, Pm, cam, shp, msk, img, fea, nullptr, nullptr, nullptr,
            cw[0], cw[1], cw[2], cw[3], cw[4], cw[5], cw[6], cw[7],
            nullptr, cdens, crgb);

        k_comp_coarse<<<R_ / 256, 256, 0, stream>>>(ray, cdens, crgb, outp, fulld);

        k_mlp<NC_ + NF_, L_, true, false><<<R_ * (NC_+NF_) * 8 / 256, 256, 0, stream>>>(
            ray, Pm, cam, shp, msk, img, fea, nullptr, nullptr, nullptr,
            fw[0], fw[1], fw[2], fw[3], fw[4], fw[5], fw[6], fw[7],
            fulld, fdens, frgb);

        k_comp_fine<<<R_ / 256, 256, 0, stream>>>(fulld, fdens, frgb, outp);
    }
}

// Round 7
// 402.843 us; speedup vs baseline: 2.0833x; 1.4122x over previous
//
#include <hip/hip_runtime.h>
#include <math.h>

#define V_   8
#define H_   256
#define W_   256
#define L_   32
#define HID_ 64
#define NC_  64
#define NF_  64
#define R_   1024
#define IND_ 41              // 3 + 32 + 3 + 3
#define HW_  (H_*W_)

typedef float v2f __attribute__((ext_vector_type(2)));
typedef __attribute__((ext_vector_type(8)))  short short8v;
typedef __attribute__((ext_vector_type(16))) float f32x16;

// ---------------- bf16 helpers (RNE) ----------------
__device__ __forceinline__ unsigned int pk2bf(float a, float b) {
    unsigned int ua = __float_as_uint(a);
    unsigned int ub = __float_as_uint(b);
    unsigned int ra = (ua + 0x7FFFu + ((ua >> 16) & 1u)) >> 16;
    unsigned int rb = (ub + 0x7FFFu + ((ub >> 16) & 1u)) & 0xFFFF0000u;
    return ra | rb;
}

// ---- cross-lane helpers: xor1/xor2 via DPP quad_perm (VALU), xor4 via shfl ----
template<int CTRL>
__device__ __forceinline__ float dpp_add(float x) {
    int m = __builtin_amdgcn_mov_dpp(__builtin_bit_cast(int, x), CTRL, 0xF, 0xF, true);
    return x + __builtin_bit_cast(float, m);
}
template<int CTRL>
__device__ __forceinline__ float dpp_max(float x) {
    int m = __builtin_amdgcn_mov_dpp(__builtin_bit_cast(int, x), CTRL, 0xF, 0xF, true);
    return fmaxf(x, __builtin_bit_cast(float, m));
}
__device__ __forceinline__ float vsum8(float x) {
    x = dpp_add<0xB1>(x);           // xor 1
    x = dpp_add<0x4E>(x);           // xor 2
    x += __shfl_xor(x, 4, 64);      // xor 4
    return x;
}
__device__ __forceinline__ float vmax8(float x) {
    x = dpp_max<0xB1>(x);
    x = dpp_max<0x4E>(x);
    x = fmaxf(x, __shfl_xor(x, 4, 64));
    return x;
}

// ---------------------------------------------------------------- P = K @ E
__global__ void k_computeP(const float* __restrict__ Km,
                           const float* __restrict__ Em,
                           float* __restrict__ Pm) {
    int t = threadIdx.x;
    if (t >= V_ * 12) return;
    int v = t / 12, e = t - v * 12, row = e >> 2, col = e & 3;
    float acc = 0.f;
    #pragma unroll
    for (int k = 0; k < 3; ++k)
        acc += Km[v * 9 + row * 3 + k] * Em[v * 12 + k * 4 + col];
    Pm[v * 12 + row * 4 + col] = acc;
}

// ---------------- pack weights into MFMA fragment order (bf16) ----------------
// out (4096 dwords per MLP):
//  [0,1536)    W1T A-frags: blk=mt1*3+kt (tile M=j1, K=xdim 48, bias at k=41)
//  [1536,3584) W2T A-frags: blk=mt2*4+kt2
//  [3584,3840) pooled weights (float): [w:b2,Wb,Wd,Wd2][mt][hi][16] in C-row order
__global__ void k_packMFMA(const float* __restrict__ W1, const float* __restrict__ b1,
                           const float* __restrict__ W2, const float* __restrict__ b2,
                           const float* __restrict__ Wd, const float* __restrict__ Wb,
                           unsigned int* __restrict__ out) {
    int t = blockIdx.x * 256 + threadIdx.x;   // 0..3839
    if (t < 1536) {
        int blk = t >> 8, idx = t & 255;
        int mt = blk / 3, kt = blk % 3;
        int l = idx >> 2, rg = idx & 3;
        int hi = l >> 5;
        int j  = 32 * mt + (l & 31);
        int k0 = 16 * kt + 8 * hi + 2 * rg;
        int k1 = k0 + 1;
        float v0 = (k0 < 41) ? W1[k0 * 64 + j] : (k0 == 41 ? b1[j] : 0.f);
        float v1 = (k1 < 41) ? W1[k1 * 64 + j] : (k1 == 41 ? b1[j] : 0.f);
        out[t] = pk2bf(v0, v1);
    } else if (t < 3584) {
        int u = t - 1536;
        int blk = u >> 8, idx = u & 255;
        int l = idx >> 2, rg = idx & 3;
        int hi = l >> 5;
        int j2 = 32 * (blk >> 2) + (l & 31);
        int k0 = 16 * (blk & 3) + 8 * hi + 2 * rg;
        out[t] = pk2bf(W2[k0 * 64 + j2], W2[(k0 + 1) * 64 + j2]);
    } else if (t < 3840) {
        int i = t - 3584;
        int w = i >> 6, mt = (i >> 5) & 1, hi = (i >> 4) & 1, rg = i & 15;
        int j2 = (rg & 3) + 8 * (rg >> 2) + 4 * hi + 32 * mt;
        float v = (w == 0) ? b2[j2] : (w == 1) ? Wb[j2] : (w == 2) ? Wd[j2] : Wd[64 + j2];
        ((float*)out)[t] = v;
    }
}

// -------------------------- pack 32 feature channels to pixel-major [V][HW][32]
__global__ __launch_bounds__(256) void k_packF32(const float* __restrict__ fea,
                                                 float* __restrict__ pk, int FS) {
    __shared__ float tile[32][65];
    const int xb = blockIdx.x * 64, y = blockIdx.y, v = blockIdx.z;
    const int t = threadIdx.x;
    #pragma unroll
    for (int step = 0; step < 8; ++step) {
        int c = step * 4 + (t >> 6);
        int x = t & 63;
        tile[c][x] = fea[((size_t)(v * 2 * L_ + FS + c)) * HW_ + y * W_ + xb + x];
    }
    __syncthreads();
    #pragma unroll
    for (int step = 0; step < 8; ++step) {
        int x = step * 8 + (t >> 5);
        int c = t & 31;
        pk[((size_t)v * HW_ + y * W_ + xb + x) * 32 + c] = tile[c][x];
    }
}

// ------------------------------------------------------------- MFMA MLP kernel
// Wave = 8 points x 8 views = 64 ray-rows. Both layers computed transposed
// (H^T = W^T @ X^T): weights = preloaded A-frags, activations = B-frags via LDS.
// Final C: lane holds 32 h-values of ONE ray-row -> per-lane pooling.
template <int S, bool FINE>
__global__ __launch_bounds__(256) void k_mlp_mfma(
    const float* __restrict__ ray, const float* __restrict__ Pm,
    const float* __restrict__ cam, const float* __restrict__ shp,
    const float* __restrict__ msk, const float* __restrict__ img,
    const float* __restrict__ pk,
    const unsigned int* __restrict__ FR,
    const float* __restrict__ bd, const float* __restrict__ bb,
    const float* __restrict__ deptharr,
    float* __restrict__ odens, float* __restrict__ orgb) {

    __shared__ __align__(16) char smem[49152];
    const int lane = threadIdx.x & 63;
    const int wv   = threadIdx.x >> 6;
    const int hi   = lane >> 5;
    const int l31  = lane & 31;
    char* Xw  = smem + wv * 12288;     // X: 64 rows x 128B (48 bf16 + pad)
    char* H1w = Xw + 8192;             // H1: 32 rows x 128B (64 bf16)

    const int pbase = (blockIdx.x * 4 + wv) * 8;
    const int P0 = pbase + (lane >> 3);
    const int v  = lane & 7;
    const int r  = P0 / S, s = P0 - r * S;

    const float ox = ray[r*8+0], oy = ray[r*8+1], oz = ray[r*8+2];
    const float dx = ray[r*8+3], dy = ray[r*8+4], dz = ray[r*8+5];
    const float nv = ray[r*8+6], fv = ray[r*8+7];

    float depth;
    if (FINE) depth = deptharr[P0];
    else      depth = nv + (fv - nv) * ((s + 0.5f) / (float)S);

    const float px = ox + dx*depth, py = oy + dy*depth, pz = oz + dz*depth;
    const float dn = sqrtf(dx*dx + dy*dy + dz*dz);
    const float rdx = -dx/dn, rdy = -dy/dn, rdz = -dz/dn;

    // ---- projection for this lane's view ----
    const float* Pv = Pm + v * 12;
    float q0 = Pv[0]*px + Pv[1]*py + Pv[2]*pz  + Pv[3];
    float q1 = Pv[4]*px + Pv[5]*py + Pv[6]*pz  + Pv[7];
    float q2 = Pv[8]*px + Pv[9]*py + Pv[10]*pz + Pv[11];
    float inv = 1.0f / (q2 + 1e-6f);
    float uu = q0 * inv, ww = q1 * inv;
    float gx = 2.0f * (uu / shp[v*2+1]) - 1.0f;
    float gy = 2.0f * (ww / shp[v*2+0]) - 1.0f;
    float sx = (gx + 1.0f) * ((float)W_ * 0.5f) - 0.5f;
    float sy = (gy + 1.0f) * ((float)H_ * 0.5f) - 0.5f;
    float x0f = floorf(sx), y0f = floorf(sy);
    float fx = sx - x0f, fy = sy - y0f;

    int offp[4]; float wt[4];
    {
        float xs[2] = {x0f, x0f + 1.f}, ys[2] = {y0f, y0f + 1.f};
        float wxs[2] = {1.f - fx, fx},  wys[2] = {1.f - fy, fy};
        #pragma unroll
        for (int t = 0; t < 4; ++t) {
            float xf = xs[t & 1], yf = ys[t >> 1];
            bool val = (xf >= 0.f) && (xf <= (float)(W_-1)) &&
                       (yf >= 0.f) && (yf <= (float)(H_-1));
            int xi = (int)fminf(fmaxf(xf, 0.f), (float)(W_-1));
            int yi = (int)fminf(fmaxf(yf, 0.f), (float)(H_-1));
            offp[t] = yi * W_ + xi;
            wt[t] = wxs[t & 1] * wys[t >> 1] * (val ? 1.f : 0.f);
        }
    }

    const float* mb = msk + v * HW_;
    float msample = wt[0]*mb[offp[0]] + wt[1]*mb[offp[1]]
                  + wt[2]*mb[offp[2]] + wt[3]*mb[offp[3]];
    float rv0 = 0.f, rv1 = 0.f, rv2 = 0.f;
    {
        const float* ib = img + (v * 3) * HW_;
        #pragma unroll
        for (int t = 0; t < 4; ++t) {
            rv0 += wt[t] * ib[offp[t]];
            rv1 += wt[t] * ib[HW_ + offp[t]];
            rv2 += wt[t] * ib[2 * HW_ + offp[t]];
        }
    }
    float sdx = cam[v*3+0]-px, sdy = cam[v*3+1]-py, sdz = cam[v*3+2]-pz;
    float snv = sqrtf(sdx*sdx + sdy*sdy + sdz*sdz);
    sdx /= snv; sdy /= snv; sdz /= snv;

    // ---- build x[42] (x[41] = 1.0 -> layer-1 bias via W1T col 41) ----
    float xx[42];
    xx[0] = rv0; xx[1] = rv1; xx[2] = rv2;
    #pragma unroll
    for (int i = 3; i < 35; ++i) xx[i] = 0.f;
    #pragma unroll
    for (int t = 0; t < 4; ++t) {
        const float4* fp = (const float4*)(pk + ((size_t)v * HW_ + offp[t]) * 32);
        float wtt = wt[t];
        #pragma unroll
        for (int k4 = 0; k4 < 8; ++k4) {
            float4 f = fp[k4];
            xx[3+k4*4+0] += wtt * f.x;
            xx[3+k4*4+1] += wtt * f.y;
            xx[3+k4*4+2] += wtt * f.z;
            xx[3+k4*4+3] += wtt * f.w;
        }
    }
    xx[35] = sdx; xx[36] = sdy; xx[37] = sdz;
    xx[38] = rdx; xx[39] = rdy; xx[40] = rdz;
    xx[41] = 1.0f;

    // ---- write X row (48 bf16, XOR-swizzled 16B slots) ----
    {
        unsigned int d[24];
        #pragma unroll
        for (int i = 0; i < 21; ++i) d[i] = pk2bf(xx[2*i], xx[2*i+1]);
        d[21] = 0u; d[22] = 0u; d[23] = 0u;
        const int swzw = (lane & 7) << 4;
        char* base = Xw + lane * 128;
        #pragma unroll
        for (int o = 0; o < 6; ++o)
            *(uint4*)(base + ((o * 16) ^ swzw)) =
                make_uint4(d[o*4], d[o*4+1], d[o*4+2], d[o*4+3]);
    }

    // ---- preload weight A-frags ----
    short8v aw1[6], aw2[8];
    #pragma unroll
    for (int i = 0; i < 6; ++i)
        aw1[i] = __builtin_bit_cast(short8v, ((const uint4*)FR)[i * 64 + lane]);
    #pragma unroll
    for (int i = 0; i < 8; ++i)
        aw2[i] = __builtin_bit_cast(short8v, ((const uint4*)(FR + 1536))[i * 64 + lane]);
    const float* PL = (const float*)(FR + 3584);
    const float bdv = bd[0], bbv = bb[0];

    float hs = vsum8(msample);
    float hssw  = __shfl_xor(hs, 32, 64);
    float rv0sw = __shfl_xor(rv0, 32, 64);
    float rv1sw = __shfl_xor(rv1, 32, 64);
    float rv2sw = __shfl_xor(rv2, 32, 64);

    const int swz  = (l31 & 7) << 4;
    const int hi16 = hi * 16;

    #pragma unroll
    for (int nt = 0; nt < 2; ++nt) {
        const int n = nt * 32 + l31;
        // ---- layer 1: H1^T = W1T @ X^T ----
        f32x16 acc1[2];
        #pragma unroll
        for (int mt = 0; mt < 2; ++mt)
            #pragma unroll
            for (int q = 0; q < 16; ++q) acc1[mt][q] = 0.f;
        #pragma unroll
        for (int kt = 0; kt < 3; ++kt) {
            uint4 bu = *(const uint4*)(Xw + n * 128 + ((kt * 32 + hi16) ^ swz));
            short8v b = __builtin_bit_cast(short8v, bu);
            acc1[0] = __builtin_amdgcn_mfma_f32_32x32x16_bf16(aw1[kt],     b, acc1[0], 0, 0, 0);
            acc1[1] = __builtin_amdgcn_mfma_f32_32x32x16_bf16(aw1[3 + kt], b, acc1[1], 0, 0, 0);
        }
        // relu + bf16 + write H1[row=l31][j1] (quads of 4 consecutive j1)
        #pragma unroll
        for (int mt = 0; mt < 2; ++mt)
            #pragma unroll
            for (int q = 0; q < 4; ++q) {
                unsigned int w0 = pk2bf(fmaxf(acc1[mt][4*q+0], 0.f),
                                        fmaxf(acc1[mt][4*q+1], 0.f));
                unsigned int w1 = pk2bf(fmaxf(acc1[mt][4*q+2], 0.f),
                                        fmaxf(acc1[mt][4*q+3], 0.f));
                int o = 16 * q + 8 * hi + 64 * mt;
                *(uint2*)(H1w + l31 * 128 + (o ^ swz)) = make_uint2(w0, w1);
            }
        // ---- layer 2: H2^T = W2T @ H1^T (bias via C-init) ----
        f32x16 acc2[2];
        #pragma unroll
        for (int mt = 0; mt < 2; ++mt)
            #pragma unroll
            for (int q = 0; q < 16; ++q) acc2[mt][q] = PL[mt * 32 + hi16 + q];
        #pragma unroll
        for (int kt = 0; kt < 4; ++kt) {
            uint4 bu = *(const uint4*)(H1w + l31 * 128 + ((kt * 32 + hi16) ^ swz));
            short8v b = __builtin_bit_cast(short8v, bu);
            acc2[0] = __builtin_amdgcn_mfma_f32_32x32x16_bf16(aw2[kt],     b, acc2[0], 0, 0, 0);
            acc2[1] = __builtin_amdgcn_mfma_f32_32x32x16_bf16(aw2[4 + kt], b, acc2[1], 0, 0, 0);
        }

        // ---- pooling: lane owns ray-row rr = 32*nt + l31, 32 j2 values ----
        float h[2][16];
        #pragma unroll
        for (int mt = 0; mt < 2; ++mt)
            #pragma unroll
            for (int q = 0; q < 16; ++q) h[mt][q] = fmaxf(acc2[mt][q], 0.f);

        float lgp = 0.f, dacc = 0.f, cacc = 0.f;
        #pragma unroll
        for (int mt = 0; mt < 2; ++mt)
            #pragma unroll
            for (int q = 0; q < 16; ++q) {
                float hv = h[mt][q];
                lgp  += hv * PL[64  + mt * 32 + hi16 + q];
                float wd  = PL[128 + mt * 32 + hi16 + q];
                float wd2 = PL[192 + mt * 32 + hi16 + q];
                dacc += hv * wd + hv * hv * wd2;
                float sj = vsum8(hv);
                cacc += sj * sj * wd2;
            }
        float lg = lgp + __shfl_xor(lgp, 32, 64) + bbv;
        dacc += __shfl_xor(dacc, 32, 64);
        dacc  = vsum8(dacc);
        cacc += __shfl_xor(cacc, 32, 64);
        float density = dacc * 0.125f - cacc * (1.0f / 64.0f) + bdv;

        float mx = vmax8(lg);
        float e  = expf(lg - mx);
        float es = vsum8(e);
        float r0c = (hi == nt) ? rv0 : rv0sw;
        float r1c = (hi == nt) ? rv1 : rv1sw;
        float r2c = (hi == nt) ? rv2 : rv2sw;
        float br  = vsum8(e * r0c);
        float bg  = vsum8(e * r1c);
        float bbl = vsum8(e * r2c);
        float hn  = (nt == 0) ? hs : hssw;
        bool hull = hn > ((float)V_ - 0.001f);

        if ((lane & 0x27) == 0) {      // lane in {0,8,16,24}
            int PP = pbase + 4 * nt + (lane >> 3);
            float is = 1.0f / es;
            odens[PP]      = hull ? density  : 0.f;
            orgb[PP*3 + 0] = hull ? br  * is : 0.f;
            orgb[PP*3 + 1] = hull ? bg  * is : 0.f;
            orgb[PP*3 + 2] = hull ? bbl * is : 0.f;
        }
    }
}

// ---------------------- fallback (unpacked ws): round-6 scalar kernel ----------
template <int S, int FS, bool FINE>
__global__ __launch_bounds__(256, 2) void k_mlp_fb(
    const float* __restrict__ ray, const float* __restrict__ Pm,
    const float* __restrict__ cam, const float* __restrict__ shp,
    const float* __restrict__ msk, const float* __restrict__ img,
    const float* __restrict__ fea,
    const float* __restrict__ W1, const float* __restrict__ b1,
    const float* __restrict__ W2, const float* __restrict__ b2,
    const float* __restrict__ Wd, const float* __restrict__ bd,
    const float* __restrict__ Wb, const float* __restrict__ bb,
    const float* __restrict__ deptharr,
    float* __restrict__ odens, float* __restrict__ orgb) {

    const int tid = blockIdx.x * 256 + threadIdx.x;
    const int v   = tid & 7;
    const int P   = tid >> 3;
    const int r   = P / S, s = P - r * S;

    const float ox = ray[r*8+0], oy = ray[r*8+1], oz = ray[r*8+2];
    const float dx = ray[r*8+3], dy = ray[r*8+4], dz = ray[r*8+5];
    const float nv = ray[r*8+6], fv = ray[r*8+7];
    float depth;
    if (FINE) depth = deptharr[P];
    else      depth = nv + (fv - nv) * ((s + 0.5f) / (float)S);
    const float px = ox + dx*depth, py = oy + dy*depth, pz = oz + dz*depth;
    const float dn = sqrtf(dx*dx + dy*dy + dz*dz);
    const float rdx = -dx/dn, rdy = -dy/dn, rdz = -dz/dn;
    const float* Pv = Pm + v * 12;
    float q0 = Pv[0]*px + Pv[1]*py + Pv[2]*pz  + Pv[3];
    float q1 = Pv[4]*px + Pv[5]*py + Pv[6]*pz  + Pv[7];
    float q2 = Pv[8]*px + Pv[9]*py + Pv[10]*pz + Pv[11];
    float inv = 1.0f / (q2 + 1e-6f);
    float uu = q0 * inv, ww = q1 * inv;
    float gx = 2.0f * (uu / shp[v*2+1]) - 1.0f;
    float gy = 2.0f * (ww / shp[v*2+0]) - 1.0f;
    float sx = (gx + 1.0f) * ((float)W_ * 0.5f) - 0.5f;
    float sy = (gy + 1.0f) * ((float)H_ * 0.5f) - 0.5f;
    float x0f = floorf(sx), y0f = floorf(sy);
    float fx = sx - x0f, fy = sy - y0f;
    int offp[4]; float wt[4];
    {
        float xs[2] = {x0f, x0f + 1.f}, ys[2] = {y0f, y0f + 1.f};
        float wxs[2] = {1.f - fx, fx},  wys[2] = {1.f - fy, fy};
        #pragma unroll
        for (int t = 0; t < 4; ++t) {
            float xf = xs[t & 1], yf = ys[t >> 1];
            bool val = (xf >= 0.f) && (xf <= (float)(W_-1)) &&
                       (yf >= 0.f) && (yf <= (float)(H_-1));
            int xi = (int)fminf(fmaxf(xf, 0.f), (float)(W_-1));
            int yi = (int)fminf(fmaxf(yf, 0.f), (float)(H_-1));
            offp[t] = yi * W_ + xi;
            wt[t] = wxs[t & 1] * wys[t >> 1] * (val ? 1.f : 0.f);
        }
    }
    const float* mb = msk + v * HW_;
    float msample = wt[0]*mb[offp[0]] + wt[1]*mb[offp[1]]
                  + wt[2]*mb[offp[2]] + wt[3]*mb[offp[3]];
    float rv0 = 0.f, rv1 = 0.f, rv2 = 0.f;
    {
        const float* ib = img + (v * 3) * HW_;
        #pragma unroll
        for (int t = 0; t < 4; ++t) {
            rv0 += wt[t] * ib[offp[t]];
            rv1 += wt[t] * ib[HW_ + offp[t]];
            rv2 += wt[t] * ib[2 * HW_ + offp[t]];
        }
    }
    float sdx = cam[v*3+0]-px, sdy = cam[v*3+1]-py, sdz = cam[v*3+2]-pz;
    float snv = sqrtf(sdx*sdx + sdy*sdy + sdz*sdz);
    sdx /= snv; sdy /= snv; sdz /= snv;
    float xx[IND_];
    xx[0] = rv0; xx[1] = rv1; xx[2] = rv2;
    #pragma unroll
    for (int k = 0; k < 32; ++k) {
        const float* fb = fea + (size_t)(v * (2*L_) + FS + k) * HW_;
        xx[3+k] = wt[0]*fb[offp[0]] + wt[1]*fb[offp[1]]
                + wt[2]*fb[offp[2]] + wt[3]*fb[offp[3]];
    }
    xx[35] = sdx; xx[36] = sdy; xx[37] = sdz;
    xx[38] = rdx; xx[39] = rdy; xx[40] = rdz;
    float h1[HID_];
    #pragma unroll
    for (int j = 0; j < HID_; ++j) {
        float a0 = 0.f;
        #pragma unroll
        for (int k = 0; k < IND_; ++k) a0 += xx[k] * W1[k * HID_ + j];
        h1[j] = fmaxf(b1[j] + a0, 0.f);
    }
    float lg = bb[0];
    float A = 0.f, B = 0.f, C = 0.f;
    #pragma unroll 1
    for (int j = 0; j < HID_; j += 4) {
        float hh[4];
        #pragma unroll
        for (int jj = 0; jj < 4; ++jj) {
            float a0 = 0.f;
            #pragma unroll
            for (int k = 0; k < HID_; ++k) a0 += h1[k] * W2[k * HID_ + (j + jj)];
            hh[jj] = fmaxf(b2[j + jj] + a0, 0.f);
        }
        #pragma unroll
        for (int jj = 0; jj < 4; ++jj) {
            float h = hh[jj];
            lg += h * Wb[j + jj];
            A  += h * Wd[j + jj];
            B  += h * h * Wd[HID_ + j + jj];
            float sj = vsum8(h);
            C  += sj * sj * Wd[HID_ + j + jj];
        }
    }
    A = vsum8(A); B = vsum8(B);
    float density = A * 0.125f + B * 0.125f - C * (1.0f / 64.0f) + bd[0];
    float hsv = vsum8(msample);
    bool hull = hsv > ((float)V_ - 0.001f);
    float mx = vmax8(lg);
    float e = expf(lg - mx);
    float es = vsum8(e);
    float br  = vsum8(e * rv0);
    float bg  = vsum8(e * rv1);
    float bbl = vsum8(e * rv2);
    if (v == 0) {
        float is = 1.0f / es;
        odens[P]      = hull ? density  : 0.f;
        orgb[P*3 + 0] = hull ? br  * is : 0.f;
        orgb[P*3 + 1] = hull ? bg  * is : 0.f;
        orgb[P*3 + 2] = hull ? bbl * is : 0.f;
    }
}

// ---------------------------------------- coarse composite + sample_pdf + merge
__global__ void k_comp_coarse(const float* __restrict__ ray,
                              const float* __restrict__ dens,
                              const float* __restrict__ rgb,
                              float* __restrict__ out,
                              float* __restrict__ fulld) {
    int r = blockIdx.x * blockDim.x + threadIdx.x;
    if (r >= R_) return;
    const float nv = ray[r*8+6], fv = ray[r*8+7];
    float wv[NC_];
    float T = 1.f, c0 = 0.f, c1 = 0.f, c2 = 0.f, cd = 0.f, ca = 0.f;
    for (int s = 0; s < NC_; ++s) {
        float d0 = nv + (fv - nv) * ((s + 0.5f) / NC_);
        float d1 = nv + (fv - nv) * ((s + 1.5f) / NC_);
        float delta = (s == NC_-1) ? 1e10f : (d1 - d0);
        float a = 1.f - expf(-fmaxf(dens[r*NC_+s], 0.f) * delta);
        float wi = a * T;
        wv[s] = wi;
        c0 += wi * rgb[(r*NC_+s)*3+0];
        c1 += wi * rgb[(r*NC_+s)*3+1];
        c2 += wi * rgb[(r*NC_+s)*3+2];
        cd += wi * d0; ca += wi;
        T *= (1.f - a + 1e-10f);
    }
    out[r*3+0] = c0; out[r*3+1] = c1; out[r*3+2] = c2;
    out[3072 + r] = cd;
    out[4096 + r] = ca;
    float tot = 0.f;
    for (int i = 0; i < 62; ++i) tot += wv[i+1] + 1e-5f;
    float cdf[63];
    cdf[0] = 0.f;
    float run = 0.f;
    for (int i = 0; i < 62; ++i) { run += (wv[i+1] + 1e-5f) / tot; cdf[i+1] = run; }
    float fd[NF_];
    int idx = 1;
    for (int i = 0; i < NF_; ++i) {
        float u = (i + 0.5f) / NF_;
        while (idx < 63 && cdf[idx] <= u) ++idx;
        int below = idx - 1;
        int above = (idx > 62) ? 62 : idx;
        float cA = cdf[below], cB = cdf[above];
        float b0 = nv + (fv - nv) * ((below + 1.0f) / NC_);
        float b1 = nv + (fv - nv) * ((above + 1.0f) / NC_);
        float dnm = cB - cA;
        dnm = (dnm < 1e-5f) ? 1.f : dnm;
        float t = (u - cA) / dnm;
        fd[i] = b0 + t * (b1 - b0);
    }
    float* fl = fulld + r * (NC_ + NF_);
    int a_ = 0, b_ = 0;
    for (int i = 0; i < NC_ + NF_; ++i) {
        float da = (a_ < NC_) ? nv + (fv - nv) * ((a_ + 0.5f) / NC_) : 3.0e38f;
        float db = (b_ < NF_) ? fd[b_] : 3.0e38f;
        if (da <= db) { fl[i] = da; ++a_; } else { fl[i] = db; ++b_; }
    }
}

// ---------------------------------------------------------- fine composite
__global__ void k_comp_fine(const float* __restrict__ fulld,
                            const float* __restrict__ dens,
                            const float* __restrict__ rgb,
                            float* __restrict__ out) {
    int r = blockIdx.x * blockDim.x + threadIdx.x;
    if (r >= R_) return;
    const int S = NC_ + NF_;
    const float* fl = fulld + r * S;
    float T = 1.f, c0 = 0.f, c1 = 0.f, c2 = 0.f, cd = 0.f, ca = 0.f;
    for (int s = 0; s < S; ++s) {
        float d0 = fl[s];
        float delta = (s == S-1) ? 1e10f : (fl[s+1] - d0);
        float a = 1.f - expf(-fmaxf(dens[r*S+s], 0.f) * delta);
        float wi = a * T;
        c0 += wi * rgb[(r*S+s)*3+0];
        c1 += wi * rgb[(r*S+s)*3+1];
        c2 += wi * rgb[(r*S+s)*3+2];
        cd += wi * d0; ca += wi;
        T *= (1.f - a + 1e-10f);
    }
    out[5120 + r*3+0] = c0; out[5120 + r*3+1] = c1; out[5120 + r*3+2] = c2;
    out[8192 + r] = cd;
    out[9216 + r] = ca;
}

// ------------------------------------------------------------------ launch
extern "C" void kernel_launch(void* const* d_in, const int* in_sizes, int n_in,
                              void* d_out, int out_size, void* d_ws, size_t ws_size,
                              hipStream_t stream) {
    const float* ray = (const float*)d_in[0];
    const float* Kin = (const float*)d_in[1];
    const float* Ein = (const float*)d_in[2];
    const float* cam = (const float*)d_in[3];
    const float* shp = (const float*)d_in[4];
    const float* msk = (const float*)d_in[5];
    const float* img = (const float*)d_in[6];
    const float* fea = (const float*)d_in[7];
    const float* cw[8]; for (int i = 0; i < 8; ++i) cw[i] = (const float*)d_in[8+i];
    const float* fw[8]; for (int i = 0; i < 8; ++i) fw[i] = (const float*)d_in[16+i];

    float* ws    = (float*)d_ws;
    float* Pm    = ws;                        // 96
    unsigned int* FRc = (unsigned int*)(Pm + 96);   // 4096 dwords
    unsigned int* FRf = FRc + 4096;                 // 4096 dwords
    float* cdens = (float*)(FRf + 4096);      // 65536
    float* crgb  = cdens + R_ * NC_;          // 196608
    float* fulld = crgb + R_ * NC_ * 3;       // 131072
    float* fdens = fulld + R_ * (NC_+NF_);    // 131072
    float* frgb  = fdens + R_ * (NC_+NF_);    // 393216
    float* pk    = frgb + R_ * (NC_+NF_) * 3; // V*HW*32

    size_t base_floats = (size_t)(pk - ws);
    size_t need = (base_floats + (size_t)V_ * HW_ * 32 + 64) * sizeof(float);
    bool packed = (ws_size >= need);

    float* outp  = (float*)d_out;

    k_computeP<<<1, 96, 0, stream>>>(Kin, Ein, Pm);

    if (packed) {
        k_packMFMA<<<15, 256, 0, stream>>>(cw[0], cw[1], cw[2], cw[3], cw[4], cw[6], FRc);
        k_packMFMA<<<15, 256, 0, stream>>>(fw[0], fw[1], fw[2], fw[3], fw[4], fw[6], FRf);
        k_packF32<<<dim3(W_/64, H_, V_), 256, 0, stream>>>(fea, pk, 0);

        k_mlp_mfma<NC_, false><<<R_ * NC_ / 32, 256, 0, stream>>>(
            ray, Pm, cam, shp, msk, img, pk, FRc, cw[5], cw[7],
            nullptr, cdens, crgb);

        k_comp_coarse<<<R_ / 256, 256, 0, stream>>>(ray, cdens, crgb, outp, fulld);

        k_packF32<<<dim3(W_/64, H_, V_), 256, 0, stream>>>(fea, pk, L_);

        k_mlp_mfma<NC_ + NF_, true><<<R_ * (NC_+NF_) / 32, 256, 0, stream>>>(
            ray, Pm, cam, shp, msk, img, pk, FRf, fw[5], fw[7],
            fulld, fdens, frgb);

        k_comp_fine<<<R_ / 256, 256, 0, stream>>>(fulld, fdens, frgb, outp);
    } else {
        k_mlp_fb<NC_, 0, false><<<R_ * NC_ * 8 / 256, 256, 0, stream>>>(
            ray, Pm, cam, shp, msk, img, fea,
            cw[0], cw[1], cw[2], cw[3], cw[4], cw[5], cw[6], cw[7],
            nullptr, cdens, crgb);

        k_comp_coarse<<<R_ / 256, 256, 0, stream>>>(ray, cdens, crgb, outp, fulld);

        k_mlp_fb<NC_ + NF_, L_, true><<<R_ * (NC_+NF_) * 8 / 256, 256, 0, stream>>>(
            ray, Pm, cam, shp, msk, img, fea,
            fw[0], fw[1], fw[2], fw[3], fw[4], fw[5], fw[6], fw[7],
            fulld, fdens, frgb);

        k_comp_fine<<<R_ / 256, 256, 0, stream>>>(fulld, fdens, frgb, outp);
    }
}

// Round 8
// 253.023 us; speedup vs baseline: 3.3168x; 1.5921x over previous
//
#include <hip/hip_runtime.h>
#include <math.h>

#define V_   8
#define H_   256
#define W_   256
#define L_   32
#define HID_ 64
#define NC_  64
#define NF_  64
#define R_   1024
#define IND_ 41              // 3 + 32 + 3 + 3
#define HW_  (H_*W_)

typedef __attribute__((ext_vector_type(8)))  short short8v;
typedef __attribute__((ext_vector_type(16))) float f32x16;

// ---------------- bf16 helpers (RNE) ----------------
__device__ __forceinline__ unsigned int pk2bf(float a, float b) {
    unsigned int ua = __float_as_uint(a);
    unsigned int ub = __float_as_uint(b);
    unsigned int ra = (ua + 0x7FFFu + ((ua >> 16) & 1u)) >> 16;
    unsigned int rb = (ub + 0x7FFFu + ((ub >> 16) & 1u)) & 0xFFFF0000u;
    return ra | rb;
}

// ---- cross-lane helpers ----
template<int CTRL>
__device__ __forceinline__ float dpp_add(float x) {
    int m = __builtin_amdgcn_mov_dpp(__builtin_bit_cast(int, x), CTRL, 0xF, 0xF, true);
    return x + __builtin_bit_cast(float, m);
}
template<int CTRL>
__device__ __forceinline__ float dpp_max(float x) {
    int m = __builtin_amdgcn_mov_dpp(__builtin_bit_cast(int, x), CTRL, 0xF, 0xF, true);
    return fmaxf(x, __builtin_bit_cast(float, m));
}
__device__ __forceinline__ float vsum8(float x) {
    x = dpp_add<0xB1>(x);           // xor 1
    x = dpp_add<0x4E>(x);           // xor 2
    x += __shfl_xor(x, 4, 64);      // xor 4
    return x;
}
__device__ __forceinline__ float vmax8(float x) {
    x = dpp_max<0xB1>(x);
    x = dpp_max<0x4E>(x);
    x = fmaxf(x, __shfl_xor(x, 4, 64));
    return x;
}
__device__ __forceinline__ float redsum64(float x) {
    #pragma unroll
    for (int off = 32; off >= 1; off >>= 1) x += __shfl_xor(x, off, 64);
    return x;
}
__device__ __forceinline__ float scan_mul64(float x, int lane) {
    #pragma unroll
    for (int off = 1; off < 64; off <<= 1) {
        float y = __shfl_up(x, off, 64);
        x = (lane >= off) ? x * y : x;
    }
    return x;
}
__device__ __forceinline__ float scan_add64(float x, int lane) {
    #pragma unroll
    for (int off = 1; off < 64; off <<= 1) {
        float y = __shfl_up(x, off, 64);
        x = (lane >= off) ? x + y : x;
    }
    return x;
}

// ---------------------------------------------------------------- P = K @ E
__global__ void k_computeP(const float* __restrict__ Km,
                           const float* __restrict__ Em,
                           float* __restrict__ Pm) {
    int t = threadIdx.x;
    if (t >= V_ * 12) return;
    int v = t / 12, e = t - v * 12, row = e >> 2, col = e & 3;
    float acc = 0.f;
    #pragma unroll
    for (int k = 0; k < 3; ++k)
        acc += Km[v * 9 + row * 3 + k] * Em[v * 12 + k * 4 + col];
    Pm[v * 12 + row * 4 + col] = acc;
}

// ---------------- pack weights into MFMA fragment order (bf16) ----------------
__global__ void k_packMFMA(const float* __restrict__ W1, const float* __restrict__ b1,
                           const float* __restrict__ W2, const float* __restrict__ b2,
                           const float* __restrict__ Wd, const float* __restrict__ Wb,
                           unsigned int* __restrict__ out) {
    int t = blockIdx.x * 256 + threadIdx.x;   // 0..3839
    if (t < 1536) {
        int blk = t >> 8, idx = t & 255;
        int mt = blk / 3, kt = blk % 3;
        int l = idx >> 2, rg = idx & 3;
        int hi = l >> 5;
        int j  = 32 * mt + (l & 31);
        int k0 = 16 * kt + 8 * hi + 2 * rg;
        int k1 = k0 + 1;
        float v0 = (k0 < 41) ? W1[k0 * 64 + j] : (k0 == 41 ? b1[j] : 0.f);
        float v1 = (k1 < 41) ? W1[k1 * 64 + j] : (k1 == 41 ? b1[j] : 0.f);
        out[t] = pk2bf(v0, v1);
    } else if (t < 3584) {
        int u = t - 1536;
        int blk = u >> 8, idx = u & 255;
        int l = idx >> 2, rg = idx & 3;
        int hi = l >> 5;
        int j2 = 32 * (blk >> 2) + (l & 31);
        int k0 = 16 * (blk & 3) + 8 * hi + 2 * rg;
        out[t] = pk2bf(W2[k0 * 64 + j2], W2[(k0 + 1) * 64 + j2]);
    } else if (t < 3840) {
        int i = t - 3584;
        int w = i >> 6, mt = (i >> 5) & 1, hi = (i >> 4) & 1, rg = i & 15;
        int j2 = (rg & 3) + 8 * (rg >> 2) + 4 * hi + 32 * mt;
        float v = (w == 0) ? b2[j2] : (w == 1) ? Wb[j2] : (w == 2) ? Wd[j2] : Wd[64 + j2];
        ((float*)out)[t] = v;
    }
}

// -------------------------- pack 32 feature channels to pixel-major [V][HW][32]
__global__ __launch_bounds__(256) void k_packF32(const float* __restrict__ fea,
                                                 float* __restrict__ pk, int FS) {
    __shared__ float tile[32][65];
    const int xb = blockIdx.x * 64, y = blockIdx.y, v = blockIdx.z;
    const int t = threadIdx.x;
    #pragma unroll
    for (int step = 0; step < 8; ++step) {
        int c = step * 4 + (t >> 6);
        int x = t & 63;
        tile[c][x] = fea[((size_t)(v * 2 * L_ + FS + c)) * HW_ + y * W_ + xb + x];
    }
    __syncthreads();
    #pragma unroll
    for (int step = 0; step < 8; ++step) {
        int x = step * 8 + (t >> 5);
        int c = t & 31;
        pk[((size_t)v * HW_ + y * W_ + xb + x) * 32 + c] = tile[c][x];
    }
}

// ------------------------------------------------------------- MFMA MLP kernel
template <int S, bool FINE>
__global__ __launch_bounds__(256) void k_mlp_mfma(
    const float* __restrict__ ray, const float* __restrict__ Pm,
    const float* __restrict__ cam, const float* __restrict__ shp,
    const float* __restrict__ msk, const float* __restrict__ img,
    const float* __restrict__ pk,
    const unsigned int* __restrict__ FR,
    const float* __restrict__ bd, const float* __restrict__ bb,
    const float* __restrict__ deptharr,
    float* __restrict__ odens, float* __restrict__ orgb) {

    __shared__ __align__(16) char smem[49152];
    const int lane = threadIdx.x & 63;
    const int wv   = threadIdx.x >> 6;
    const int hi   = lane >> 5;
    const int l31  = lane & 31;
    char* Xw  = smem + wv * 12288;     // X: 64 rows x 128B (48 bf16 + pad)
    char* H1w = Xw + 8192;             // H1: 32 rows x 128B (64 bf16)

    const int pbase = (blockIdx.x * 4 + wv) * 8;
    const int P0 = pbase + (lane >> 3);
    const int v  = lane & 7;
    const int r  = P0 / S, s = P0 - r * S;

    const float ox = ray[r*8+0], oy = ray[r*8+1], oz = ray[r*8+2];
    const float dx = ray[r*8+3], dy = ray[r*8+4], dz = ray[r*8+5];
    const float nv = ray[r*8+6], fv = ray[r*8+7];

    float depth;
    if (FINE) depth = deptharr[P0];
    else      depth = nv + (fv - nv) * ((s + 0.5f) / (float)S);

    const float px = ox + dx*depth, py = oy + dy*depth, pz = oz + dz*depth;
    const float dn = sqrtf(dx*dx + dy*dy + dz*dz);
    const float rdx = -dx/dn, rdy = -dy/dn, rdz = -dz/dn;

    const float* Pv = Pm + v * 12;
    float q0 = Pv[0]*px + Pv[1]*py + Pv[2]*pz  + Pv[3];
    float q1 = Pv[4]*px + Pv[5]*py + Pv[6]*pz  + Pv[7];
    float q2 = Pv[8]*px + Pv[9]*py + Pv[10]*pz + Pv[11];
    float inv = 1.0f / (q2 + 1e-6f);
    float uu = q0 * inv, ww = q1 * inv;
    float gx = 2.0f * (uu / shp[v*2+1]) - 1.0f;
    float gy = 2.0f * (ww / shp[v*2+0]) - 1.0f;
    float sx = (gx + 1.0f) * ((float)W_ * 0.5f) - 0.5f;
    float sy = (gy + 1.0f) * ((float)H_ * 0.5f) - 0.5f;
    float x0f = floorf(sx), y0f = floorf(sy);
    float fx = sx - x0f, fy = sy - y0f;

    int offp[4]; float wt[4];
    {
        float xs[2] = {x0f, x0f + 1.f}, ys[2] = {y0f, y0f + 1.f};
        float wxs[2] = {1.f - fx, fx},  wys[2] = {1.f - fy, fy};
        #pragma unroll
        for (int t = 0; t < 4; ++t) {
            float xf = xs[t & 1], yf = ys[t >> 1];
            bool val = (xf >= 0.f) && (xf <= (float)(W_-1)) &&
                       (yf >= 0.f) && (yf <= (float)(H_-1));
            int xi = (int)fminf(fmaxf(xf, 0.f), (float)(W_-1));
            int yi = (int)fminf(fmaxf(yf, 0.f), (float)(H_-1));
            offp[t] = yi * W_ + xi;
            wt[t] = wxs[t & 1] * wys[t >> 1] * (val ? 1.f : 0.f);
        }
    }

    const float* mb = msk + v * HW_;
    float msample = wt[0]*mb[offp[0]] + wt[1]*mb[offp[1]]
                  + wt[2]*mb[offp[2]] + wt[3]*mb[offp[3]];
    float rv0 = 0.f, rv1 = 0.f, rv2 = 0.f;
    {
        const float* ib = img + (v * 3) * HW_;
        #pragma unroll
        for (int t = 0; t < 4; ++t) {
            rv0 += wt[t] * ib[offp[t]];
            rv1 += wt[t] * ib[HW_ + offp[t]];
            rv2 += wt[t] * ib[2 * HW_ + offp[t]];
        }
    }
    float sdx = cam[v*3+0]-px, sdy = cam[v*3+1]-py, sdz = cam[v*3+2]-pz;
    float snv = sqrtf(sdx*sdx + sdy*sdy + sdz*sdz);
    sdx /= snv; sdy /= snv; sdz /= snv;

    // ---- build x[42] (x[41] = 1.0 -> layer-1 bias via W1T col 41) ----
    float xx[42];
    xx[0] = rv0; xx[1] = rv1; xx[2] = rv2;
    #pragma unroll
    for (int i = 3; i < 35; ++i) xx[i] = 0.f;
    #pragma unroll
    for (int t = 0; t < 4; ++t) {
        const float4* fp = (const float4*)(pk + ((size_t)v * HW_ + offp[t]) * 32);
        float wtt = wt[t];
        #pragma unroll
        for (int k4 = 0; k4 < 8; ++k4) {
            float4 f = fp[k4];
            xx[3+k4*4+0] += wtt * f.x;
            xx[3+k4*4+1] += wtt * f.y;
            xx[3+k4*4+2] += wtt * f.z;
            xx[3+k4*4+3] += wtt * f.w;
        }
    }
    xx[35] = sdx; xx[36] = sdy; xx[37] = sdz;
    xx[38] = rdx; xx[39] = rdy; xx[40] = rdz;
    xx[41] = 1.0f;

    // ---- write X row (48 bf16, XOR-swizzled 16B slots) ----
    {
        unsigned int d[24];
        #pragma unroll
        for (int i = 0; i < 21; ++i) d[i] = pk2bf(xx[2*i], xx[2*i+1]);
        d[21] = 0u; d[22] = 0u; d[23] = 0u;
        const int swzw = (lane & 7) << 4;
        char* base = Xw + lane * 128;
        #pragma unroll
        for (int o = 0; o < 6; ++o)
            *(uint4*)(base + ((o * 16) ^ swzw)) =
                make_uint4(d[o*4], d[o*4+1], d[o*4+2], d[o*4+3]);
    }

    // ---- preload weight A-frags ----
    short8v aw1[6], aw2[8];
    #pragma unroll
    for (int i = 0; i < 6; ++i)
        aw1[i] = __builtin_bit_cast(short8v, ((const uint4*)FR)[i * 64 + lane]);
    #pragma unroll
    for (int i = 0; i < 8; ++i)
        aw2[i] = __builtin_bit_cast(short8v, ((const uint4*)(FR + 1536))[i * 64 + lane]);
    const float* PL = (const float*)(FR + 3584);
    const float bdv = bd[0], bbv = bb[0];

    float hs = vsum8(msample);
    float hssw  = __shfl_xor(hs, 32, 64);
    float rv0sw = __shfl_xor(rv0, 32, 64);
    float rv1sw = __shfl_xor(rv1, 32, 64);
    float rv2sw = __shfl_xor(rv2, 32, 64);

    const int swz  = (l31 & 7) << 4;
    const int hi16 = hi * 16;

    #pragma unroll
    for (int nt = 0; nt < 2; ++nt) {
        const int n = nt * 32 + l31;
        // ---- layer 1: H1^T = W1T @ X^T ----
        f32x16 acc1[2];
        #pragma unroll
        for (int mt = 0; mt < 2; ++mt)
            #pragma unroll
            for (int q = 0; q < 16; ++q) acc1[mt][q] = 0.f;
        #pragma unroll
        for (int kt = 0; kt < 3; ++kt) {
            uint4 bu = *(const uint4*)(Xw + n * 128 + ((kt * 32 + hi16) ^ swz));
            short8v b = __builtin_bit_cast(short8v, bu);
            acc1[0] = __builtin_amdgcn_mfma_f32_32x32x16_bf16(aw1[kt],     b, acc1[0], 0, 0, 0);
            acc1[1] = __builtin_amdgcn_mfma_f32_32x32x16_bf16(aw1[3 + kt], b, acc1[1], 0, 0, 0);
        }
        #pragma unroll
        for (int mt = 0; mt < 2; ++mt)
            #pragma unroll
            for (int q = 0; q < 4; ++q) {
                unsigned int w0 = pk2bf(fmaxf(acc1[mt][4*q+0], 0.f),
                                        fmaxf(acc1[mt][4*q+1], 0.f));
                unsigned int w1 = pk2bf(fmaxf(acc1[mt][4*q+2], 0.f),
                                        fmaxf(acc1[mt][4*q+3], 0.f));
                int o = 16 * q + 8 * hi + 64 * mt;
                *(uint2*)(H1w + l31 * 128 + (o ^ swz)) = make_uint2(w0, w1);
            }
        // ---- layer 2: H2^T = W2T @ H1^T (bias via C-init) ----
        f32x16 acc2[2];
        #pragma unroll
        for (int mt = 0; mt < 2; ++mt)
            #pragma unroll
            for (int q = 0; q < 16; ++q) acc2[mt][q] = PL[mt * 32 + hi16 + q];
        #pragma unroll
        for (int kt = 0; kt < 4; ++kt) {
            uint4 bu = *(const uint4*)(H1w + l31 * 128 + ((kt * 32 + hi16) ^ swz));
            short8v b = __builtin_bit_cast(short8v, bu);
            acc2[0] = __builtin_amdgcn_mfma_f32_32x32x16_bf16(aw2[kt],     b, acc2[0], 0, 0, 0);
            acc2[1] = __builtin_amdgcn_mfma_f32_32x32x16_bf16(aw2[4 + kt], b, acc2[1], 0, 0, 0);
        }

        // ---- pooling ----
        float h[2][16];
        #pragma unroll
        for (int mt = 0; mt < 2; ++mt)
            #pragma unroll
            for (int q = 0; q < 16; ++q) h[mt][q] = fmaxf(acc2[mt][q], 0.f);

        float lgp = 0.f, dacc = 0.f, cacc = 0.f;
        #pragma unroll
        for (int mt = 0; mt < 2; ++mt)
            #pragma unroll
            for (int q = 0; q < 16; ++q) {
                float hv = h[mt][q];
                lgp  += hv * PL[64  + mt * 32 + hi16 + q];
                float wd  = PL[128 + mt * 32 + hi16 + q];
                float wd2 = PL[192 + mt * 32 + hi16 + q];
                dacc += hv * wd + hv * hv * wd2;
                float sj = vsum8(hv);
                cacc += sj * sj * wd2;
            }
        float lg = lgp + __shfl_xor(lgp, 32, 64) + bbv;
        dacc += __shfl_xor(dacc, 32, 64);
        dacc  = vsum8(dacc);
        cacc += __shfl_xor(cacc, 32, 64);
        float density = dacc * 0.125f - cacc * (1.0f / 64.0f) + bdv;

        float mx = vmax8(lg);
        float e  = expf(lg - mx);
        float es = vsum8(e);
        float r0c = (hi == nt) ? rv0 : rv0sw;
        float r1c = (hi == nt) ? rv1 : rv1sw;
        float r2c = (hi == nt) ? rv2 : rv2sw;
        float br  = vsum8(e * r0c);
        float bg  = vsum8(e * r1c);
        float bbl = vsum8(e * r2c);
        float hn  = (nt == 0) ? hs : hssw;
        bool hull = hn > ((float)V_ - 0.001f);

        if ((lane & 0x27) == 0) {      // lane in {0,8,16,24}
            int PP = pbase + 4 * nt + (lane >> 3);
            float is = 1.0f / es;
            odens[PP]      = hull ? density  : 0.f;
            orgb[PP*3 + 0] = hull ? br  * is : 0.f;
            orgb[PP*3 + 1] = hull ? bg  * is : 0.f;
            orgb[PP*3 + 2] = hull ? bbl * is : 0.f;
        }
    }
}

// ---------------------- fallback (unpacked ws): scalar kernel ----------
template <int S, int FS, bool FINE>
__global__ __launch_bounds__(256, 2) void k_mlp_fb(
    const float* __restrict__ ray, const float* __restrict__ Pm,
    const float* __restrict__ cam, const float* __restrict__ shp,
    const float* __restrict__ msk, const float* __restrict__ img,
    const float* __restrict__ fea,
    const float* __restrict__ W1, const float* __restrict__ b1,
    const float* __restrict__ W2, const float* __restrict__ b2,
    const float* __restrict__ Wd, const float* __restrict__ bd,
    const float* __restrict__ Wb, const float* __restrict__ bb,
    const float* __restrict__ deptharr,
    float* __restrict__ odens, float* __restrict__ orgb) {

    const int tid = blockIdx.x * 256 + threadIdx.x;
    const int v   = tid & 7;
    const int P   = tid >> 3;
    const int r   = P / S, s = P - r * S;

    const float ox = ray[r*8+0], oy = ray[r*8+1], oz = ray[r*8+2];
    const float dx = ray[r*8+3], dy = ray[r*8+4], dz = ray[r*8+5];
    const float nv = ray[r*8+6], fv = ray[r*8+7];
    float depth;
    if (FINE) depth = deptharr[P];
    else      depth = nv + (fv - nv) * ((s + 0.5f) / (float)S);
    const float px = ox + dx*depth, py = oy + dy*depth, pz = oz + dz*depth;
    const float dn = sqrtf(dx*dx + dy*dy + dz*dz);
    const float rdx = -dx/dn, rdy = -dy/dn, rdz = -dz/dn;
    const float* Pv = Pm + v * 12;
    float q0 = Pv[0]*px + Pv[1]*py + Pv[2]*pz  + Pv[3];
    float q1 = Pv[4]*px + Pv[5]*py + Pv[6]*pz  + Pv[7];
    float q2 = Pv[8]*px + Pv[9]*py + Pv[10]*pz + Pv[11];
    float inv = 1.0f / (q2 + 1e-6f);
    float uu = q0 * inv, ww = q1 * inv;
    float gx = 2.0f * (uu / shp[v*2+1]) - 1.0f;
    float gy = 2.0f * (ww / shp[v*2+0]) - 1.0f;
    float sx = (gx + 1.0f) * ((float)W_ * 0.5f) - 0.5f;
    float sy = (gy + 1.0f) * ((float)H_ * 0.5f) - 0.5f;
    float x0f = floorf(sx), y0f = floorf(sy);
    float fx = sx - x0f, fy = sy - y0f;
    int offp[4]; float wt[4];
    {
        float xs[2] = {x0f, x0f + 1.f}, ys[2] = {y0f, y0f + 1.f};
        float wxs[2] = {1.f - fx, fx},  wys[2] = {1.f - fy, fy};
        #pragma unroll
        for (int t = 0; t < 4; ++t) {
            float xf = xs[t & 1], yf = ys[t >> 1];
            bool val = (xf >= 0.f) && (xf <= (float)(W_-1)) &&
                       (yf >= 0.f) && (yf <= (float)(H_-1));
            int xi = (int)fminf(fmaxf(xf, 0.f), (float)(W_-1));
            int yi = (int)fminf(fmaxf(yf, 0.f), (float)(H_-1));
            offp[t] = yi * W_ + xi;
            wt[t] = wxs[t & 1] * wys[t >> 1] * (val ? 1.f : 0.f);
        }
    }
    const float* mb = msk + v * HW_;
    float msample = wt[0]*mb[offp[0]] + wt[1]*mb[offp[1]]
                  + wt[2]*mb[offp[2]] + wt[3]*mb[offp[3]];
    float rv0 = 0.f, rv1 = 0.f, rv2 = 0.f;
    {
        const float* ib = img + (v * 3) * HW_;
        #pragma unroll
        for (int t = 0; t < 4; ++t) {
            rv0 += wt[t] * ib[offp[t]];
            rv1 += wt[t] * ib[HW_ + offp[t]];
            rv2 += wt[t] * ib[2 * HW_ + offp[t]];
        }
    }
    float sdx = cam[v*3+0]-px, sdy = cam[v*3+1]-py, sdz = cam[v*3+2]-pz;
    float snv = sqrtf(sdx*sdx + sdy*sdy + sdz*sdz);
    sdx /= snv; sdy /= snv; sdz /= snv;
    float xx[IND_];
    xx[0] = rv0; xx[1] = rv1; xx[2] = rv2;
    #pragma unroll
    for (int k = 0; k < 32; ++k) {
        const float* fb = fea + (size_t)(v * (2*L_) + FS + k) * HW_;
        xx[3+k] = wt[0]*fb[offp[0]] + wt[1]*fb[offp[1]]
                + wt[2]*fb[offp[2]] + wt[3]*fb[offp[3]];
    }
    xx[35] = sdx; xx[36] = sdy; xx[37] = sdz;
    xx[38] = rdx; xx[39] = rdy; xx[40] = rdz;
    float h1[HID_];
    #pragma unroll
    for (int j = 0; j < HID_; ++j) {
        float a0 = 0.f;
        #pragma unroll
        for (int k = 0; k < IND_; ++k) a0 += xx[k] * W1[k * HID_ + j];
        h1[j] = fmaxf(b1[j] + a0, 0.f);
    }
    float lg = bb[0];
    float A = 0.f, B = 0.f, C = 0.f;
    #pragma unroll 1
    for (int j = 0; j < HID_; j += 4) {
        float hh[4];
        #pragma unroll
        for (int jj = 0; jj < 4; ++jj) {
            float a0 = 0.f;
            #pragma unroll
            for (int k = 0; k < HID_; ++k) a0 += h1[k] * W2[k * HID_ + (j + jj)];
            hh[jj] = fmaxf(b2[j + jj] + a0, 0.f);
        }
        #pragma unroll
        for (int jj = 0; jj < 4; ++jj) {
            float h = hh[jj];
            lg += h * Wb[j + jj];
            A  += h * Wd[j + jj];
            B  += h * h * Wd[HID_ + j + jj];
            float sj = vsum8(h);
            C  += sj * sj * Wd[HID_ + j + jj];
        }
    }
    A = vsum8(A); B = vsum8(B);
    float density = A * 0.125f + B * 0.125f - C * (1.0f / 64.0f) + bd[0];
    float hsv = vsum8(msample);
    bool hull = hsv > ((float)V_ - 0.001f);
    float mx = vmax8(lg);
    float e = expf(lg - mx);
    float es = vsum8(e);
    float br  = vsum8(e * rv0);
    float bg  = vsum8(e * rv1);
    float bbl = vsum8(e * rv2);
    if (v == 0) {
        float is = 1.0f / es;
        odens[P]      = hull ? density  : 0.f;
        orgb[P*3 + 0] = hull ? br  * is : 0.f;
        orgb[P*3 + 1] = hull ? bg  * is : 0.f;
        orgb[P*3 + 2] = hull ? bbl * is : 0.f;
    }
}

// -------------- wave-per-ray coarse composite + sample_pdf + merge-path -------
__global__ __launch_bounds__(256) void k_comp_coarse(const float* __restrict__ ray,
                                                     const float* __restrict__ dens,
                                                     const float* __restrict__ rgb,
                                                     float* __restrict__ out,
                                                     float* __restrict__ fulld) {
    __shared__ float cdfS[4][64];
    __shared__ float fdS[4][64];
    const int wv = threadIdx.x >> 6, lane = threadIdx.x & 63;
    const int r = blockIdx.x * 4 + wv;
    const float nv = ray[r*8+6], fv = ray[r*8+7];
    const int s = lane;

    float d0 = nv + (fv - nv) * ((s + 0.5f) / NC_);
    float d1 = nv + (fv - nv) * ((s + 1.5f) / NC_);
    float delta = (s == NC_-1) ? 1e10f : (d1 - d0);
    float a = 1.f - expf(-fmaxf(dens[r*NC_ + s], 0.f) * delta);
    float qv = 1.f - a + 1e-10f;
    float inc = scan_mul64(qv, lane);
    float trans = __shfl_up(inc, 1, 64);
    if (lane == 0) trans = 1.f;
    float w = a * trans;

    float g0 = rgb[(r*NC_+s)*3+0], g1 = rgb[(r*NC_+s)*3+1], g2 = rgb[(r*NC_+s)*3+2];
    float c0 = redsum64(w * g0);
    float c1 = redsum64(w * g1);
    float c2 = redsum64(w * g2);
    float cd = redsum64(w * d0);
    float ca = redsum64(w);
    if (lane == 0) {
        out[r*3+0] = c0; out[r*3+1] = c1; out[r*3+2] = c2;
        out[3072 + r] = cd;
        out[4096 + r] = ca;
    }

    // ---- sample_pdf: pdf over w[1..62], cdf via scan, per-lane searchsorted ----
    float pw = (s >= 1 && s <= 62) ? (w + 1e-5f) : 0.f;
    float tot = redsum64(pw);
    float p = pw / tot;
    float ic = scan_add64(p, lane);          // cdf[j] = ic[j], j=0..62 (ic[0]=0)
    cdfS[wv][lane] = ic;
    __syncthreads();

    float u = (lane + 0.5f) / NF_;
    int lo = 0, hi = 63;                     // searchsorted right over cdf[0..62]
    while (lo < hi) {
        int mid = (lo + hi) >> 1;
        if (cdfS[wv][mid] <= u) lo = mid + 1; else hi = mid;
    }
    int below = lo - 1;
    int above = (lo > 62) ? 62 : lo;
    float cA = cdfS[wv][below], cB = cdfS[wv][above];
    float b0 = nv + (fv - nv) * ((below + 1.0f) / NC_);
    float b1 = nv + (fv - nv) * ((above + 1.0f) / NC_);
    float dnm = cB - cA;
    dnm = (dnm < 1e-5f) ? 1.f : dnm;
    float fdv = b0 + (u - cA) / dnm * (b1 - b0);
    fdS[wv][lane] = fdv;
    __syncthreads();

    // ---- merge-path: place coarse depth d0 and fine depth fdv ----
    lo = 0; hi = 64;                         // count fd < d0
    while (lo < hi) {
        int mid = (lo + hi) >> 1;
        if (fdS[wv][mid] < d0) lo = mid + 1; else hi = mid;
    }
    fulld[r*128 + s + lo] = d0;

    lo = 0; hi = 64;                         // count da <= fdv (da recomputed exactly)
    while (lo < hi) {
        int mid = (lo + hi) >> 1;
        float daj = nv + (fv - nv) * ((mid + 0.5f) / NC_);
        if (daj <= fdv) lo = mid + 1; else hi = mid;
    }
    fulld[r*128 + lane + lo] = fdv;
}

// ------------------------- wave-per-ray fine composite (2 samples/lane) -------
__global__ __launch_bounds__(256) void k_comp_fine(const float* __restrict__ fulld,
                                                   const float* __restrict__ dens,
                                                   const float* __restrict__ rgb,
                                                   float* __restrict__ out) {
    const int wv = threadIdx.x >> 6, lane = threadIdx.x & 63;
    const int r = blockIdx.x * 4 + wv;
    const int S = NC_ + NF_;
    const float* fl = fulld + r * S;
    const int s0 = 2 * lane, s1 = 2 * lane + 1;

    float f0 = fl[s0], f1 = fl[s1];
    float nx = __shfl_down(f0, 1, 64);
    float dl0 = f1 - f0;
    float dl1 = (lane == 63) ? 1e10f : (nx - f1);
    float a0 = 1.f - expf(-fmaxf(dens[r*S + s0], 0.f) * dl0);
    float a1 = 1.f - expf(-fmaxf(dens[r*S + s1], 0.f) * dl1);
    float q0 = 1.f - a0 + 1e-10f, q1 = 1.f - a1 + 1e-10f;
    float inc = scan_mul64(q0 * q1, lane);
    float E = __shfl_up(inc, 1, 64);
    if (lane == 0) E = 1.f;
    float w0 = a0 * E, w1 = a1 * (E * q0);

    float g00 = rgb[(r*S+s0)*3+0], g01 = rgb[(r*S+s0)*3+1], g02 = rgb[(r*S+s0)*3+2];
    float g10 = rgb[(r*S+s1)*3+0], g11 = rgb[(r*S+s1)*3+1], g12 = rgb[(r*S+s1)*3+2];
    float c0 = redsum64(w0*g00 + w1*g10);
    float c1 = redsum64(w0*g01 + w1*g11);
    float c2 = redsum64(w0*g02 + w1*g12);
    float cd = redsum64(w0*f0 + w1*f1);
    float ca = redsum64(w0 + w1);
    if (lane == 0) {
        out[5120 + r*3+0] = c0; out[5120 + r*3+1] = c1; out[5120 + r*3+2] = c2;
        out[8192 + r] = cd;
        out[9216 + r] = ca;
    }
}

// ------------------------------------------------------------------ launch
extern "C" void kernel_launch(void* const* d_in, const int* in_sizes, int n_in,
                              void* d_out, int out_size, void* d_ws, size_t ws_size,
                              hipStream_t stream) {
    const float* ray = (const float*)d_in[0];
    const float* Kin = (const float*)d_in[1];
    const float* Ein = (const float*)d_in[2];
    const float* cam = (const float*)d_in[3];
    const float* shp = (const float*)d_in[4];
    const float* msk = (const float*)d_in[5];
    const float* img = (const float*)d_in[6];
    const float* fea = (const float*)d_in[7];
    const float* cw[8]; for (int i = 0; i < 8; ++i) cw[i] = (const float*)d_in[8+i];
    const float* fw[8]; for (int i = 0; i < 8; ++i) fw[i] = (const float*)d_in[16+i];

    float* ws    = (float*)d_ws;
    float* Pm    = ws;                        // 96
    unsigned int* FRc = (unsigned int*)(Pm + 96);   // 4096 dwords
    unsigned int* FRf = FRc + 4096;                 // 4096 dwords
    float* cdens = (float*)(FRf + 4096);      // 65536
    float* crgb  = cdens + R_ * NC_;          // 196608
    float* fulld = crgb + R_ * NC_ * 3;       // 131072
    float* fdens = fulld + R_ * (NC_+NF_);    // 131072
    float* frgb  = fdens + R_ * (NC_+NF_);    // 393216
    float* pk    = frgb + R_ * (NC_+NF_) * 3; // V*HW*32

    size_t base_floats = (size_t)(pk - ws);
    size_t need = (base_floats + (size_t)V_ * HW_ * 32 + 64) * sizeof(float);
    bool packed = (ws_size >= need);

    float* outp  = (float*)d_out;

    k_computeP<<<1, 96, 0, stream>>>(Kin, Ein, Pm);

    if (packed) {
        k_packMFMA<<<15, 256, 0, stream>>>(cw[0], cw[1], cw[2], cw[3], cw[4], cw[6], FRc);
        k_packMFMA<<<15, 256, 0, stream>>>(fw[0], fw[1], fw[2], fw[3], fw[4], fw[6], FRf);
        k_packF32<<<dim3(W_/64, H_, V_), 256, 0, stream>>>(fea, pk, 0);

        k_mlp_mfma<NC_, false><<<R_ * NC_ / 32, 256, 0, stream>>>(
            ray, Pm, cam, shp, msk, img, pk, FRc, cw[5], cw[7],
            nullptr, cdens, crgb);

        k_comp_coarse<<<R_ / 4, 256, 0, stream>>>(ray, cdens, crgb, outp, fulld);

        k_packF32<<<dim3(W_/64, H_, V_), 256, 0, stream>>>(fea, pk, L_);

        k_mlp_mfma<NC_ + NF_, true><<<R_ * (NC_+NF_) / 32, 256, 0, stream>>>(
            ray, Pm, cam, shp, msk, img, pk, FRf, fw[5], fw[7],
            fulld, fdens, frgb);

        k_comp_fine<<<R_ / 4, 256, 0, stream>>>(fulld, fdens, frgb, outp);
    } else {
        k_mlp_fb<NC_, 0, false><<<R_ * NC_ * 8 / 256, 256, 0, stream>>>(
            ray, Pm, cam, shp, msk, img, fea,
            cw[0], cw[1], cw[2], cw[3], cw[4], cw[5], cw[6], cw[7],
            nullptr, cdens, crgb);

        k_comp_coarse<<<R_ / 4, 256, 0, stream>>>(ray, cdens, crgb, outp, fulld);

        k_mlp_fb<NC_ + NF_, L_, true><<<R_ * (NC_+NF_) * 8 / 256, 256, 0, stream>>>(
            ray, Pm, cam, shp, msk, img, fea,
            fw[0], fw[1], fw[2], fw[3], fw[4], fw[5], fw[6], fw[7],
            fulld, fdens, frgb);

        k_comp_fine<<<R_ / 4, 256, 0, stream>>>(fulld, fdens, frgb, outp);
    }
}

// Round 10
// 252.792 us; speedup vs baseline: 3.3199x; 1.0009x over previous
//
#include <hip/hip_runtime.h>
#include <hip/hip_bf16.h>
#include <math.h>

#define V_   8
#define H_   256
#define W_   256
#define L_   32
#define HID_ 64
#define NC_  64
#define NF_  64
#define R_   1024
#define IND_ 41              // 3 + 32 + 3 + 3
#define HW_  (H_*W_)

typedef __attribute__((ext_vector_type(8)))  short short8v;
typedef __attribute__((ext_vector_type(16))) float f32x16;

// ---------------- bf16 helpers (RNE) ----------------
__device__ __forceinline__ unsigned int pk2bf(float a, float b) {
    // paired f32->bf16 converts; compiler fuses to v_cvt_pk_bf16_f32
    unsigned int ra = (unsigned int)__bfloat16_as_ushort(__float2bfloat16(a));
    unsigned int rb = (unsigned int)__bfloat16_as_ushort(__float2bfloat16(b));
    return ra | (rb << 16);
}

// ---- cross-lane helpers ----
template<int CTRL>
__device__ __forceinline__ float dpp_add(float x) {
    int m = __builtin_amdgcn_mov_dpp(__builtin_bit_cast(int, x), CTRL, 0xF, 0xF, true);
    return x + __builtin_bit_cast(float, m);
}
template<int CTRL>
__device__ __forceinline__ float dpp_max(float x) {
    int m = __builtin_amdgcn_mov_dpp(__builtin_bit_cast(int, x), CTRL, 0xF, 0xF, true);
    return fmaxf(x, __builtin_bit_cast(float, m));
}
__device__ __forceinline__ float vsum8(float x) {
    x = dpp_add<0xB1>(x);           // xor 1
    x = dpp_add<0x4E>(x);           // xor 2
    x += __shfl_xor(x, 4, 64);      // xor 4
    return x;
}
__device__ __forceinline__ float vmax8(float x) {
    x = dpp_max<0xB1>(x);
    x = dpp_max<0x4E>(x);
    x = fmaxf(x, __shfl_xor(x, 4, 64));
    return x;
}
__device__ __forceinline__ float redsum64(float x) {
    #pragma unroll
    for (int off = 32; off >= 1; off >>= 1) x += __shfl_xor(x, off, 64);
    return x;
}
__device__ __forceinline__ float scan_mul64(float x, int lane) {
    #pragma unroll
    for (int off = 1; off < 64; off <<= 1) {
        float y = __shfl_up(x, off, 64);
        x = (lane >= off) ? x * y : x;
    }
    return x;
}
__device__ __forceinline__ float scan_add64(float x, int lane) {
    #pragma unroll
    for (int off = 1; off < 64; off <<= 1) {
        float y = __shfl_up(x, off, 64);
        x = (lane >= off) ? x + y : x;
    }
    return x;
}

// ---------------------------------------------------------------- P = K @ E
__global__ void k_computeP(const float* __restrict__ Km,
                           const float* __restrict__ Em,
                           float* __restrict__ Pm) {
    int t = threadIdx.x;
    if (t >= V_ * 12) return;
    int v = t / 12, e = t - v * 12, row = e >> 2, col = e & 3;
    float acc = 0.f;
    #pragma unroll
    for (int k = 0; k < 3; ++k)
        acc += Km[v * 9 + row * 3 + k] * Em[v * 12 + k * 4 + col];
    Pm[v * 12 + row * 4 + col] = acc;
}

// ---------------- pack weights into MFMA fragment order (bf16) ----------------
__global__ void k_packMFMA(const float* __restrict__ W1, const float* __restrict__ b1,
                           const float* __restrict__ W2, const float* __restrict__ b2,
                           const float* __restrict__ Wd, const float* __restrict__ Wb,
                           unsigned int* __restrict__ out) {
    int t = blockIdx.x * 256 + threadIdx.x;   // 0..3839
    if (t < 1536) {
        int blk = t >> 8, idx = t & 255;
        int mt = blk / 3, kt = blk % 3;
        int l = idx >> 2, rg = idx & 3;
        int hi = l >> 5;
        int j  = 32 * mt + (l & 31);
        int k0 = 16 * kt + 8 * hi + 2 * rg;
        int k1 = k0 + 1;
        float v0 = (k0 < 41) ? W1[k0 * 64 + j] : (k0 == 41 ? b1[j] : 0.f);
        float v1 = (k1 < 41) ? W1[k1 * 64 + j] : (k1 == 41 ? b1[j] : 0.f);
        out[t] = pk2bf(v0, v1);
    } else if (t < 3584) {
        int u = t - 1536;
        int blk = u >> 8, idx = u & 255;
        int l = idx >> 2, rg = idx & 3;
        int hi = l >> 5;
        int j2 = 32 * (blk >> 2) + (l & 31);
        int k0 = 16 * (blk & 3) + 8 * hi + 2 * rg;
        out[t] = pk2bf(W2[k0 * 64 + j2], W2[(k0 + 1) * 64 + j2]);
    } else if (t < 3840) {
        int i = t - 3584;
        int w = i >> 6, mt = (i >> 5) & 1, hi = (i >> 4) & 1, rg = i & 15;
        int j2 = (rg & 3) + 8 * (rg >> 2) + 4 * hi + 32 * mt;
        float v = (w == 0) ? b2[j2] : (w == 1) ? Wb[j2] : (w == 2) ? Wd[j2] : Wd[64 + j2];
        ((float*)out)[t] = v;
    }
}

// -------------------------- pack 32 feature channels to pixel-major [V][HW][32]
__global__ __launch_bounds__(256) void k_packF32(const float* __restrict__ fea,
                                                 float* __restrict__ pk, int FS) {
    __shared__ float tile[32][65];
    const int xb = blockIdx.x * 64, y = blockIdx.y, v = blockIdx.z;
    const int t = threadIdx.x;
    #pragma unroll
    for (int step = 0; step < 8; ++step) {
        int c = step * 4 + (t >> 6);
        int x = t & 63;
        tile[c][x] = fea[((size_t)(v * 2 * L_ + FS + c)) * HW_ + y * W_ + xb + x];
    }
    __syncthreads();
    #pragma unroll
    for (int step = 0; step < 8; ++step) {
        int x = step * 8 + (t >> 5);
        int c = t & 31;
        pk[((size_t)v * HW_ + y * W_ + xb + x) * 32 + c] = tile[c][x];
    }
}

// ------------------------------------------------------------- MFMA MLP kernel
// Wave = 8 points x 8 views = 64 ray-rows. Both layers computed transposed
// (H^T = W^T @ X^T). LDS per wave: X slot-major [6][64][16B] = 6KB,
// H1 slot-major [8][32][16B] = 4KB -> 40KB/block -> 4 blocks/CU.
template <int S, bool FINE>
__global__ __launch_bounds__(256) void k_mlp_mfma(
    const float* __restrict__ ray, const float* __restrict__ Pm,
    const float* __restrict__ cam, const float* __restrict__ shp,
    const float* __restrict__ msk, const float* __restrict__ img,
    const float* __restrict__ pk,
    const unsigned int* __restrict__ FR,
    const float* __restrict__ bd, const float* __restrict__ bb,
    const float* __restrict__ deptharr,
    float* __restrict__ odens, float* __restrict__ orgb) {

    __shared__ __align__(16) char smem[40960];
    const int lane = threadIdx.x & 63;
    const int wv   = threadIdx.x >> 6;
    const int hi   = lane >> 5;
    const int l31  = lane & 31;
    char* Xw  = smem + wv * 10240;     // X: [slot 0..5][row 0..63][16B]
    char* H1w = Xw + 6144;             // H1: [slot 0..7][col 0..31][16B]

    const int pbase = (blockIdx.x * 4 + wv) * 8;
    const int P0 = pbase + (lane >> 3);
    const int v  = lane & 7;
    const int r  = P0 / S, s = P0 - r * S;

    const float ox = ray[r*8+0], oy = ray[r*8+1], oz = ray[r*8+2];
    const float dx = ray[r*8+3], dy = ray[r*8+4], dz = ray[r*8+5];
    const float nv = ray[r*8+6], fv = ray[r*8+7];

    float depth;
    if (FINE) depth = deptharr[P0];
    else      depth = nv + (fv - nv) * ((s + 0.5f) / (float)S);

    const float px = ox + dx*depth, py = oy + dy*depth, pz = oz + dz*depth;
    const float dn = sqrtf(dx*dx + dy*dy + dz*dz);
    const float rdx = -dx/dn, rdy = -dy/dn, rdz = -dz/dn;

    const float* Pv = Pm + v * 12;
    float q0 = Pv[0]*px + Pv[1]*py + Pv[2]*pz  + Pv[3];
    float q1 = Pv[4]*px + Pv[5]*py + Pv[6]*pz  + Pv[7];
    float q2 = Pv[8]*px + Pv[9]*py + Pv[10]*pz + Pv[11];
    float inv = 1.0f / (q2 + 1e-6f);
    float uu = q0 * inv, ww = q1 * inv;
    float gx = 2.0f * (uu / shp[v*2+1]) - 1.0f;
    float gy = 2.0f * (ww / shp[v*2+0]) - 1.0f;
    float sx = (gx + 1.0f) * ((float)W_ * 0.5f) - 0.5f;
    float sy = (gy + 1.0f) * ((float)H_ * 0.5f) - 0.5f;
    float x0f = floorf(sx), y0f = floorf(sy);
    float fx = sx - x0f, fy = sy - y0f;

    int offp[4]; float wt[4];
    {
        float xs[2] = {x0f, x0f + 1.f}, ys[2] = {y0f, y0f + 1.f};
        float wxs[2] = {1.f - fx, fx},  wys[2] = {1.f - fy, fy};
        #pragma unroll
        for (int t = 0; t < 4; ++t) {
            float xf = xs[t & 1], yf = ys[t >> 1];
            bool val = (xf >= 0.f) && (xf <= (float)(W_-1)) &&
                       (yf >= 0.f) && (yf <= (float)(H_-1));
            int xi = (int)fminf(fmaxf(xf, 0.f), (float)(W_-1));
            int yi = (int)fminf(fmaxf(yf, 0.f), (float)(H_-1));
            offp[t] = yi * W_ + xi;
            wt[t] = wxs[t & 1] * wys[t >> 1] * (val ? 1.f : 0.f);
        }
    }

    const float* mb = msk + v * HW_;
    float msample = wt[0]*mb[offp[0]] + wt[1]*mb[offp[1]]
                  + wt[2]*mb[offp[2]] + wt[3]*mb[offp[3]];
    float rv0 = 0.f, rv1 = 0.f, rv2 = 0.f;
    {
        const float* ib = img + (v * 3) * HW_;
        #pragma unroll
        for (int t = 0; t < 4; ++t) {
            rv0 += wt[t] * ib[offp[t]];
            rv1 += wt[t] * ib[HW_ + offp[t]];
            rv2 += wt[t] * ib[2 * HW_ + offp[t]];
        }
    }
    float sdx = cam[v*3+0]-px, sdy = cam[v*3+1]-py, sdz = cam[v*3+2]-pz;
    float snv = sqrtf(sdx*sdx + sdy*sdy + sdz*sdz);
    sdx /= snv; sdy /= snv; sdz /= snv;

    // ---- build x[42] (x[41] = 1.0 -> layer-1 bias via W1T col 41) ----
    float xx[42];
    xx[0] = rv0; xx[1] = rv1; xx[2] = rv2;
    #pragma unroll
    for (int i = 3; i < 35; ++i) xx[i] = 0.f;
    #pragma unroll
    for (int t = 0; t < 4; ++t) {
        const float4* fp = (const float4*)(pk + ((size_t)v * HW_ + offp[t]) * 32);
        float wtt = wt[t];
        #pragma unroll
        for (int k4 = 0; k4 < 8; ++k4) {
            float4 f = fp[k4];
            xx[3+k4*4+0] += wtt * f.x;
            xx[3+k4*4+1] += wtt * f.y;
            xx[3+k4*4+2] += wtt * f.z;
            xx[3+k4*4+3] += wtt * f.w;
        }
    }
    xx[35] = sdx; xx[36] = sdy; xx[37] = sdz;
    xx[38] = rdx; xx[39] = rdy; xx[40] = rdz;
    xx[41] = 1.0f;

    // ---- write X row: slot-major, slot o = k dwords [4o,4o+4), coalesced ----
    {
        unsigned int d[24];
        #pragma unroll
        for (int i = 0; i < 21; ++i) d[i] = pk2bf(xx[2*i], xx[2*i+1]);
        d[21] = 0u; d[22] = 0u; d[23] = 0u;
        #pragma unroll
        for (int o = 0; o < 6; ++o)
            *(uint4*)(Xw + o * 1024 + lane * 16) =
                make_uint4(d[o*4], d[o*4+1], d[o*4+2], d[o*4+3]);
    }

    // ---- preload weight A-frags ----
    short8v aw1[6], aw2[8];
    #pragma unroll
    for (int i = 0; i < 6; ++i)
        aw1[i] = __builtin_bit_cast(short8v, ((const uint4*)FR)[i * 64 + lane]);
    #pragma unroll
    for (int i = 0; i < 8; ++i)
        aw2[i] = __builtin_bit_cast(short8v, ((const uint4*)(FR + 1536))[i * 64 + lane]);
    const float4* PL4 = (const float4*)(FR + 3584);   // [w(4)][mt(2)][hi(2)][4xfloat4]
    const float bdv = bd[0], bbv = bb[0];

    float hs = vsum8(msample);
    float hssw  = __shfl_xor(hs, 32, 64);
    float rv0sw = __shfl_xor(rv0, 32, 64);
    float rv1sw = __shfl_xor(rv1, 32, 64);
    float rv2sw = __shfl_xor(rv2, 32, 64);

    #pragma unroll
    for (int nt = 0; nt < 2; ++nt) {
        const int n = nt * 32 + l31;
        // ---- layer 1: H1^T = W1T @ X^T ----
        f32x16 acc1[2];
        #pragma unroll
        for (int mt = 0; mt < 2; ++mt)
            #pragma unroll
            for (int q = 0; q < 16; ++q) acc1[mt][q] = 0.f;
        #pragma unroll
        for (int kt = 0; kt < 3; ++kt) {
            uint4 bu = *(const uint4*)(Xw + (2*kt + hi) * 1024 + n * 16);
            short8v b = __builtin_bit_cast(short8v, bu);
            acc1[0] = __builtin_amdgcn_mfma_f32_32x32x16_bf16(aw1[kt],     b, acc1[0], 0, 0, 0);
            acc1[1] = __builtin_amdgcn_mfma_f32_32x32x16_bf16(aw1[3 + kt], b, acc1[1], 0, 0, 0);
        }
        // relu + bf16 + write H1 slot-major: slot = q + 4*mt, col = l31
        #pragma unroll
        for (int mt = 0; mt < 2; ++mt)
            #pragma unroll
            for (int q = 0; q < 4; ++q) {
                unsigned int w0 = pk2bf(fmaxf(acc1[mt][4*q+0], 0.f),
                                        fmaxf(acc1[mt][4*q+1], 0.f));
                unsigned int w1 = pk2bf(fmaxf(acc1[mt][4*q+2], 0.f),
                                        fmaxf(acc1[mt][4*q+3], 0.f));
                *(uint2*)(H1w + (q + 4*mt) * 512 + l31 * 16 + hi * 8) = make_uint2(w0, w1);
            }
        // ---- layer 2: H2^T = W2T @ H1^T (bias via C-init, float4 loads) ----
        f32x16 acc2[2];
        #pragma unroll
        for (int mt = 0; mt < 2; ++mt)
            #pragma unroll
            for (int q4 = 0; q4 < 4; ++q4) {
                float4 c = PL4[(mt*2 + hi)*4 + q4];
                acc2[mt][4*q4+0] = c.x; acc2[mt][4*q4+1] = c.y;
                acc2[mt][4*q4+2] = c.z; acc2[mt][4*q4+3] = c.w;
            }
        #pragma unroll
        for (int kt = 0; kt < 4; ++kt) {
            uint4 bu = *(const uint4*)(H1w + (2*kt + hi) * 512 + l31 * 16);
            short8v b = __builtin_bit_cast(short8v, bu);
            acc2[0] = __builtin_amdgcn_mfma_f32_32x32x16_bf16(aw2[kt],     b, acc2[0], 0, 0, 0);
            acc2[1] = __builtin_amdgcn_mfma_f32_32x32x16_bf16(aw2[4 + kt], b, acc2[1], 0, 0, 0);
        }

        // ---- pooling: lane owns ray-row n, 32 j2 values ----
        float lgp = 0.f, dacc = 0.f, cacc = 0.f;
        #pragma unroll
        for (int mt = 0; mt < 2; ++mt)
            #pragma unroll
            for (int q4 = 0; q4 < 4; ++q4) {
                float4 wb4 = PL4[16 + (mt*2 + hi)*4 + q4];
                float4 wd4 = PL4[32 + (mt*2 + hi)*4 + q4];
                float4 w24 = PL4[48 + (mt*2 + hi)*4 + q4];
                #pragma unroll
                for (int e = 0; e < 4; ++e) {
                    float hv = fmaxf(acc2[mt][4*q4+e], 0.f);
                    float wbv = (e==0)?wb4.x:(e==1)?wb4.y:(e==2)?wb4.z:wb4.w;
                    float wdv = (e==0)?wd4.x:(e==1)?wd4.y:(e==2)?wd4.z:wd4.w;
                    float w2v = (e==0)?w24.x:(e==1)?w24.y:(e==2)?w24.z:w24.w;
                    lgp  += hv * wbv;
                    dacc += hv * wdv + hv * hv * w2v;
                    float sj = vsum8(hv);
                    cacc += sj * sj * w2v;
                }
            }
        float lg = lgp + __shfl_xor(lgp, 32, 64) + bbv;
        dacc += __shfl_xor(dacc, 32, 64);
        dacc  = vsum8(dacc);
        cacc += __shfl_xor(cacc, 32, 64);
        float density = dacc * 0.125f - cacc * (1.0f / 64.0f) + bdv;

        float mx = vmax8(lg);
        float e  = expf(lg - mx);
        float es = vsum8(e);
        float r0c = (hi == nt) ? rv0 : rv0sw;
        float r1c = (hi == nt) ? rv1 : rv1sw;
        float r2c = (hi == nt) ? rv2 : rv2sw;
        float br  = vsum8(e * r0c);
        float bg  = vsum8(e * r1c);
        float bbl = vsum8(e * r2c);
        float hn  = (nt == 0) ? hs : hssw;
        bool hull = hn > ((float)V_ - 0.001f);

        if ((lane & 0x27) == 0) {      // lane in {0,8,16,24}
            int PP = pbase + 4 * nt + (lane >> 3);
            float is = 1.0f / es;
            odens[PP]      = hull ? density  : 0.f;
            orgb[PP*3 + 0] = hull ? br  * is : 0.f;
            orgb[PP*3 + 1] = hull ? bg  * is : 0.f;
            orgb[PP*3 + 2] = hull ? bbl * is : 0.f;
        }
    }
}

// ---------------------- fallback (unpacked ws): scalar kernel ----------
template <int S, int FS, bool FINE>
__global__ __launch_bounds__(256, 2) void k_mlp_fb(
    const float* __restrict__ ray, const float* __restrict__ Pm,
    const float* __restrict__ cam, const float* __restrict__ shp,
    const float* __restrict__ msk, const float* __restrict__ img,
    const float* __restrict__ fea,
    const float* __restrict__ W1, const float* __restrict__ b1,
    const float* __restrict__ W2, const float* __restrict__ b2,
    const float* __restrict__ Wd, const float* __restrict__ bd,
    const float* __restrict__ Wb, const float* __restrict__ bb,
    const float* __restrict__ deptharr,
    float* __restrict__ odens, float* __restrict__ orgb) {

    const int tid = blockIdx.x * 256 + threadIdx.x;
    const int v   = tid & 7;
    const int P   = tid >> 3;
    const int r   = P / S, s = P - r * S;

    const float ox = ray[r*8+0], oy = ray[r*8+1], oz = ray[r*8+2];
    const float dx = ray[r*8+3], dy = ray[r*8+4], dz = ray[r*8+5];
    const float nv = ray[r*8+6], fv = ray[r*8+7];
    float depth;
    if (FINE) depth = deptharr[P];
    else      depth = nv + (fv - nv) * ((s + 0.5f) / (float)S);
    const float px = ox + dx*depth, py = oy + dy*depth, pz = oz + dz*depth;
    const float dn = sqrtf(dx*dx + dy*dy + dz*dz);
    const float rdx = -dx/dn, rdy = -dy/dn, rdz = -dz/dn;
    const float* Pv = Pm + v * 12;
    float q0 = Pv[0]*px + Pv[1]*py + Pv[2]*pz  + Pv[3];
    float q1 = Pv[4]*px + Pv[5]*py + Pv[6]*pz  + Pv[7];
    float q2 = Pv[8]*px + Pv[9]*py + Pv[10]*pz + Pv[11];
    float inv = 1.0f / (q2 + 1e-6f);
    float uu = q0 * inv, ww = q1 * inv;
    float gx = 2.0f * (uu / shp[v*2+1]) - 1.0f;
    float gy = 2.0f * (ww / shp[v*2+0]) - 1.0f;
    float sx = (gx + 1.0f) * ((float)W_ * 0.5f) - 0.5f;
    float sy = (gy + 1.0f) * ((float)H_ * 0.5f) - 0.5f;
    float x0f = floorf(sx), y0f = floorf(sy);
    float fx = sx - x0f, fy = sy - y0f;
    int offp[4]; float wt[4];
    {
        float xs[2] = {x0f, x0f + 1.f}, ys[2] = {y0f, y0f + 1.f};
        float wxs[2] = {1.f - fx, fx},  wys[2] = {1.f - fy, fy};
        #pragma unroll
        for (int t = 0; t < 4; ++t) {
            float xf = xs[t & 1], yf = ys[t >> 1];
            bool val = (xf >= 0.f) && (xf <= (float)(W_-1)) &&
                       (yf >= 0.f) && (yf <= (float)(H_-1));
            int xi = (int)fminf(fmaxf(xf, 0.f), (float)(W_-1));
            int yi = (int)fminf(fmaxf(yf, 0.f), (float)(H_-1));
            offp[t] = yi * W_ + xi;
            wt[t] = wxs[t & 1] * wys[t >> 1] * (val ? 1.f : 0.f);
        }
    }
    const float* mb = msk + v * HW_;
    float msample = wt[0]*mb[offp[0]] + wt[1]*mb[offp[1]]
                  + wt[2]*mb[offp[2]] + wt[3]*mb[offp[3]];
    float rv0 = 0.f, rv1 = 0.f, rv2 = 0.f;
    {
        const float* ib = img + (v * 3) * HW_;
        #pragma unroll
        for (int t = 0; t < 4; ++t) {
            rv0 += wt[t] * ib[offp[t]];
            rv1 += wt[t] * ib[HW_ + offp[t]];
            rv2 += wt[t] * ib[2 * HW_ + offp[t]];
        }
    }
    float sdx = cam[v*3+0]-px, sdy = cam[v*3+1]-py, sdz = cam[v*3+2]-pz;
    float snv = sqrtf(sdx*sdx + sdy*sdy + sdz*sdz);
    sdx /= snv; sdy /= snv; sdz /= snv;
    float xx[IND_];
    xx[0] = rv0; xx[1] = rv1; xx[2] = rv2;
    #pragma unroll
    for (int k = 0; k < 32; ++k) {
        const float* fb = fea + (size_t)(v * (2*L_) + FS + k) * HW_;
        xx[3+k] = wt[0]*fb[offp[0]] + wt[1]*fb[offp[1]]
                + wt[2]*fb[offp[2]] + wt[3]*fb[offp[3]];
    }
    xx[35] = sdx; xx[36] = sdy; xx[37] = sdz;
    xx[38] = rdx; xx[39] = rdy; xx[40] = rdz;
    float h1[HID_];
    #pragma unroll
    for (int j = 0; j < HID_; ++j) {
        float a0 = 0.f;
        #pragma unroll
        for (int k = 0; k < IND_; ++k) a0 += xx[k] * W1[k * HID_ + j];
        h1[j] = fmaxf(b1[j] + a0, 0.f);
    }
    float lg = bb[0];
    float A = 0.f, B = 0.f, C = 0.f;
    #pragma unroll 1
    for (int j = 0; j < HID_; j += 4) {
        float hh[4];
        #pragma unroll
        for (int jj = 0; jj < 4; ++jj) {
            float a0 = 0.f;
            #pragma unroll
            for (int k = 0; k < HID_; ++k) a0 += h1[k] * W2[k * HID_ + (j + jj)];
            hh[jj] = fmaxf(b2[j + jj] + a0, 0.f);
        }
        #pragma unroll
        for (int jj = 0; jj < 4; ++jj) {
            float h = hh[jj];
            lg += h * Wb[j + jj];
            A  += h * Wd[j + jj];
            B  += h * h * Wd[HID_ + j + jj];
            float sj = vsum8(h);
            C  += sj * sj * Wd[HID_ + j + jj];
        }
    }
    A = vsum8(A); B = vsum8(B);
    float density = A * 0.125f + B * 0.125f - C * (1.0f / 64.0f) + bd[0];
    float hsv = vsum8(msample);
    bool hull = hsv > ((float)V_ - 0.001f);
    float mx = vmax8(lg);
    float e = expf(lg - mx);
    float es = vsum8(e);
    float br  = vsum8(e * rv0);
    float bg  = vsum8(e * rv1);
    float bbl = vsum8(e * rv2);
    if (v == 0) {
        float is = 1.0f / es;
        odens[P]      = hull ? density  : 0.f;
        orgb[P*3 + 0] = hull ? br  * is : 0.f;
        orgb[P*3 + 1] = hull ? bg  * is : 0.f;
        orgb[P*3 + 2] = hull ? bbl * is : 0.f;
    }
}

// -------------- wave-per-ray coarse composite + sample_pdf + merge-path -------
__global__ __launch_bounds__(256) void k_comp_coarse(const float* __restrict__ ray,
                                                     const float* __restrict__ dens,
                                                     const float* __restrict__ rgb,
                                                     float* __restrict__ out,
                                                     float* __restrict__ fulld) {
    __shared__ float cdfS[4][64];
    __shared__ float fdS[4][64];
    const int wv = threadIdx.x >> 6, lane = threadIdx.x & 63;
    const int r = blockIdx.x * 4 + wv;
    const float nv = ray[r*8+6], fv = ray[r*8+7];
    const int s = lane;

    float d0 = nv + (fv - nv) * ((s + 0.5f) / NC_);
    float d1 = nv + (fv - nv) * ((s + 1.5f) / NC_);
    float delta = (s == NC_-1) ? 1e10f : (d1 - d0);
    float a = 1.f - expf(-fmaxf(dens[r*NC_ + s], 0.f) * delta);
    float qv = 1.f - a + 1e-10f;
    float inc = scan_mul64(qv, lane);
    float trans = __shfl_up(inc, 1, 64);
    if (lane == 0) trans = 1.f;
    float w = a * trans;

    float g0 = rgb[(r*NC_+s)*3+0], g1 = rgb[(r*NC_+s)*3+1], g2 = rgb[(r*NC_+s)*3+2];
    float c0 = redsum64(w * g0);
    float c1 = redsum64(w * g1);
    float c2 = redsum64(w * g2);
    float cd = redsum64(w * d0);
    float ca = redsum64(w);
    if (lane == 0) {
        out[r*3+0] = c0; out[r*3+1] = c1; out[r*3+2] = c2;
        out[3072 + r] = cd;
        out[4096 + r] = ca;
    }

    float pw = (s >= 1 && s <= 62) ? (w + 1e-5f) : 0.f;
    float tot = redsum64(pw);
    float p = pw / tot;
    float ic = scan_add64(p, lane);
    cdfS[wv][lane] = ic;
    __syncthreads();

    float u = (lane + 0.5f) / NF_;
    int lo = 0, hi = 63;
    while (lo < hi) {
        int mid = (lo + hi) >> 1;
        if (cdfS[wv][mid] <= u) lo = mid + 1; else hi = mid;
    }
    int below = lo - 1;
    int above = (lo > 62) ? 62 : lo;
    float cA = cdfS[wv][below], cB = cdfS[wv][above];
    float b0 = nv + (fv - nv) * ((below + 1.0f) / NC_);
    float b1 = nv + (fv - nv) * ((above + 1.0f) / NC_);
    float dnm = cB - cA;
    dnm = (dnm < 1e-5f) ? 1.f : dnm;
    float fdv = b0 + (u - cA) / dnm * (b1 - b0);
    fdS[wv][lane] = fdv;
    __syncthreads();

    lo = 0; hi = 64;
    while (lo < hi) {
        int mid = (lo + hi) >> 1;
        if (fdS[wv][mid] < d0) lo = mid + 1; else hi = mid;
    }
    fulld[r*128 + s + lo] = d0;

    lo = 0; hi = 64;
    while (lo < hi) {
        int mid = (lo + hi) >> 1;
        float daj = nv + (fv - nv) * ((mid + 0.5f) / NC_);
        if (daj <= fdv) lo = mid + 1; else hi = mid;
    }
    fulld[r*128 + lane + lo] = fdv;
}

// ------------------------- wave-per-ray fine composite (2 samples/lane) -------
__global__ __launch_bounds__(256) void k_comp_fine(const float* __restrict__ fulld,
                                                   const float* __restrict__ dens,
                                                   const float* __restrict__ rgb,
                                                   float* __restrict__ out) {
    const int wv = threadIdx.x >> 6, lane = threadIdx.x & 63;
    const int r = blockIdx.x * 4 + wv;
    const int S = NC_ + NF_;
    const float* fl = fulld + r * S;
    const int s0 = 2 * lane, s1 = 2 * lane + 1;

    float f0 = fl[s0], f1 = fl[s1];
    float nx = __shfl_down(f0, 1, 64);
    float dl0 = f1 - f0;
    float dl1 = (lane == 63) ? 1e10f : (nx - f1);
    float a0 = 1.f - expf(-fmaxf(dens[r*S + s0], 0.f) * dl0);
    float a1 = 1.f - expf(-fmaxf(dens[r*S + s1], 0.f) * dl1);
    float q0 = 1.f - a0 + 1e-10f, q1 = 1.f - a1 + 1e-10f;
    float inc = scan_mul64(q0 * q1, lane);
    float E = __shfl_up(inc, 1, 64);
    if (lane == 0) E = 1.f;
    float w0 = a0 * E, w1 = a1 * (E * q0);

    float g00 = rgb[(r*S+s0)*3+0], g01 = rgb[(r*S+s0)*3+1], g02 = rgb[(r*S+s0)*3+2];
    float g10 = rgb[(r*S+s1)*3+0], g11 = rgb[(r*S+s1)*3+1], g12 = rgb[(r*S+s1)*3+2];
    float c0 = redsum64(w0*g00 + w1*g10);
    float c1 = redsum64(w0*g01 + w1*g11);
    float c2 = redsum64(w0*g02 + w1*g12);
    float cd = redsum64(w0*f0 + w1*f1);
    float ca = redsum64(w0 + w1);
    if (lane == 0) {
        out[5120 + r*3+0] = c0; out[5120 + r*3+1] = c1; out[5120 + r*3+2] = c2;
        out[8192 + r] = cd;
        out[9216 + r] = ca;
    }
}

// ------------------------------------------------------------------ launch
extern "C" void kernel_launch(void* const* d_in, const int* in_sizes, int n_in,
                              void* d_out, int out_size, void* d_ws, size_t ws_size,
                              hipStream_t stream) {
    const float* ray = (const float*)d_in[0];
    const float* Kin = (const float*)d_in[1];
    const float* Ein = (const float*)d_in[2];
    const float* cam = (const float*)d_in[3];
    const float* shp = (const float*)d_in[4];
    const float* msk = (const float*)d_in[5];
    const float* img = (const float*)d_in[6];
    const float* fea = (const float*)d_in[7];
    const float* cw[8]; for (int i = 0; i < 8; ++i) cw[i] = (const float*)d_in[8+i];
    const float* fw[8]; for (int i = 0; i < 8; ++i) fw[i] = (const float*)d_in[16+i];

    float* ws    = (float*)d_ws;
    float* Pm    = ws;                        // 96
    unsigned int* FRc = (unsigned int*)(Pm + 96);   // 4096 dwords
    unsigned int* FRf = FRc + 4096;                 // 4096 dwords
    float* cdens = (float*)(FRf + 4096);      // 65536
    float* crgb  = cdens + R_ * NC_;          // 196608
    float* fulld = crgb + R_ * NC_ * 3;       // 131072
    float* fdens = fulld + R_ * (NC_+NF_);    // 131072
    float* frgb  = fdens + R_ * (NC_+NF_);    // 393216
    float* pk    = frgb + R_ * (NC_+NF_) * 3; // V*HW*32

    size_t base_floats = (size_t)(pk - ws);
    size_t need = (base_floats + (size_t)V_ * HW_ * 32 + 64) * sizeof(float);
    bool packed = (ws_size >= need);

    float* outp  = (float*)d_out;

    k_computeP<<<1, 96, 0, stream>>>(Kin, Ein, Pm);

    if (packed) {
        k_packMFMA<<<15, 256, 0, stream>>>(cw[0], cw[1], cw[2], cw[3], cw[4], cw[6], FRc);
        k_packMFMA<<<15, 256, 0, stream>>>(fw[0], fw[1], fw[2], fw[3], fw[4], fw[6], FRf);
        k_packF32<<<dim3(W_/64, H_, V_), 256, 0, stream>>>(fea, pk, 0);

        k_mlp_mfma<NC_, false><<<R_ * NC_ / 32, 256, 0, stream>>>(
            ray, Pm, cam, shp, msk, img, pk, FRc, cw[5], cw[7],
            nullptr, cdens, crgb);

        k_comp_coarse<<<R_ / 4, 256, 0, stream>>>(ray, cdens, crgb, outp, fulld);

        k_packF32<<<dim3(W_/64, H_, V_), 256, 0, stream>>>(fea, pk, L_);

        k_mlp_mfma<NC_ + NF_, true><<<R_ * (NC_+NF_) / 32, 256, 0, stream>>>(
            ray, Pm, cam, shp, msk, img, pk, FRf, fw[5], fw[7],
            fulld, fdens, frgb);

        k_comp_fine<<<R_ / 4, 256, 0, stream>>>(fulld, fdens, frgb, outp);
    } else {
        k_mlp_fb<NC_, 0, false><<<R_ * NC_ * 8 / 256, 256, 0, stream>>>(
            ray, Pm, cam, shp, msk, img, fea,
            cw[0], cw[1], cw[2], cw[3], cw[4], cw[5], cw[6], cw[7],
            nullptr, cdens, crgb);

        k_comp_coarse<<<R_ / 4, 256, 0, stream>>>(ray, cdens, crgb, outp, fulld);

        k_mlp_fb<NC_ + NF_, L_, true><<<R_ * (NC_+NF_) * 8 / 256, 256, 0, stream>>>(
            ray, Pm, cam, shp, msk, img, fea,
            fw[0], fw[1], fw[2], fw[3], fw[4], fw[5], fw[6], fw[7],
            fulld, fdens, frgb);

        k_comp_fine<<<R_ / 4, 256, 0, stream>>>(fulld, fdens, frgb, outp);
    }
}

// Round 11
// 197.409 us; speedup vs baseline: 4.2512x; 1.2805x over previous
//
#include <hip/hip_runtime.h>
#include <hip/hip_bf16.h>
#include <math.h>

#define V_   8
#define H_   256
#define W_   256
#define L_   32
#define HID_ 64
#define NC_  64
#define NF_  64
#define R_   1024
#define IND_ 41              // 3 + 32 + 3 + 3
#define HW_  (H_*W_)

typedef __attribute__((ext_vector_type(8)))  short short8v;
typedef __attribute__((ext_vector_type(16))) float f32x16;

// ---------------- bf16 helpers (RNE) ----------------
__device__ __forceinline__ unsigned int pk2bf(float a, float b) {
    unsigned int ra = (unsigned int)__bfloat16_as_ushort(__float2bfloat16(a));
    unsigned int rb = (unsigned int)__bfloat16_as_ushort(__float2bfloat16(b));
    return ra | (rb << 16);
}

// ---- cross-lane helpers ----
template<int CTRL>
__device__ __forceinline__ float dpp_add(float x) {
    int m = __builtin_amdgcn_mov_dpp(__builtin_bit_cast(int, x), CTRL, 0xF, 0xF, true);
    return x + __builtin_bit_cast(float, m);
}
template<int CTRL>
__device__ __forceinline__ float dpp_max(float x) {
    int m = __builtin_amdgcn_mov_dpp(__builtin_bit_cast(int, x), CTRL, 0xF, 0xF, true);
    return fmaxf(x, __builtin_bit_cast(float, m));
}
__device__ __forceinline__ float vsum8(float x) {
    x = dpp_add<0xB1>(x);
    x = dpp_add<0x4E>(x);
    x += __shfl_xor(x, 4, 64);
    return x;
}
__device__ __forceinline__ float vmax8(float x) {
    x = dpp_max<0xB1>(x);
    x = dpp_max<0x4E>(x);
    x = fmaxf(x, __shfl_xor(x, 4, 64));
    return x;
}
__device__ __forceinline__ float redsum64(float x) {
    #pragma unroll
    for (int off = 32; off >= 1; off >>= 1) x += __shfl_xor(x, off, 64);
    return x;
}
__device__ __forceinline__ float scan_mul64(float x, int lane) {
    #pragma unroll
    for (int off = 1; off < 64; off <<= 1) {
        float y = __shfl_up(x, off, 64);
        x = (lane >= off) ? x * y : x;
    }
    return x;
}
__device__ __forceinline__ float scan_add64(float x, int lane) {
    #pragma unroll
    for (int off = 1; off < 64; off <<= 1) {
        float y = __shfl_up(x, off, 64);
        x = (lane >= off) ? x + y : x;
    }
    return x;
}

// ---------------------------------------------------------------- P = K @ E
__global__ void k_computeP(const float* __restrict__ Km,
                           const float* __restrict__ Em,
                           float* __restrict__ Pm) {
    int t = threadIdx.x;
    if (t >= V_ * 12) return;
    int v = t / 12, e = t - v * 12, row = e >> 2, col = e & 3;
    float acc = 0.f;
    #pragma unroll
    for (int k = 0; k < 3; ++k)
        acc += Km[v * 9 + row * 3 + k] * Em[v * 12 + k * 4 + col];
    Pm[v * 12 + row * 4 + col] = acc;
}

// ---------------- pack weights into MFMA fragment order (bf16) ----------------
__global__ void k_packMFMA(const float* __restrict__ W1, const float* __restrict__ b1,
                           const float* __restrict__ W2, const float* __restrict__ b2,
                           const float* __restrict__ Wd, const float* __restrict__ Wb,
                           unsigned int* __restrict__ out) {
    int t = blockIdx.x * 256 + threadIdx.x;   // 0..3839
    if (t < 1536) {
        int blk = t >> 8, idx = t & 255;
        int mt = blk / 3, kt = blk % 3;
        int l = idx >> 2, rg = idx & 3;
        int hi = l >> 5;
        int j  = 32 * mt + (l & 31);
        int k0 = 16 * kt + 8 * hi + 2 * rg;
        int k1 = k0 + 1;
        float v0 = (k0 < 41) ? W1[k0 * 64 + j] : (k0 == 41 ? b1[j] : 0.f);
        float v1 = (k1 < 41) ? W1[k1 * 64 + j] : (k1 == 41 ? b1[j] : 0.f);
        out[t] = pk2bf(v0, v1);
    } else if (t < 3584) {
        int u = t - 1536;
        int blk = u >> 8, idx = u & 255;
        int l = idx >> 2, rg = idx & 3;
        int hi = l >> 5;
        int j2 = 32 * (blk >> 2) + (l & 31);
        int k0 = 16 * (blk & 3) + 8 * hi + 2 * rg;
        out[t] = pk2bf(W2[k0 * 64 + j2], W2[(k0 + 1) * 64 + j2]);
    } else if (t < 3840) {
        int i = t - 3584;
        int w = i >> 6, mt = (i >> 5) & 1, hi = (i >> 4) & 1, rg = i & 15;
        int j2 = (rg & 3) + 8 * (rg >> 2) + 4 * hi + 32 * mt;
        float v = (w == 0) ? b2[j2] : (w == 1) ? Wb[j2] : (w == 2) ? Wd[j2] : Wd[64 + j2];
        ((float*)out)[t] = v;
    }
}

// ---------- pack mask+rgb+32feat as bf16 rows [V][HW][40 bf16 = 80B] ----------
__global__ __launch_bounds__(256) void k_packB(const float* __restrict__ msk,
                                               const float* __restrict__ img,
                                               const float* __restrict__ fea,
                                               float* __restrict__ pk, int FS) {
    __shared__ unsigned short tile[64][48];   // 96B rows (16B-aligned)
    const int xb = blockIdx.x * 64, y = blockIdx.y, v = blockIdx.z;
    const int t = threadIdx.x;
    const int x = t & 63, cg = t >> 6;
    const size_t px = (size_t)y * W_ + xb + x;
    #pragma unroll
    for (int step = 0; step < 9; ++step) {
        int ch = step * 4 + cg;               // 0..35
        if (ch < 36) {
            float val;
            if (ch == 0)      val = msk[(size_t)v * HW_ + px];
            else if (ch < 4)  val = img[((size_t)(v * 3 + (ch - 1))) * HW_ + px];
            else              val = fea[((size_t)(v * 2 * L_ + FS + (ch - 4))) * HW_ + px];
            tile[x][ch] = __bfloat16_as_ushort(__float2bfloat16(val));
        }
    }
    if (t < 256) { int xi = t >> 2, c = 36 + (t & 3); tile[xi][c] = 0; }
    __syncthreads();
    // write 64 rows x 80B = 640 uint2, coalesced
    uint2* dst = (uint2*)(pk + ((size_t)v * HW_ + (size_t)y * W_ + xb) * 20);
    for (int j = t; j < 640; j += 256) {
        int p = j / 10, sl = j % 10;
        dst[j] = *(const uint2*)&tile[p][sl * 4];
    }
}

// ------------------------------------------------------------- MFMA MLP kernel
// Wave = 8 points x 8 views = 64 ray-rows. Gather reads bf16-packed 80B rows
// (20 uint4 loads/row vs 48 scattered loads). LDS: X [6][64][16B] + H1
// [8][32][16B] = 10KB/wave -> 40KB/block.
template <int S, bool FINE>
__global__ __launch_bounds__(256) void k_mlp_mfma(
    const float* __restrict__ ray, const float* __restrict__ Pm,
    const float* __restrict__ cam, const float* __restrict__ shp,
    const float* __restrict__ pk,
    const unsigned int* __restrict__ FR,
    const float* __restrict__ bd, const float* __restrict__ bb,
    const float* __restrict__ deptharr,
    float* __restrict__ odens, float* __restrict__ orgb) {

    __shared__ __align__(16) char smem[40960];
    const int lane = threadIdx.x & 63;
    const int wv   = threadIdx.x >> 6;
    const int hi   = lane >> 5;
    const int l31  = lane & 31;
    char* Xw  = smem + wv * 10240;
    char* H1w = Xw + 6144;

    const int pbase = (blockIdx.x * 4 + wv) * 8;
    const int P0 = pbase + (lane >> 3);
    const int v  = lane & 7;
    const int r  = P0 / S, s = P0 - r * S;

    const float ox = ray[r*8+0], oy = ray[r*8+1], oz = ray[r*8+2];
    const float dx = ray[r*8+3], dy = ray[r*8+4], dz = ray[r*8+5];
    const float nv = ray[r*8+6], fv = ray[r*8+7];

    float depth;
    if (FINE) depth = deptharr[P0];
    else      depth = nv + (fv - nv) * ((s + 0.5f) / (float)S);

    const float px = ox + dx*depth, py = oy + dy*depth, pz = oz + dz*depth;
    const float dn = sqrtf(dx*dx + dy*dy + dz*dz);
    const float rdx = -dx/dn, rdy = -dy/dn, rdz = -dz/dn;

    const float* Pv = Pm + v * 12;
    float q0 = Pv[0]*px + Pv[1]*py + Pv[2]*pz  + Pv[3];
    float q1 = Pv[4]*px + Pv[5]*py + Pv[6]*pz  + Pv[7];
    float q2 = Pv[8]*px + Pv[9]*py + Pv[10]*pz + Pv[11];
    float inv = 1.0f / (q2 + 1e-6f);
    float uu = q0 * inv, ww = q1 * inv;
    float gx = 2.0f * (uu / shp[v*2+1]) - 1.0f;
    float gy = 2.0f * (ww / shp[v*2+0]) - 1.0f;
    float sx = (gx + 1.0f) * ((float)W_ * 0.5f) - 0.5f;
    float sy = (gy + 1.0f) * ((float)H_ * 0.5f) - 0.5f;
    float x0f = floorf(sx), y0f = floorf(sy);
    float fx = sx - x0f, fy = sy - y0f;

    int offp[4]; float wt[4];
    {
        float xs[2] = {x0f, x0f + 1.f}, ys[2] = {y0f, y0f + 1.f};
        float wxs[2] = {1.f - fx, fx},  wys[2] = {1.f - fy, fy};
        #pragma unroll
        for (int t = 0; t < 4; ++t) {
            float xf = xs[t & 1], yf = ys[t >> 1];
            bool val = (xf >= 0.f) && (xf <= (float)(W_-1)) &&
                       (yf >= 0.f) && (yf <= (float)(H_-1));
            int xi = (int)fminf(fmaxf(xf, 0.f), (float)(W_-1));
            int yi = (int)fminf(fmaxf(yf, 0.f), (float)(H_-1));
            offp[t] = yi * W_ + xi;
            wt[t] = wxs[t & 1] * wys[t >> 1] * (val ? 1.f : 0.f);
        }
    }

    // ---- gather: 4 taps x 5 uint4 of packed bf16 [m, rgb, feat0..31] ----
    float vals[40];
    #pragma unroll
    for (int i = 0; i < 40; ++i) vals[i] = 0.f;
    #pragma unroll
    for (int t = 0; t < 4; ++t) {
        const uint4* fp = (const uint4*)pk + ((size_t)v * HW_ + offp[t]) * 5;
        float wtt = wt[t];
        #pragma unroll
        for (int s5 = 0; s5 < 5; ++s5) {
            uint4 q = fp[s5];
            unsigned int dw[4] = {q.x, q.y, q.z, q.w};
            #pragma unroll
            for (int e = 0; e < 4; ++e) {
                int i = s5 * 8 + e * 2;
                vals[i]   += wtt * __uint_as_float(dw[e] << 16);
                vals[i+1] += wtt * __uint_as_float(dw[e] & 0xFFFF0000u);
            }
        }
    }
    float msample = vals[0];
    float rv0 = vals[1], rv1 = vals[2], rv2 = vals[3];
    float sdx = cam[v*3+0]-px, sdy = cam[v*3+1]-py, sdz = cam[v*3+2]-pz;
    float snv = sqrtf(sdx*sdx + sdy*sdy + sdz*sdz);
    sdx /= snv; sdy /= snv; sdz /= snv;

    float xx[42];
    xx[0] = rv0; xx[1] = rv1; xx[2] = rv2;
    #pragma unroll
    for (int k = 0; k < 32; ++k) xx[3+k] = vals[4+k];
    xx[35] = sdx; xx[36] = sdy; xx[37] = sdz;
    xx[38] = rdx; xx[39] = rdy; xx[40] = rdz;
    xx[41] = 1.0f;

    // ---- write X row: slot-major, coalesced ----
    {
        unsigned int d[24];
        #pragma unroll
        for (int i = 0; i < 21; ++i) d[i] = pk2bf(xx[2*i], xx[2*i+1]);
        d[21] = 0u; d[22] = 0u; d[23] = 0u;
        #pragma unroll
        for (int o = 0; o < 6; ++o)
            *(uint4*)(Xw + o * 1024 + lane * 16) =
                make_uint4(d[o*4], d[o*4+1], d[o*4+2], d[o*4+3]);
    }

    // ---- preload layer-1 weight A-frags (layer-2 loaded lazily per nt) ----
    short8v aw1[6];
    #pragma unroll
    for (int i = 0; i < 6; ++i)
        aw1[i] = __builtin_bit_cast(short8v, ((const uint4*)FR)[i * 64 + lane]);
    const float4* PL4 = (const float4*)(FR + 3584);
    const float bdv = bd[0], bbv = bb[0];

    float hs = vsum8(msample);
    float hssw  = __shfl_xor(hs, 32, 64);
    float rv0sw = __shfl_xor(rv0, 32, 64);
    float rv1sw = __shfl_xor(rv1, 32, 64);
    float rv2sw = __shfl_xor(rv2, 32, 64);

    #pragma unroll
    for (int nt = 0; nt < 2; ++nt) {
        const int n = nt * 32 + l31;
        // ---- layer 1: H1^T = W1T @ X^T ----
        f32x16 acc1[2];
        #pragma unroll
        for (int mt = 0; mt < 2; ++mt)
            #pragma unroll
            for (int q = 0; q < 16; ++q) acc1[mt][q] = 0.f;
        #pragma unroll
        for (int kt = 0; kt < 3; ++kt) {
            uint4 bu = *(const uint4*)(Xw + (2*kt + hi) * 1024 + n * 16);
            short8v b = __builtin_bit_cast(short8v, bu);
            acc1[0] = __builtin_amdgcn_mfma_f32_32x32x16_bf16(aw1[kt],     b, acc1[0], 0, 0, 0);
            acc1[1] = __builtin_amdgcn_mfma_f32_32x32x16_bf16(aw1[3 + kt], b, acc1[1], 0, 0, 0);
        }
        #pragma unroll
        for (int mt = 0; mt < 2; ++mt)
            #pragma unroll
            for (int q = 0; q < 4; ++q) {
                unsigned int w0 = pk2bf(fmaxf(acc1[mt][4*q+0], 0.f),
                                        fmaxf(acc1[mt][4*q+1], 0.f));
                unsigned int w1 = pk2bf(fmaxf(acc1[mt][4*q+2], 0.f),
                                        fmaxf(acc1[mt][4*q+3], 0.f));
                *(uint2*)(H1w + (q + 4*mt) * 512 + l31 * 16 + hi * 8) = make_uint2(w0, w1);
            }
        // ---- layer 2 (lazy A-frag load; bias via C-init) ----
        short8v aw2[8];
        #pragma unroll
        for (int i = 0; i < 8; ++i)
            aw2[i] = __builtin_bit_cast(short8v, ((const uint4*)(FR + 1536))[i * 64 + lane]);
        f32x16 acc2[2];
        #pragma unroll
        for (int mt = 0; mt < 2; ++mt)
            #pragma unroll
            for (int q4 = 0; q4 < 4; ++q4) {
                float4 c = PL4[(mt*2 + hi)*4 + q4];
                acc2[mt][4*q4+0] = c.x; acc2[mt][4*q4+1] = c.y;
                acc2[mt][4*q4+2] = c.z; acc2[mt][4*q4+3] = c.w;
            }
        #pragma unroll
        for (int kt = 0; kt < 4; ++kt) {
            uint4 bu = *(const uint4*)(H1w + (2*kt + hi) * 512 + l31 * 16);
            short8v b = __builtin_bit_cast(short8v, bu);
            acc2[0] = __builtin_amdgcn_mfma_f32_32x32x16_bf16(aw2[kt],     b, acc2[0], 0, 0, 0);
            acc2[1] = __builtin_amdgcn_mfma_f32_32x32x16_bf16(aw2[4 + kt], b, acc2[1], 0, 0, 0);
        }

        // ---- pooling ----
        float lgp = 0.f, dacc = 0.f, cacc = 0.f;
        #pragma unroll
        for (int mt = 0; mt < 2; ++mt)
            #pragma unroll
            for (int q4 = 0; q4 < 4; ++q4) {
                float4 wb4 = PL4[16 + (mt*2 + hi)*4 + q4];
                float4 wd4 = PL4[32 + (mt*2 + hi)*4 + q4];
                float4 w24 = PL4[48 + (mt*2 + hi)*4 + q4];
                #pragma unroll
                for (int e = 0; e < 4; ++e) {
                    float hv = fmaxf(acc2[mt][4*q4+e], 0.f);
                    float wbv = (e==0)?wb4.x:(e==1)?wb4.y:(e==2)?wb4.z:wb4.w;
                    float wdv = (e==0)?wd4.x:(e==1)?wd4.y:(e==2)?wd4.z:wd4.w;
                    float w2v = (e==0)?w24.x:(e==1)?w24.y:(e==2)?w24.z:w24.w;
                    lgp  += hv * wbv;
                    dacc += hv * wdv + hv * hv * w2v;
                    float sj = vsum8(hv);
                    cacc += sj * sj * w2v;
                }
            }
        float lg = lgp + __shfl_xor(lgp, 32, 64) + bbv;
        dacc += __shfl_xor(dacc, 32, 64);
        dacc  = vsum8(dacc);
        cacc += __shfl_xor(cacc, 32, 64);
        float density = dacc * 0.125f - cacc * (1.0f / 64.0f) + bdv;

        float mx = vmax8(lg);
        float e  = expf(lg - mx);
        float es = vsum8(e);
        float r0c = (hi == nt) ? rv0 : rv0sw;
        float r1c = (hi == nt) ? rv1 : rv1sw;
        float r2c = (hi == nt) ? rv2 : rv2sw;
        float br  = vsum8(e * r0c);
        float bg  = vsum8(e * r1c);
        float bbl = vsum8(e * r2c);
        float hn  = (nt == 0) ? hs : hssw;
        bool hull = hn > ((float)V_ - 0.001f);

        if ((lane & 0x27) == 0) {
            int PP = pbase + 4 * nt + (lane >> 3);
            float is = 1.0f / es;
            odens[PP]      = hull ? density  : 0.f;
            orgb[PP*3 + 0] = hull ? br  * is : 0.f;
            orgb[PP*3 + 1] = hull ? bg  * is : 0.f;
            orgb[PP*3 + 2] = hull ? bbl * is : 0.f;
        }
    }
}

// ---------------------- fallback (unpacked ws): scalar kernel ----------
template <int S, int FS, bool FINE>
__global__ __launch_bounds__(256, 2) void k_mlp_fb(
    const float* __restrict__ ray, const float* __restrict__ Pm,
    const float* __restrict__ cam, const float* __restrict__ shp,
    const float* __restrict__ msk, const float* __restrict__ img,
    const float* __restrict__ fea,
    const float* __restrict__ W1, const float* __restrict__ b1,
    const float* __restrict__ W2, const float* __restrict__ b2,
    const float* __restrict__ Wd, const float* __restrict__ bd,
    const float* __restrict__ Wb, const float* __restrict__ bb,
    const float* __restrict__ deptharr,
    float* __restrict__ odens, float* __restrict__ orgb) {

    const int tid = blockIdx.x * 256 + threadIdx.x;
    const int v   = tid & 7;
    const int P   = tid >> 3;
    const int r   = P / S, s = P - r * S;

    const float ox = ray[r*8+0], oy = ray[r*8+1], oz = ray[r*8+2];
    const float dx = ray[r*8+3], dy = ray[r*8+4], dz = ray[r*8+5];
    const float nv = ray[r*8+6], fv = ray[r*8+7];
    float depth;
    if (FINE) depth = deptharr[P];
    else      depth = nv + (fv - nv) * ((s + 0.5f) / (float)S);
    const float px = ox + dx*depth, py = oy + dy*depth, pz = oz + dz*depth;
    const float dn = sqrtf(dx*dx + dy*dy + dz*dz);
    const float rdx = -dx/dn, rdy = -dy/dn, rdz = -dz/dn;
    const float* Pv = Pm + v * 12;
    float q0 = Pv[0]*px + Pv[1]*py + Pv[2]*pz  + Pv[3];
    float q1 = Pv[4]*px + Pv[5]*py + Pv[6]*pz  + Pv[7];
    float q2 = Pv[8]*px + Pv[9]*py + Pv[10]*pz + Pv[11];
    float inv = 1.0f / (q2 + 1e-6f);
    float uu = q0 * inv, ww = q1 * inv;
    float gx = 2.0f * (uu / shp[v*2+1]) - 1.0f;
    float gy = 2.0f * (ww / shp[v*2+0]) - 1.0f;
    float sx = (gx + 1.0f) * ((float)W_ * 0.5f) - 0.5f;
    float sy = (gy + 1.0f) * ((float)H_ * 0.5f) - 0.5f;
    float x0f = floorf(sx), y0f = floorf(sy);
    float fx = sx - x0f, fy = sy - y0f;
    int offp[4]; float wt[4];
    {
        float xs[2] = {x0f, x0f + 1.f}, ys[2] = {y0f, y0f + 1.f};
        float wxs[2] = {1.f - fx, fx},  wys[2] = {1.f - fy, fy};
        #pragma unroll
        for (int t = 0; t < 4; ++t) {
            float xf = xs[t & 1], yf = ys[t >> 1];
            bool val = (xf >= 0.f) && (xf <= (float)(W_-1)) &&
                       (yf >= 0.f) && (yf <= (float)(H_-1));
            int xi = (int)fminf(fmaxf(xf, 0.f), (float)(W_-1));
            int yi = (int)fminf(fmaxf(yf, 0.f), (float)(H_-1));
            offp[t] = yi * W_ + xi;
            wt[t] = wxs[t & 1] * wys[t >> 1] * (val ? 1.f : 0.f);
        }
    }
    const float* mb = msk + v * HW_;
    float msample = wt[0]*mb[offp[0]] + wt[1]*mb[offp[1]]
                  + wt[2]*mb[offp[2]] + wt[3]*mb[offp[3]];
    float rv0 = 0.f, rv1 = 0.f, rv2 = 0.f;
    {
        const float* ib = img + (v * 3) * HW_;
        #pragma unroll
        for (int t = 0; t < 4; ++t) {
            rv0 += wt[t] * ib[offp[t]];
            rv1 += wt[t] * ib[HW_ + offp[t]];
            rv2 += wt[t] * ib[2 * HW_ + offp[t]];
        }
    }
    float sdx = cam[v*3+0]-px, sdy = cam[v*3+1]-py, sdz = cam[v*3+2]-pz;
    float snv = sqrtf(sdx*sdx + sdy*sdy + sdz*sdz);
    sdx /= snv; sdy /= snv; sdz /= snv;
    float xx[IND_];
    xx[0] = rv0; xx[1] = rv1; xx[2] = rv2;
    #pragma unroll
    for (int k = 0; k < 32; ++k) {
        const float* fb = fea + (size_t)(v * (2*L_) + FS + k) * HW_;
        xx[3+k] = wt[0]*fb[offp[0]] + wt[1]*fb[offp[1]]
                + wt[2]*fb[offp[2]] + wt[3]*fb[offp[3]];
    }
    xx[35] = sdx; xx[36] = sdy; xx[37] = sdz;
    xx[38] = rdx; xx[39] = rdy; xx[40] = rdz;
    float h1[HID_];
    #pragma unroll
    for (int j = 0; j < HID_; ++j) {
        float a0 = 0.f;
        #pragma unroll
        for (int k = 0; k < IND_; ++k) a0 += xx[k] * W1[k * HID_ + j];
        h1[j] = fmaxf(b1[j] + a0, 0.f);
    }
    float lg = bb[0];
    float A = 0.f, B = 0.f, C = 0.f;
    #pragma unroll 1
    for (int j = 0; j < HID_; j += 4) {
        float hh[4];
        #pragma unroll
        for (int jj = 0; jj < 4; ++jj) {
            float a0 = 0.f;
            #pragma unroll
            for (int k = 0; k < HID_; ++k) a0 += h1[k] * W2[k * HID_ + (j + jj)];
            hh[jj] = fmaxf(b2[j + jj] + a0, 0.f);
        }
        #pragma unroll
        for (int jj = 0; jj < 4; ++jj) {
            float h = hh[jj];
            lg += h * Wb[j + jj];
            A  += h * Wd[j + jj];
            B  += h * h * Wd[HID_ + j + jj];
            float sj = vsum8(h);
            C  += sj * sj * Wd[HID_ + j + jj];
        }
    }
    A = vsum8(A); B = vsum8(B);
    float density = A * 0.125f + B * 0.125f - C * (1.0f / 64.0f) + bd[0];
    float hsv = vsum8(msample);
    bool hull = hsv > ((float)V_ - 0.001f);
    float mx = vmax8(lg);
    float e = expf(lg - mx);
    float es = vsum8(e);
    float br  = vsum8(e * rv0);
    float bg  = vsum8(e * rv1);
    float bbl = vsum8(e * rv2);
    if (v == 0) {
        float is = 1.0f / es;
        odens[P]      = hull ? density  : 0.f;
        orgb[P*3 + 0] = hull ? br  * is : 0.f;
        orgb[P*3 + 1] = hull ? bg  * is : 0.f;
        orgb[P*3 + 2] = hull ? bbl * is : 0.f;
    }
}

// -------------- wave-per-ray coarse composite + sample_pdf + merge-path -------
__global__ __launch_bounds__(256) void k_comp_coarse(const float* __restrict__ ray,
                                                     const float* __restrict__ dens,
                                                     const float* __restrict__ rgb,
                                                     float* __restrict__ out,
                                                     float* __restrict__ fulld) {
    __shared__ float cdfS[4][64];
    __shared__ float fdS[4][64];
    const int wv = threadIdx.x >> 6, lane = threadIdx.x & 63;
    const int r = blockIdx.x * 4 + wv;
    const float nv = ray[r*8+6], fv = ray[r*8+7];
    const int s = lane;

    float d0 = nv + (fv - nv) * ((s + 0.5f) / NC_);
    float d1 = nv + (fv - nv) * ((s + 1.5f) / NC_);
    float delta = (s == NC_-1) ? 1e10f : (d1 - d0);
    float a = 1.f - expf(-fmaxf(dens[r*NC_ + s], 0.f) * delta);
    float qv = 1.f - a + 1e-10f;
    float inc = scan_mul64(qv, lane);
    float trans = __shfl_up(inc, 1, 64);
    if (lane == 0) trans = 1.f;
    float w = a * trans;

    float g0 = rgb[(r*NC_+s)*3+0], g1 = rgb[(r*NC_+s)*3+1], g2 = rgb[(r*NC_+s)*3+2];
    float c0 = redsum64(w * g0);
    float c1 = redsum64(w * g1);
    float c2 = redsum64(w * g2);
    float cd = redsum64(w * d0);
    float ca = redsum64(w);
    if (lane == 0) {
        out[r*3+0] = c0; out[r*3+1] = c1; out[r*3+2] = c2;
        out[3072 + r] = cd;
        out[4096 + r] = ca;
    }

    float pw = (s >= 1 && s <= 62) ? (w + 1e-5f) : 0.f;
    float tot = redsum64(pw);
    float p = pw / tot;
    float ic = scan_add64(p, lane);
    cdfS[wv][lane] = ic;
    __syncthreads();

    float u = (lane + 0.5f) / NF_;
    int lo = 0, hi = 63;
    while (lo < hi) {
        int mid = (lo + hi) >> 1;
        if (cdfS[wv][mid] <= u) lo = mid + 1; else hi = mid;
    }
    int below = lo - 1;
    int above = (lo > 62) ? 62 : lo;
    float cA = cdfS[wv][below], cB = cdfS[wv][above];
    float b0 = nv + (fv - nv) * ((below + 1.0f) / NC_);
    float b1 = nv + (fv - nv) * ((above + 1.0f) / NC_);
    float dnm = cB - cA;
    dnm = (dnm < 1e-5f) ? 1.f : dnm;
    float fdv = b0 + (u - cA) / dnm * (b1 - b0);
    fdS[wv][lane] = fdv;
    __syncthreads();

    lo = 0; hi = 64;
    while (lo < hi) {
        int mid = (lo + hi) >> 1;
        if (fdS[wv][mid] < d0) lo = mid + 1; else hi = mid;
    }
    fulld[r*128 + s + lo] = d0;

    lo = 0; hi = 64;
    while (lo < hi) {
        int mid = (lo + hi) >> 1;
        float daj = nv + (fv - nv) * ((mid + 0.5f) / NC_);
        if (daj <= fdv) lo = mid + 1; else hi = mid;
    }
    fulld[r*128 + lane + lo] = fdv;
}

// ------------------------- wave-per-ray fine composite (2 samples/lane) -------
__global__ __launch_bounds__(256) void k_comp_fine(const float* __restrict__ fulld,
                                                   const float* __restrict__ dens,
                                                   const float* __restrict__ rgb,
                                                   float* __restrict__ out) {
    const int wv = threadIdx.x >> 6, lane = threadIdx.x & 63;
    const int r = blockIdx.x * 4 + wv;
    const int S = NC_ + NF_;
    const float* fl = fulld + r * S;
    const int s0 = 2 * lane, s1 = 2 * lane + 1;

    float f0 = fl[s0], f1 = fl[s1];
    float nx = __shfl_down(f0, 1, 64);
    float dl0 = f1 - f0;
    float dl1 = (lane == 63) ? 1e10f : (nx - f1);
    float a0 = 1.f - expf(-fmaxf(dens[r*S + s0], 0.f) * dl0);
    float a1 = 1.f - expf(-fmaxf(dens[r*S + s1], 0.f) * dl1);
    float q0 = 1.f - a0 + 1e-10f, q1 = 1.f - a1 + 1e-10f;
    float inc = scan_mul64(q0 * q1, lane);
    float E = __shfl_up(inc, 1, 64);
    if (lane == 0) E = 1.f;
    float w0 = a0 * E, w1 = a1 * (E * q0);

    float g00 = rgb[(r*S+s0)*3+0], g01 = rgb[(r*S+s0)*3+1], g02 = rgb[(r*S+s0)*3+2];
    float g10 = rgb[(r*S+s1)*3+0], g11 = rgb[(r*S+s1)*3+1], g12 = rgb[(r*S+s1)*3+2];
    float c0 = redsum64(w0*g00 + w1*g10);
    float c1 = redsum64(w0*g01 + w1*g11);
    float c2 = redsum64(w0*g02 + w1*g12);
    float cd = redsum64(w0*f0 + w1*f1);
    float ca = redsum64(w0 + w1);
    if (lane == 0) {
        out[5120 + r*3+0] = c0; out[5120 + r*3+1] = c1; out[5120 + r*3+2] = c2;
        out[8192 + r] = cd;
        out[9216 + r] = ca;
    }
}

// ------------------------------------------------------------------ launch
extern "C" void kernel_launch(void* const* d_in, const int* in_sizes, int n_in,
                              void* d_out, int out_size, void* d_ws, size_t ws_size,
                              hipStream_t stream) {
    const float* ray = (const float*)d_in[0];
    const float* Kin = (const float*)d_in[1];
    const float* Ein = (const float*)d_in[2];
    const float* cam = (const float*)d_in[3];
    const float* shp = (const float*)d_in[4];
    const float* msk = (const float*)d_in[5];
    const float* img = (const float*)d_in[6];
    const float* fea = (const float*)d_in[7];
    const float* cw[8]; for (int i = 0; i < 8; ++i) cw[i] = (const float*)d_in[8+i];
    const float* fw[8]; for (int i = 0; i < 8; ++i) fw[i] = (const float*)d_in[16+i];

    float* ws    = (float*)d_ws;
    float* Pm    = ws;                        // 96
    unsigned int* FRc = (unsigned int*)(Pm + 96);   // 4096 dwords
    unsigned int* FRf = FRc + 4096;                 // 4096 dwords
    float* cdens = (float*)(FRf + 4096);      // 65536
    float* crgb  = cdens + R_ * NC_;          // 196608
    float* fulld = crgb + R_ * NC_ * 3;       // 131072
    float* fdens = fulld + R_ * (NC_+NF_);    // 131072
    float* frgb  = fdens + R_ * (NC_+NF_);    // 393216
    float* pk    = frgb + R_ * (NC_+NF_) * 3; // V*HW*20 floats (80B bf16 rows)

    size_t base_floats = (size_t)(pk - ws);
    size_t need = (base_floats + (size_t)V_ * HW_ * 20 + 64) * sizeof(float);
    bool packed = (ws_size >= need);

    float* outp  = (float*)d_out;

    k_computeP<<<1, 96, 0, stream>>>(Kin, Ein, Pm);

    if (packed) {
        k_packMFMA<<<15, 256, 0, stream>>>(cw[0], cw[1], cw[2], cw[3], cw[4], cw[6], FRc);
        k_packMFMA<<<15, 256, 0, stream>>>(fw[0], fw[1], fw[2], fw[3], fw[4], fw[6], FRf);
        k_packB<<<dim3(W_/64, H_, V_), 256, 0, stream>>>(msk, img, fea, pk, 0);

        k_mlp_mfma<NC_, false><<<R_ * NC_ / 32, 256, 0, stream>>>(
            ray, Pm, cam, shp, pk, FRc, cw[5], cw[7],
            nullptr, cdens, crgb);

        k_comp_coarse<<<R_ / 4, 256, 0, stream>>>(ray, cdens, crgb, outp, fulld);

        k_packB<<<dim3(W_/64, H_, V_), 256, 0, stream>>>(msk, img, fea, pk, L_);

        k_mlp_mfma<NC_ + NF_, true><<<R_ * (NC_+NF_) / 32, 256, 0, stream>>>(
            ray, Pm, cam, shp, pk, FRf, fw[5], fw[7],
            fulld, fdens, frgb);

        k_comp_fine<<<R_ / 4, 256, 0, stream>>>(fulld, fdens, frgb, outp);
    } else {
        k_mlp_fb<NC_, 0, false><<<R_ * NC_ * 8 / 256, 256, 0, stream>>>(
            ray, Pm, cam, shp, msk, img, fea,
            cw[0], cw[1], cw[2], cw[3], cw[4], cw[5], cw[6], cw[7],
            nullptr, cdens, crgb);

        k_comp_coarse<<<R_ / 4, 256, 0, stream>>>(ray, cdens, crgb, outp, fulld);

        k_mlp_fb<NC_ + NF_, L_, true><<<R_ * (NC_+NF_) * 8 / 256, 256, 0, stream>>>(
            ray, Pm, cam, shp, msk, img, fea,
            fw[0], fw[1], fw[2], fw[3], fw[4], fw[5], fw[6], fw[7],
            fulld, fdens, frgb);

        k_comp_fine<<<R_ / 4, 256, 0, stream>>>(fulld, fdens, frgb, outp);
    }
}

// Round 12
// 192.969 us; speedup vs baseline: 4.3491x; 1.0230x over previous
//
#include <hip/hip_runtime.h>
#include <hip/hip_bf16.h>
#include <math.h>

#define V_   8
#define H_   256
#define W_   256
#define L_   32
#define HID_ 64
#define NC_  64
#define NF_  64
#define R_   1024
#define IND_ 41              // 3 + 32 + 3 + 3
#define HW_  (H_*W_)

typedef __attribute__((ext_vector_type(8)))  short short8v;
typedef __attribute__((ext_vector_type(16))) float f32x16;

// ---------------- bf16 helpers (RNE) ----------------
__device__ __forceinline__ unsigned int pk2bf(float a, float b) {
    unsigned int ra = (unsigned int)__bfloat16_as_ushort(__float2bfloat16(a));
    unsigned int rb = (unsigned int)__bfloat16_as_ushort(__float2bfloat16(b));
    return ra | (rb << 16);
}

// ---- cross-lane helpers ----
template<int CTRL>
__device__ __forceinline__ float dpp_add(float x) {
    int m = __builtin_amdgcn_mov_dpp(__builtin_bit_cast(int, x), CTRL, 0xF, 0xF, true);
    return x + __builtin_bit_cast(float, m);
}
template<int CTRL>
__device__ __forceinline__ float dpp_max(float x) {
    int m = __builtin_amdgcn_mov_dpp(__builtin_bit_cast(int, x), CTRL, 0xF, 0xF, true);
    return fmaxf(x, __builtin_bit_cast(float, m));
}
__device__ __forceinline__ float swz_xor4(float x) {
    int m = __builtin_amdgcn_ds_swizzle(__builtin_bit_cast(int, x), 0x101F); // lane^4
    return __builtin_bit_cast(float, m);
}
__device__ __forceinline__ float vsum8(float x) {
    x = dpp_add<0xB1>(x);            // xor 1 (quad_perm, VALU)
    x = dpp_add<0x4E>(x);            // xor 2 (quad_perm, VALU)
    x += swz_xor4(x);                // xor 4 (single ds_swizzle)
    return x;
}
__device__ __forceinline__ float vmax8(float x) {
    x = dpp_max<0xB1>(x);
    x = dpp_max<0x4E>(x);
    x = fmaxf(x, swz_xor4(x));
    return x;
}
__device__ __forceinline__ float redsum64(float x) {
    #pragma unroll
    for (int off = 32; off >= 1; off >>= 1) x += __shfl_xor(x, off, 64);
    return x;
}
__device__ __forceinline__ float scan_mul64(float x, int lane) {
    #pragma unroll
    for (int off = 1; off < 64; off <<= 1) {
        float y = __shfl_up(x, off, 64);
        x = (lane >= off) ? x * y : x;
    }
    return x;
}
__device__ __forceinline__ float scan_add64(float x, int lane) {
    #pragma unroll
    for (int off = 1; off < 64; off <<= 1) {
        float y = __shfl_up(x, off, 64);
        x = (lane >= off) ? x + y : x;
    }
    return x;
}

// ---------------- packMFMA body (fragment-order weights, bf16) ----------------
__device__ __forceinline__ void packMFMA_body(
    int t, const float* __restrict__ W1, const float* __restrict__ b1,
    const float* __restrict__ W2, const float* __restrict__ b2,
    const float* __restrict__ Wd, const float* __restrict__ Wb,
    unsigned int* __restrict__ out) {
    if (t < 1536) {
        int blk = t >> 8, idx = t & 255;
        int mt = blk / 3, kt = blk % 3;
        int l = idx >> 2, rg = idx & 3;
        int hi = l >> 5;
        int j  = 32 * mt + (l & 31);
        int k0 = 16 * kt + 8 * hi + 2 * rg;
        int k1 = k0 + 1;
        float v0 = (k0 < 41) ? W1[k0 * 64 + j] : (k0 == 41 ? b1[j] : 0.f);
        float v1 = (k1 < 41) ? W1[k1 * 64 + j] : (k1 == 41 ? b1[j] : 0.f);
        out[t] = pk2bf(v0, v1);
    } else if (t < 3584) {
        int u = t - 1536;
        int blk = u >> 8, idx = u & 255;
        int l = idx >> 2, rg = idx & 3;
        int hi = l >> 5;
        int j2 = 32 * (blk >> 2) + (l & 31);
        int k0 = 16 * (blk & 3) + 8 * hi + 2 * rg;
        out[t] = pk2bf(W2[k0 * 64 + j2], W2[(k0 + 1) * 64 + j2]);
    } else if (t < 3840) {
        int i = t - 3584;
        int w = i >> 6, mt = (i >> 5) & 1, hi = (i >> 4) & 1, rg = i & 15;
        int j2 = (rg & 3) + 8 * (rg >> 2) + 4 * hi + 32 * mt;
        float v = (w == 0) ? b2[j2] : (w == 1) ? Wb[j2] : (w == 2) ? Wd[j2] : Wd[64 + j2];
        ((float*)out)[t] = v;
    }
}

// ------------- merged init: P = K@E + coarse/fine weight fragment packs -------
__global__ __launch_bounds__(256) void k_init(
    const float* __restrict__ Km, const float* __restrict__ Em, float* __restrict__ Pm,
    const float* __restrict__ cW1, const float* __restrict__ cb1,
    const float* __restrict__ cW2, const float* __restrict__ cb2,
    const float* __restrict__ cWd, const float* __restrict__ cWb,
    unsigned int* __restrict__ FRc,
    const float* __restrict__ fW1, const float* __restrict__ fb1,
    const float* __restrict__ fW2, const float* __restrict__ fb2,
    const float* __restrict__ fWd, const float* __restrict__ fWb,
    unsigned int* __restrict__ FRf) {
    const int bid = blockIdx.x, tid = threadIdx.x;
    if (bid == 0) {
        if (tid >= V_ * 12) return;
        int v = tid / 12, e = tid - v * 12, row = e >> 2, col = e & 3;
        float acc = 0.f;
        #pragma unroll
        for (int k = 0; k < 3; ++k)
            acc += Km[v * 9 + row * 3 + k] * Em[v * 12 + k * 4 + col];
        Pm[v * 12 + row * 4 + col] = acc;
    } else if (bid <= 15) {
        packMFMA_body((bid - 1) * 256 + tid, cW1, cb1, cW2, cb2, cWd, cWb, FRc);
    } else if (bid <= 30) {
        packMFMA_body((bid - 16) * 256 + tid, fW1, fb1, fW2, fb2, fWd, fWb, FRf);
    }
}

// ------ pack BOTH passes: 160B rows [m,rgb,f0..31 | m,rgb,f32..63] bf16 -------
__global__ __launch_bounds__(256) void k_packB2(const float* __restrict__ msk,
                                                const float* __restrict__ img,
                                                const float* __restrict__ fea,
                                                float* __restrict__ pk) {
    __shared__ unsigned short tile[64][80];
    const int xb = blockIdx.x * 64, y = blockIdx.y, v = blockIdx.z;
    const int t = threadIdx.x;
    const int x = t & 63, cg = t >> 6;
    const size_t px = (size_t)y * W_ + xb + x;
    #pragma unroll
    for (int step = 0; step < 17; ++step) {
        int ch = step * 4 + cg;               // 0..67
        if (ch < 68) {
            float val;
            if (ch == 0)      val = msk[(size_t)v * HW_ + px];
            else if (ch < 4)  val = img[((size_t)(v * 3 + (ch - 1))) * HW_ + px];
            else              val = fea[((size_t)(v * 2 * L_ + (ch - 4))) * HW_ + px];
            unsigned short bf = __bfloat16_as_ushort(__float2bfloat16(val));
            if (ch == 0)      { tile[x][0] = bf; tile[x][40] = bf; }
            else if (ch < 4)  { tile[x][ch] = bf; tile[x][40 + ch] = bf; }
            else if (ch < 36) { tile[x][ch] = bf; }
            else              { tile[x][ch + 8] = bf; }   // f32..63 -> 44..75
        }
    }
    if (t < 256) {
        int xi = t >> 2, c = t & 3;
        tile[xi][36 + c] = 0;
        tile[xi][76 + c] = 0;
    }
    __syncthreads();
    uint2* dst = (uint2*)(pk + ((size_t)v * HW_ + (size_t)y * W_ + xb) * 40);
    for (int j = t; j < 1280; j += 256) {
        int p = j / 20, sl = j % 20;
        dst[j] = *(const uint2*)&tile[p][sl * 4];
    }
}

// ------------------------------------------------------------- MFMA MLP kernel
// Wave = 8 points x 8 views. GOFF = uint4 offset into the 160B packed row
// (0 = coarse half, 5 = fine half).
template <int S, bool FINE, int GOFF>
__global__ __launch_bounds__(256) void k_mlp_mfma(
    const float* __restrict__ ray, const float* __restrict__ Pm,
    const float* __restrict__ cam, const float* __restrict__ shp,
    const float* __restrict__ pk,
    const unsigned int* __restrict__ FR,
    const float* __restrict__ bd, const float* __restrict__ bb,
    const float* __restrict__ deptharr,
    float* __restrict__ odens, float* __restrict__ orgb) {

    __shared__ __align__(16) char smem[40960];
    const int lane = threadIdx.x & 63;
    const int wv   = threadIdx.x >> 6;
    const int hi   = lane >> 5;
    const int l31  = lane & 31;
    char* Xw  = smem + wv * 10240;
    char* H1w = Xw + 6144;

    const int pbase = (blockIdx.x * 4 + wv) * 8;
    const int P0 = pbase + (lane >> 3);
    const int v  = lane & 7;
    const int r  = P0 / S, s = P0 - r * S;

    const float ox = ray[r*8+0], oy = ray[r*8+1], oz = ray[r*8+2];
    const float dx = ray[r*8+3], dy = ray[r*8+4], dz = ray[r*8+5];
    const float nv = ray[r*8+6], fv = ray[r*8+7];

    float depth;
    if (FINE) depth = deptharr[P0];
    else      depth = nv + (fv - nv) * ((s + 0.5f) / (float)S);

    const float px = ox + dx*depth, py = oy + dy*depth, pz = oz + dz*depth;
    const float dn = sqrtf(dx*dx + dy*dy + dz*dz);
    const float rdx = -dx/dn, rdy = -dy/dn, rdz = -dz/dn;

    const float* Pv = Pm + v * 12;
    float q0 = Pv[0]*px + Pv[1]*py + Pv[2]*pz  + Pv[3];
    float q1 = Pv[4]*px + Pv[5]*py + Pv[6]*pz  + Pv[7];
    float q2 = Pv[8]*px + Pv[9]*py + Pv[10]*pz + Pv[11];
    float inv = 1.0f / (q2 + 1e-6f);
    float uu = q0 * inv, ww = q1 * inv;
    float gx = 2.0f * (uu / shp[v*2+1]) - 1.0f;
    float gy = 2.0f * (ww / shp[v*2+0]) - 1.0f;
    float sx = (gx + 1.0f) * ((float)W_ * 0.5f) - 0.5f;
    float sy = (gy + 1.0f) * ((float)H_ * 0.5f) - 0.5f;
    float x0f = floorf(sx), y0f = floorf(sy);
    float fx = sx - x0f, fy = sy - y0f;

    int offp[4]; float wt[4];
    {
        float xs[2] = {x0f, x0f + 1.f}, ys[2] = {y0f, y0f + 1.f};
        float wxs[2] = {1.f - fx, fx},  wys[2] = {1.f - fy, fy};
        #pragma unroll
        for (int t = 0; t < 4; ++t) {
            float xf = xs[t & 1], yf = ys[t >> 1];
            bool val = (xf >= 0.f) && (xf <= (float)(W_-1)) &&
                       (yf >= 0.f) && (yf <= (float)(H_-1));
            int xi = (int)fminf(fmaxf(xf, 0.f), (float)(W_-1));
            int yi = (int)fminf(fmaxf(yf, 0.f), (float)(H_-1));
            offp[t] = yi * W_ + xi;
            wt[t] = wxs[t & 1] * wys[t >> 1] * (val ? 1.f : 0.f);
        }
    }

    // ---- gather: 4 taps x 5 uint4 of packed bf16 [m, rgb, feat0..31] ----
    float vals[40];
    #pragma unroll
    for (int i = 0; i < 40; ++i) vals[i] = 0.f;
    #pragma unroll
    for (int t = 0; t < 4; ++t) {
        const uint4* fp = (const uint4*)pk + ((size_t)v * HW_ + offp[t]) * 10 + GOFF;
        float wtt = wt[t];
        #pragma unroll
        for (int s5 = 0; s5 < 5; ++s5) {
            uint4 q = fp[s5];
            unsigned int dw[4] = {q.x, q.y, q.z, q.w};
            #pragma unroll
            for (int e = 0; e < 4; ++e) {
                int i = s5 * 8 + e * 2;
                vals[i]   += wtt * __uint_as_float(dw[e] << 16);
                vals[i+1] += wtt * __uint_as_float(dw[e] & 0xFFFF0000u);
            }
        }
    }
    float msample = vals[0];
    float rv0 = vals[1], rv1 = vals[2], rv2 = vals[3];
    float sdx = cam[v*3+0]-px, sdy = cam[v*3+1]-py, sdz = cam[v*3+2]-pz;
    float snv = sqrtf(sdx*sdx + sdy*sdy + sdz*sdz);
    sdx /= snv; sdy /= snv; sdz /= snv;

    float xx[42];
    xx[0] = rv0; xx[1] = rv1; xx[2] = rv2;
    #pragma unroll
    for (int k = 0; k < 32; ++k) xx[3+k] = vals[4+k];
    xx[35] = sdx; xx[36] = sdy; xx[37] = sdz;
    xx[38] = rdx; xx[39] = rdy; xx[40] = rdz;
    xx[41] = 1.0f;

    // ---- write X row: slot-major, coalesced ----
    {
        unsigned int d[24];
        #pragma unroll
        for (int i = 0; i < 21; ++i) d[i] = pk2bf(xx[2*i], xx[2*i+1]);
        d[21] = 0u; d[22] = 0u; d[23] = 0u;
        #pragma unroll
        for (int o = 0; o < 6; ++o)
            *(uint4*)(Xw + o * 1024 + lane * 16) =
                make_uint4(d[o*4], d[o*4+1], d[o*4+2], d[o*4+3]);
    }

    // ---- preload layer-1 weight A-frags (layer-2 loaded lazily per nt) ----
    short8v aw1[6];
    #pragma unroll
    for (int i = 0; i < 6; ++i)
        aw1[i] = __builtin_bit_cast(short8v, ((const uint4*)FR)[i * 64 + lane]);
    const float4* PL4 = (const float4*)(FR + 3584);
    const float bdv = bd[0], bbv = bb[0];

    float hs = vsum8(msample);
    float hssw  = __shfl_xor(hs, 32, 64);
    float rv0sw = __shfl_xor(rv0, 32, 64);
    float rv1sw = __shfl_xor(rv1, 32, 64);
    float rv2sw = __shfl_xor(rv2, 32, 64);

    #pragma unroll
    for (int nt = 0; nt < 2; ++nt) {
        const int n = nt * 32 + l31;
        // ---- layer 1: H1^T = W1T @ X^T ----
        f32x16 acc1[2];
        #pragma unroll
        for (int mt = 0; mt < 2; ++mt)
            #pragma unroll
            for (int q = 0; q < 16; ++q) acc1[mt][q] = 0.f;
        #pragma unroll
        for (int kt = 0; kt < 3; ++kt) {
            uint4 bu = *(const uint4*)(Xw + (2*kt + hi) * 1024 + n * 16);
            short8v b = __builtin_bit_cast(short8v, bu);
            acc1[0] = __builtin_amdgcn_mfma_f32_32x32x16_bf16(aw1[kt],     b, acc1[0], 0, 0, 0);
            acc1[1] = __builtin_amdgcn_mfma_f32_32x32x16_bf16(aw1[3 + kt], b, acc1[1], 0, 0, 0);
        }
        #pragma unroll
        for (int mt = 0; mt < 2; ++mt)
            #pragma unroll
            for (int q = 0; q < 4; ++q) {
                unsigned int w0 = pk2bf(fmaxf(acc1[mt][4*q+0], 0.f),
                                        fmaxf(acc1[mt][4*q+1], 0.f));
                unsigned int w1 = pk2bf(fmaxf(acc1[mt][4*q+2], 0.f),
                                        fmaxf(acc1[mt][4*q+3], 0.f));
                *(uint2*)(H1w + (q + 4*mt) * 512 + l31 * 16 + hi * 8) = make_uint2(w0, w1);
            }
        // ---- layer 2 (lazy A-frag load; bias via C-init) ----
        short8v aw2[8];
        #pragma unroll
        for (int i = 0; i < 8; ++i)
            aw2[i] = __builtin_bit_cast(short8v, ((const uint4*)(FR + 1536))[i * 64 + lane]);
        f32x16 acc2[2];
        #pragma unroll
        for (int mt = 0; mt < 2; ++mt)
            #pragma unroll
            for (int q4 = 0; q4 < 4; ++q4) {
                float4 c = PL4[(mt*2 + hi)*4 + q4];
                acc2[mt][4*q4+0] = c.x; acc2[mt][4*q4+1] = c.y;
                acc2[mt][4*q4+2] = c.z; acc2[mt][4*q4+3] = c.w;
            }
        #pragma unroll
        for (int kt = 0; kt < 4; ++kt) {
            uint4 bu = *(const uint4*)(H1w + (2*kt + hi) * 512 + l31 * 16);
            short8v b = __builtin_bit_cast(short8v, bu);
            acc2[0] = __builtin_amdgcn_mfma_f32_32x32x16_bf16(aw2[kt],     b, acc2[0], 0, 0, 0);
            acc2[1] = __builtin_amdgcn_mfma_f32_32x32x16_bf16(aw2[4 + kt], b, acc2[1], 0, 0, 0);
        }

        // ---- pooling ----
        float lgp = 0.f, dacc = 0.f, cacc = 0.f;
        #pragma unroll
        for (int mt = 0; mt < 2; ++mt)
            #pragma unroll
            for (int q4 = 0; q4 < 4; ++q4) {
                float4 wb4 = PL4[16 + (mt*2 + hi)*4 + q4];
                float4 wd4 = PL4[32 + (mt*2 + hi)*4 + q4];
                float4 w24 = PL4[48 + (mt*2 + hi)*4 + q4];
                #pragma unroll
                for (int e = 0; e < 4; ++e) {
                    float hv = fmaxf(acc2[mt][4*q4+e], 0.f);
                    float wbv = (e==0)?wb4.x:(e==1)?wb4.y:(e==2)?wb4.z:wb4.w;
                    float wdv = (e==0)?wd4.x:(e==1)?wd4.y:(e==2)?wd4.z:wd4.w;
                    float w2v = (e==0)?w24.x:(e==1)?w24.y:(e==2)?w24.z:w24.w;
                    lgp  += hv * wbv;
                    dacc += hv * wdv + hv * hv * w2v;
                    float sj = vsum8(hv);
                    cacc += sj * sj * w2v;
                }
            }
        float lg = lgp + __shfl_xor(lgp, 32, 64) + bbv;
        dacc += __shfl_xor(dacc, 32, 64);
        dacc  = vsum8(dacc);
        cacc += __shfl_xor(cacc, 32, 64);
        float density = dacc * 0.125f - cacc * (1.0f / 64.0f) + bdv;

        float mx = vmax8(lg);
        float e  = expf(lg - mx);
        float es = vsum8(e);
        float r0c = (hi == nt) ? rv0 : rv0sw;
        float r1c = (hi == nt) ? rv1 : rv1sw;
        float r2c = (hi == nt) ? rv2 : rv2sw;
        float br  = vsum8(e * r0c);
        float bg  = vsum8(e * r1c);
        float bbl = vsum8(e * r2c);
        float hn  = (nt == 0) ? hs : hssw;
        bool hull = hn > ((float)V_ - 0.001f);

        if ((lane & 0x27) == 0) {
            int PP = pbase + 4 * nt + (lane >> 3);
            float is = 1.0f / es;
            odens[PP]      = hull ? density  : 0.f;
            orgb[PP*3 + 0] = hull ? br  * is : 0.f;
            orgb[PP*3 + 1] = hull ? bg  * is : 0.f;
            orgb[PP*3 + 2] = hull ? bbl * is : 0.f;
        }
    }
}

// ---------------------- fallback (unpacked ws): scalar kernel ----------
template <int S, int FS, bool FINE>
__global__ __launch_bounds__(256, 2) void k_mlp_fb(
    const float* __restrict__ ray, const float* __restrict__ Pm,
    const float* __restrict__ cam, const float* __restrict__ shp,
    const float* __restrict__ msk, const float* __restrict__ img,
    const float* __restrict__ fea,
    const float* __restrict__ W1, const float* __restrict__ b1,
    const float* __restrict__ W2, const float* __restrict__ b2,
    const float* __restrict__ Wd, const float* __restrict__ bd,
    const float* __restrict__ Wb, const float* __restrict__ bb,
    const float* __restrict__ deptharr,
    float* __restrict__ odens, float* __restrict__ orgb) {

    const int tid = blockIdx.x * 256 + threadIdx.x;
    const int v   = tid & 7;
    const int P   = tid >> 3;
    const int r   = P / S, s = P - r * S;

    const float ox = ray[r*8+0], oy = ray[r*8+1], oz = ray[r*8+2];
    const float dx = ray[r*8+3], dy = ray[r*8+4], dz = ray[r*8+5];
    const float nv = ray[r*8+6], fv = ray[r*8+7];
    float depth;
    if (FINE) depth = deptharr[P];
    else      depth = nv + (fv - nv) * ((s + 0.5f) / (float)S);
    const float px = ox + dx*depth, py = oy + dy*depth, pz = oz + dz*depth;
    const float dn = sqrtf(dx*dx + dy*dy + dz*dz);
    const float rdx = -dx/dn, rdy = -dy/dn, rdz = -dz/dn;
    const float* Pv = Pm + v * 12;
    float q0 = Pv[0]*px + Pv[1]*py + Pv[2]*pz  + Pv[3];
    float q1 = Pv[4]*px + Pv[5]*py + Pv[6]*pz  + Pv[7];
    float q2 = Pv[8]*px + Pv[9]*py + Pv[10]*pz + Pv[11];
    float inv = 1.0f / (q2 + 1e-6f);
    float uu = q0 * inv, ww = q1 * inv;
    float gx = 2.0f * (uu / shp[v*2+1]) - 1.0f;
    float gy = 2.0f * (ww / shp[v*2+0]) - 1.0f;
    float sx = (gx + 1.0f) * ((float)W_ * 0.5f) - 0.5f;
    float sy = (gy + 1.0f) * ((float)H_ * 0.5f) - 0.5f;
    float x0f = floorf(sx), y0f = floorf(sy);
    float fx = sx - x0f, fy = sy - y0f;
    int offp[4]; float wt[4];
    {
        float xs[2] = {x0f, x0f + 1.f}, ys[2] = {y0f, y0f + 1.f};
        float wxs[2] = {1.f - fx, fx},  wys[2] = {1.f - fy, fy};
        #pragma unroll
        for (int t = 0; t < 4; ++t) {
            float xf = xs[t & 1], yf = ys[t >> 1];
            bool val = (xf >= 0.f) && (xf <= (float)(W_-1)) &&
                       (yf >= 0.f) && (yf <= (float)(H_-1));
            int xi = (int)fminf(fmaxf(xf, 0.f), (float)(W_-1));
            int yi = (int)fminf(fmaxf(yf, 0.f), (float)(H_-1));
            offp[t] = yi * W_ + xi;
            wt[t] = wxs[t & 1] * wys[t >> 1] * (val ? 1.f : 0.f);
        }
    }
    const float* mb = msk + v * HW_;
    float msample = wt[0]*mb[offp[0]] + wt[1]*mb[offp[1]]
                  + wt[2]*mb[offp[2]] + wt[3]*mb[offp[3]];
    float rv0 = 0.f, rv1 = 0.f, rv2 = 0.f;
    {
        const float* ib = img + (v * 3) * HW_;
        #pragma unroll
        for (int t = 0; t < 4; ++t) {
            rv0 += wt[t] * ib[offp[t]];
            rv1 += wt[t] * ib[HW_ + offp[t]];
            rv2 += wt[t] * ib[2 * HW_ + offp[t]];
        }
    }
    float sdx = cam[v*3+0]-px, sdy = cam[v*3+1]-py, sdz = cam[v*3+2]-pz;
    float snv = sqrtf(sdx*sdx + sdy*sdy + sdz*sdz);
    sdx /= snv; sdy /= snv; sdz /= snv;
    float xx[IND_];
    xx[0] = rv0; xx[1] = rv1; xx[2] = rv2;
    #pragma unroll
    for (int k = 0; k < 32; ++k) {
        const float* fb = fea + (size_t)(v * (2*L_) + FS + k) * HW_;
        xx[3+k] = wt[0]*fb[offp[0]] + wt[1]*fb[offp[1]]
                + wt[2]*fb[offp[2]] + wt[3]*fb[offp[3]];
    }
    xx[35] = sdx; xx[36] = sdy; xx[37] = sdz;
    xx[38] = rdx; xx[39] = rdy; xx[40] = rdz;
    float h1[HID_];
    #pragma unroll
    for (int j = 0; j < HID_; ++j) {
        float a0 = 0.f;
        #pragma unroll
        for (int k = 0; k < IND_; ++k) a0 += xx[k] * W1[k * HID_ + j];
        h1[j] = fmaxf(b1[j] + a0, 0.f);
    }
    float lg = bb[0];
    float A = 0.f, B = 0.f, C = 0.f;
    #pragma unroll 1
    for (int j = 0; j < HID_; j += 4) {
        float hh[4];
        #pragma unroll
        for (int jj = 0; jj < 4; ++jj) {
            float a0 = 0.f;
            #pragma unroll
            for (int k = 0; k < HID_; ++k) a0 += h1[k] * W2[k * HID_ + (j + jj)];
            hh[jj] = fmaxf(b2[j + jj] + a0, 0.f);
        }
        #pragma unroll
        for (int jj = 0; jj < 4; ++jj) {
            float h = hh[jj];
            lg += h * Wb[j + jj];
            A  += h * Wd[j + jj];
            B  += h * h * Wd[HID_ + j + jj];
            float sj = vsum8(h);
            C  += sj * sj * Wd[HID_ + j + jj];
        }
    }
    A = vsum8(A); B = vsum8(B);
    float density = A * 0.125f + B * 0.125f - C * (1.0f / 64.0f) + bd[0];
    float hsv = vsum8(msample);
    bool hull = hsv > ((float)V_ - 0.001f);
    float mx = vmax8(lg);
    float e = expf(lg - mx);
    float es = vsum8(e);
    float br  = vsum8(e * rv0);
    float bg  = vsum8(e * rv1);
    float bbl = vsum8(e * rv2);
    if (v == 0) {
        float is = 1.0f / es;
        odens[P]      = hull ? density  : 0.f;
        orgb[P*3 + 0] = hull ? br  * is : 0.f;
        orgb[P*3 + 1] = hull ? bg  * is : 0.f;
        orgb[P*3 + 2] = hull ? bbl * is : 0.f;
    }
}

// -------------- wave-per-ray coarse composite + sample_pdf + merge-path -------
__global__ __launch_bounds__(256) void k_comp_coarse(const float* __restrict__ ray,
                                                     const float* __restrict__ dens,
                                                     const float* __restrict__ rgb,
                                                     float* __restrict__ out,
                                                     float* __restrict__ fulld) {
    __shared__ float cdfS[4][64];
    __shared__ float fdS[4][64];
    const int wv = threadIdx.x >> 6, lane = threadIdx.x & 63;
    const int r = blockIdx.x * 4 + wv;
    const float nv = ray[r*8+6], fv = ray[r*8+7];
    const int s = lane;

    float d0 = nv + (fv - nv) * ((s + 0.5f) / NC_);
    float d1 = nv + (fv - nv) * ((s + 1.5f) / NC_);
    float delta = (s == NC_-1) ? 1e10f : (d1 - d0);
    float a = 1.f - expf(-fmaxf(dens[r*NC_ + s], 0.f) * delta);
    float qv = 1.f - a + 1e-10f;
    float inc = scan_mul64(qv, lane);
    float trans = __shfl_up(inc, 1, 64);
    if (lane == 0) trans = 1.f;
    float w = a * trans;

    float g0 = rgb[(r*NC_+s)*3+0], g1 = rgb[(r*NC_+s)*3+1], g2 = rgb[(r*NC_+s)*3+2];
    float c0 = redsum64(w * g0);
    float c1 = redsum64(w * g1);
    float c2 = redsum64(w * g2);
    float cd = redsum64(w * d0);
    float ca = redsum64(w);
    if (lane == 0) {
        out[r*3+0] = c0; out[r*3+1] = c1; out[r*3+2] = c2;
        out[3072 + r] = cd;
        out[4096 + r] = ca;
    }

    float pw = (s >= 1 && s <= 62) ? (w + 1e-5f) : 0.f;
    float tot = redsum64(pw);
    float p = pw / tot;
    float ic = scan_add64(p, lane);
    cdfS[wv][lane] = ic;
    __syncthreads();

    float u = (lane + 0.5f) / NF_;
    int lo = 0, hi = 63;
    while (lo < hi) {
        int mid = (lo + hi) >> 1;
        if (cdfS[wv][mid] <= u) lo = mid + 1; else hi = mid;
    }
    int below = lo - 1;
    int above = (lo > 62) ? 62 : lo;
    float cA = cdfS[wv][below], cB = cdfS[wv][above];
    float b0 = nv + (fv - nv) * ((below + 1.0f) / NC_);
    float b1 = nv + (fv - nv) * ((above + 1.0f) / NC_);
    float dnm = cB - cA;
    dnm = (dnm < 1e-5f) ? 1.f : dnm;
    float fdv = b0 + (u - cA) / dnm * (b1 - b0);
    fdS[wv][lane] = fdv;
    __syncthreads();

    lo = 0; hi = 64;
    while (lo < hi) {
        int mid = (lo + hi) >> 1;
        if (fdS[wv][mid] < d0) lo = mid + 1; else hi = mid;
    }
    fulld[r*128 + s + lo] = d0;

    lo = 0; hi = 64;
    while (lo < hi) {
        int mid = (lo + hi) >> 1;
        float daj = nv + (fv - nv) * ((mid + 0.5f) / NC_);
        if (daj <= fdv) lo = mid + 1; else hi = mid;
    }
    fulld[r*128 + lane + lo] = fdv;
}

// ------------------------- wave-per-ray fine composite (2 samples/lane) -------
__global__ __launch_bounds__(256) void k_comp_fine(const float* __restrict__ fulld,
                                                   const float* __restrict__ dens,
                                                   const float* __restrict__ rgb,
                                                   float* __restrict__ out) {
    const int wv = threadIdx.x >> 6, lane = threadIdx.x & 63;
    const int r = blockIdx.x * 4 + wv;
    const int S = NC_ + NF_;
    const float* fl = fulld + r * S;
    const int s0 = 2 * lane, s1 = 2 * lane + 1;

    float f0 = fl[s0], f1 = fl[s1];
    float nx = __shfl_down(f0, 1, 64);
    float dl0 = f1 - f0;
    float dl1 = (lane == 63) ? 1e10f : (nx - f1);
    float a0 = 1.f - expf(-fmaxf(dens[r*S + s0], 0.f) * dl0);
    float a1 = 1.f - expf(-fmaxf(dens[r*S + s1], 0.f) * dl1);
    float q0 = 1.f - a0 + 1e-10f, q1 = 1.f - a1 + 1e-10f;
    float inc = scan_mul64(q0 * q1, lane);
    float E = __shfl_up(inc, 1, 64);
    if (lane == 0) E = 1.f;
    float w0 = a0 * E, w1 = a1 * (E * q0);

    float g00 = rgb[(r*S+s0)*3+0], g01 = rgb[(r*S+s0)*3+1], g02 = rgb[(r*S+s0)*3+2];
    float g10 = rgb[(r*S+s1)*3+0], g11 = rgb[(r*S+s1)*3+1], g12 = rgb[(r*S+s1)*3+2];
    float c0 = redsum64(w0*g00 + w1*g10);
    float c1 = redsum64(w0*g01 + w1*g11);
    float c2 = redsum64(w0*g02 + w1*g12);
    float cd = redsum64(w0*f0 + w1*f1);
    float ca = redsum64(w0 + w1);
    if (lane == 0) {
        out[5120 + r*3+0] = c0; out[5120 + r*3+1] = c1; out[5120 + r*3+2] = c2;
        out[8192 + r] = cd;
        out[9216 + r] = ca;
    }
}

// ------------------------------------------------------------------ launch
extern "C" void kernel_launch(void* const* d_in, const int* in_sizes, int n_in,
                              void* d_out, int out_size, void* d_ws, size_t ws_size,
                              hipStream_t stream) {
    const float* ray = (const float*)d_in[0];
    const float* Kin = (const float*)d_in[1];
    const float* Ein = (const float*)d_in[2];
    const float* cam = (const float*)d_in[3];
    const float* shp = (const float*)d_in[4];
    const float* msk = (const float*)d_in[5];
    const float* img = (const float*)d_in[6];
    const float* fea = (const float*)d_in[7];
    const float* cw[8]; for (int i = 0; i < 8; ++i) cw[i] = (const float*)d_in[8+i];
    const float* fw[8]; for (int i = 0; i < 8; ++i) fw[i] = (const float*)d_in[16+i];

    float* ws    = (float*)d_ws;
    float* Pm    = ws;                        // 96
    unsigned int* FRc = (unsigned int*)(Pm + 96);   // 4096 dwords
    unsigned int* FRf = FRc + 4096;                 // 4096 dwords
    float* cdens = (float*)(FRf + 4096);      // 65536
    float* crgb  = cdens + R_ * NC_;          // 196608
    float* fulld = crgb + R_ * NC_ * 3;       // 131072
    float* fdens = fulld + R_ * (NC_+NF_);    // 131072
    float* frgb  = fdens + R_ * (NC_+NF_);    // 393216
    float* pk    = frgb + R_ * (NC_+NF_) * 3; // V*HW*40 floats (160B bf16 rows)

    size_t base_floats = (size_t)(pk - ws);
    size_t need = (base_floats + (size_t)V_ * HW_ * 40 + 64) * sizeof(float);
    bool packed = (ws_size >= need);

    float* outp  = (float*)d_out;

    if (packed) {
        k_init<<<31, 256, 0, stream>>>(Kin, Ein, Pm,
            cw[0], cw[1], cw[2], cw[3], cw[4], cw[6], FRc,
            fw[0], fw[1], fw[2], fw[3], fw[4], fw[6], FRf);
        k_packB2<<<dim3(W_/64, H_, V_), 256, 0, stream>>>(msk, img, fea, pk);

        k_mlp_mfma<NC_, false, 0><<<R_ * NC_ / 32, 256, 0, stream>>>(
            ray, Pm, cam, shp, pk, FRc, cw[5], cw[7],
            nullptr, cdens, crgb);

        k_comp_coarse<<<R_ / 4, 256, 0, stream>>>(ray, cdens, crgb, outp, fulld);

        k_mlp_mfma<NC_ + NF_, true, 5><<<R_ * (NC_+NF_) / 32, 256, 0, stream>>>(
            ray, Pm, cam, shp, pk, FRf, fw[5], fw[7],
            fulld, fdens, frgb);

        k_comp_fine<<<R_ / 4, 256, 0, stream>>>(fulld, fdens, frgb, outp);
    } else {
        k_init<<<1, 256, 0, stream>>>(Kin, Ein, Pm,
            cw[0], cw[1], cw[2], cw[3], cw[4], cw[6], FRc,
            fw[0], fw[1], fw[2], fw[3], fw[4], fw[6], FRf);
        k_mlp_fb<NC_, 0, false><<<R_ * NC_ * 8 / 256, 256, 0, stream>>>(
            ray, Pm, cam, shp, msk, img, fea,
            cw[0], cw[1], cw[2], cw[3], cw[4], cw[5], cw[6], cw[7],
            nullptr, cdens, crgb);

        k_comp_coarse<<<R_ / 4, 256, 0, stream>>>(ray, cdens, crgb, outp, fulld);

        k_mlp_fb<NC_ + NF_, L_, true><<<R_ * (NC_+NF_) * 8 / 256, 256, 0, stream>>>(
            ray, Pm, cam, shp, msk, img, fea,
            fw[0], fw[1], fw[2], fw[3], fw[4], fw[5], fw[6], fw[7],
            fulld, fdens, frgb);

        k_comp_fine<<<R_ / 4, 256, 0, stream>>>(fulld, fdens, frgb, outp);
    }
}

// Round 14
// 186.529 us; speedup vs baseline: 4.4992x; 1.0345x over previous
//
#include <hip/hip_runtime.h>
#include <hip/hip_bf16.h>
#include <math.h>

#define V_   8
#define H_   256
#define W_   256
#define L_   32
#define HID_ 64
#define NC_  64
#define NF_  64
#define R_   1024
#define IND_ 41
#define HW_  (H_*W_)

typedef _Float16 h2v __attribute__((ext_vector_type(2)));
typedef _Float16 h8v __attribute__((ext_vector_type(8)));
typedef __attribute__((ext_vector_type(16))) float f32x16;

// ---------------- fp16 helpers (RNE converts) ----------------
__device__ __forceinline__ unsigned int pk2hf(float a, float b) {
    h2v t; t[0] = (_Float16)a; t[1] = (_Float16)b;
    return __builtin_bit_cast(unsigned int, t);
}

// ---- cross-lane helpers ----
template<int CTRL>
__device__ __forceinline__ float dpp_add(float x) {
    int m = __builtin_amdgcn_mov_dpp(__builtin_bit_cast(int, x), CTRL, 0xF, 0xF, true);
    return x + __builtin_bit_cast(float, m);
}
template<int CTRL>
__device__ __forceinline__ float dpp_max(float x) {
    int m = __builtin_amdgcn_mov_dpp(__builtin_bit_cast(int, x), CTRL, 0xF, 0xF, true);
    return fmaxf(x, __builtin_bit_cast(float, m));
}
__device__ __forceinline__ float swz_xor4(float x) {
    int m = __builtin_amdgcn_ds_swizzle(__builtin_bit_cast(int, x), 0x101F);
    return __builtin_bit_cast(float, m);
}
__device__ __forceinline__ float vsum8(float x) {
    x = dpp_add<0xB1>(x);
    x = dpp_add<0x4E>(x);
    x += swz_xor4(x);
    return x;
}
__device__ __forceinline__ float vmax8(float x) {
    x = dpp_max<0xB1>(x);
    x = dpp_max<0x4E>(x);
    x = fmaxf(x, swz_xor4(x));
    return x;
}
__device__ __forceinline__ float redsum64(float x) {
    #pragma unroll
    for (int off = 32; off >= 1; off >>= 1) x += __shfl_xor(x, off, 64);
    return x;
}
__device__ __forceinline__ float scan_mul64(float x, int lane) {
    #pragma unroll
    for (int off = 1; off < 64; off <<= 1) {
        float y = __shfl_up(x, off, 64);
        x = (lane >= off) ? x * y : x;
    }
    return x;
}
__device__ __forceinline__ float scan_add64(float x, int lane) {
    #pragma unroll
    for (int off = 1; off < 64; off <<= 1) {
        float y = __shfl_up(x, off, 64);
        x = (lane >= off) ? x + y : x;
    }
    return x;
}

// ---------------- packMFMA body (fragment-order weights, fp16) ----------------
// X layout (48 inputs): x'[0]=mask(zero weight), x'[1..3]=rgb, x'[4..35]=feat,
// x'[36..38]=sd, x'[39..41]=rd, x'[42]=1 (bias row), x'[43..47]=0.
__device__ __forceinline__ void packMFMA_body(
    int t, const float* __restrict__ W1, const float* __restrict__ b1,
    const float* __restrict__ W2, const float* __restrict__ b2,
    const float* __restrict__ Wd, const float* __restrict__ Wb,
    unsigned int* __restrict__ out) {
    if (t < 1536) {
        int blk = t >> 8, idx = t & 255;
        int mt = blk / 3, kt = blk % 3;
        int l = idx >> 2, rg = idx & 3;
        int hi = l >> 5;
        int j  = 32 * mt + (l & 31);
        int k0 = 16 * kt + 8 * hi + 2 * rg;
        int k1 = k0 + 1;
        auto w1v = [&](int k) -> float {
            if (k == 0) return 0.f;
            if (k <= 41) return W1[(k - 1) * 64 + j];
            if (k == 42) return b1[j];
            return 0.f;
        };
        out[t] = pk2hf(w1v(k0), w1v(k1));
    } else if (t < 3584) {
        int u = t - 1536;
        int blk = u >> 8, idx = u & 255;
        int l = idx >> 2, rg = idx & 3;
        int hi = l >> 5;
        int j2 = 32 * (blk >> 2) + (l & 31);
        int k0 = 16 * (blk & 3) + 8 * hi + 2 * rg;
        out[t] = pk2hf(W2[k0 * 64 + j2], W2[(k0 + 1) * 64 + j2]);
    } else if (t < 3840) {
        int i = t - 3584;
        int w = i >> 6, mt = (i >> 5) & 1, hi = (i >> 4) & 1, rg = i & 15;
        int j2 = (rg & 3) + 8 * (rg >> 2) + 4 * hi + 32 * mt;
        float v = (w == 0) ? b2[j2] : (w == 1) ? Wb[j2] : (w == 2) ? Wd[j2] : Wd[64 + j2];
        ((float*)out)[t] = v;
    }
}

// ------------- merged init: P = K@E + coarse/fine weight fragment packs -------
__global__ __launch_bounds__(256) void k_init(
    const float* __restrict__ Km, const float* __restrict__ Em, float* __restrict__ Pm,
    const float* __restrict__ cW1, const float* __restrict__ cb1,
    const float* __restrict__ cW2, const float* __restrict__ cb2,
    const float* __restrict__ cWd, const float* __restrict__ cWb,
    unsigned int* __restrict__ FRc,
    const float* __restrict__ fW1, const float* __restrict__ fb1,
    const float* __restrict__ fW2, const float* __restrict__ fb2,
    const float* __restrict__ fWd, const float* __restrict__ fWb,
    unsigned int* __restrict__ FRf) {
    const int bid = blockIdx.x, tid = threadIdx.x;
    if (bid == 0) {
        if (tid >= V_ * 12) return;
        int v = tid / 12, e = tid - v * 12, row = e >> 2, col = e & 3;
        float acc = 0.f;
        #pragma unroll
        for (int k = 0; k < 3; ++k)
            acc += Km[v * 9 + row * 3 + k] * Em[v * 12 + k * 4 + col];
        Pm[v * 12 + row * 4 + col] = acc;
    } else if (bid <= 15) {
        packMFMA_body((bid - 1) * 256 + tid, cW1, cb1, cW2, cb2, cWd, cWb, FRc);
    } else if (bid <= 30) {
        packMFMA_body((bid - 16) * 256 + tid, fW1, fb1, fW2, fb2, fWd, fWb, FRf);
    }
}

// ------ pack BOTH passes: 160B rows [m,rgb,f0..31 | m,rgb,f32..63] fp16 -------
__global__ __launch_bounds__(256) void k_packB2(const float* __restrict__ msk,
                                                const float* __restrict__ img,
                                                const float* __restrict__ fea,
                                                float* __restrict__ pk) {
    __shared__ unsigned short tile[64][80];
    const int xb = blockIdx.x * 64, y = blockIdx.y, v = blockIdx.z;
    const int t = threadIdx.x;
    const int x = t & 63, cg = t >> 6;
    const size_t px = (size_t)y * W_ + xb + x;
    #pragma unroll
    for (int step = 0; step < 17; ++step) {
        int ch = step * 4 + cg;               // 0..67
        if (ch < 68) {
            float val;
            if (ch == 0)      val = msk[(size_t)v * HW_ + px];
            else if (ch < 4)  val = img[((size_t)(v * 3 + (ch - 1))) * HW_ + px];
            else              val = fea[((size_t)(v * 2 * L_ + (ch - 4))) * HW_ + px];
            unsigned short bf = __builtin_bit_cast(unsigned short, (_Float16)val);
            if (ch == 0)      { tile[x][0] = bf; tile[x][40] = bf; }
            else if (ch < 4)  { tile[x][ch] = bf; tile[x][40 + ch] = bf; }
            else if (ch < 36) { tile[x][ch] = bf; }
            else              { tile[x][ch + 8] = bf; }   // f32..63 -> 44..75
        }
    }
    if (t < 256) {
        int xi = t >> 2, c = t & 3;
        tile[xi][36 + c] = 0;
        tile[xi][76 + c] = 0;
    }
    __syncthreads();
    uint2* dst = (uint2*)(pk + ((size_t)v * HW_ + (size_t)y * W_ + xb) * 40);
    for (int j = t; j < 1280; j += 256) {
        int p = j / 20, sl = j % 20;
        dst[j] = *(const uint2*)&tile[p][sl * 4];
    }
}

// ------------------------------------------------------------- MFMA MLP kernel
// Wave = 8 points x 8 views. Gather accumulates bilinear taps in packed fp16
// (v_pk_fma_f16); the 18 packed dwords ARE X dwords 0..17. Mask sample
// accumulated separately in fp32 (hull threshold needs ~1e-4 accuracy).
template <int S, bool FINE, int GOFF>
__global__ __launch_bounds__(256) void k_mlp_mfma(
    const float* __restrict__ ray, const float* __restrict__ Pm,
    const float* __restrict__ cam, const float* __restrict__ shp,
    const float* __restrict__ pk,
    const unsigned int* __restrict__ FR,
    const float* __restrict__ bd, const float* __restrict__ bb,
    const float* __restrict__ deptharr,
    float* __restrict__ odens, float* __restrict__ orgb) {

    __shared__ __align__(16) char smem[40960];
    const int lane = threadIdx.x & 63;
    const int wv   = threadIdx.x >> 6;
    const int hi   = lane >> 5;
    const int l31  = lane & 31;
    char* Xw  = smem + wv * 10240;
    char* H1w = Xw + 6144;

    const int pbase = (blockIdx.x * 4 + wv) * 8;
    const int P0 = pbase + (lane >> 3);
    const int v  = lane & 7;
    const int r  = P0 / S, s = P0 - r * S;

    const float ox = ray[r*8+0], oy = ray[r*8+1], oz = ray[r*8+2];
    const float dx = ray[r*8+3], dy = ray[r*8+4], dz = ray[r*8+5];
    const float nv = ray[r*8+6], fv = ray[r*8+7];

    float depth;
    if (FINE) depth = deptharr[P0];
    else      depth = nv + (fv - nv) * ((s + 0.5f) / (float)S);

    const float px = ox + dx*depth, py = oy + dy*depth, pz = oz + dz*depth;
    const float dn = sqrtf(dx*dx + dy*dy + dz*dz);
    const float rdx = -dx/dn, rdy = -dy/dn, rdz = -dz/dn;

    const float* Pv = Pm + v * 12;
    float q0 = Pv[0]*px + Pv[1]*py + Pv[2]*pz  + Pv[3];
    float q1 = Pv[4]*px + Pv[5]*py + Pv[6]*pz  + Pv[7];
    float q2 = Pv[8]*px + Pv[9]*py + Pv[10]*pz + Pv[11];
    float inv = 1.0f / (q2 + 1e-6f);
    float uu = q0 * inv, ww = q1 * inv;
    float gx = 2.0f * (uu / shp[v*2+1]) - 1.0f;
    float gy = 2.0f * (ww / shp[v*2+0]) - 1.0f;
    float sx = (gx + 1.0f) * ((float)W_ * 0.5f) - 0.5f;
    float sy = (gy + 1.0f) * ((float)H_ * 0.5f) - 0.5f;
    float x0f = floorf(sx), y0f = floorf(sy);
    float fx = sx - x0f, fy = sy - y0f;

    int offp[4]; float wt[4];
    {
        float xs[2] = {x0f, x0f + 1.f}, ys[2] = {y0f, y0f + 1.f};
        float wxs[2] = {1.f - fx, fx},  wys[2] = {1.f - fy, fy};
        #pragma unroll
        for (int t = 0; t < 4; ++t) {
            float xf = xs[t & 1], yf = ys[t >> 1];
            bool val = (xf >= 0.f) && (xf <= (float)(W_-1)) &&
                       (yf >= 0.f) && (yf <= (float)(H_-1));
            int xi = (int)fminf(fmaxf(xf, 0.f), (float)(W_-1));
            int yi = (int)fminf(fmaxf(yf, 0.f), (float)(H_-1));
            offp[t] = yi * W_ + xi;
            wt[t] = wxs[t & 1] * wys[t >> 1] * (val ? 1.f : 0.f);
        }
    }

    // ---- gather: 4 taps x 5 uint4; bilinear in packed fp16; mask in fp32 ----
    h2v vals[18];
    #pragma unroll
    for (int i = 0; i < 18; ++i) vals[i] = (h2v){(_Float16)0.f, (_Float16)0.f};
    float msample = 0.f;
    #pragma unroll
    for (int t = 0; t < 4; ++t) {
        const uint4* fp = (const uint4*)pk + ((size_t)v * HW_ + offp[t]) * 10 + GOFF;
        float wf = wt[t];
        _Float16 wh = (_Float16)wf;
        h2v w2 = (h2v){wh, wh};
        #pragma unroll
        for (int s5 = 0; s5 < 5; ++s5) {
            uint4 q = fp[s5];
            unsigned int dw[4] = {q.x, q.y, q.z, q.w};
            if (s5 == 0) {
                h2v m2 = __builtin_bit_cast(h2v, dw[0]);
                msample += wf * (float)m2[0];      // fp32 mask accumulate
            }
            #pragma unroll
            for (int e = 0; e < 4; ++e) {
                int i = s5 * 4 + e;
                if (i < 18) vals[i] += w2 * __builtin_bit_cast(h2v, dw[e]);
            }
        }
    }
    float rv0 = (float)vals[0][1], rv1 = (float)vals[1][0], rv2 = (float)vals[1][1];
    float sdx = cam[v*3+0]-px, sdy = cam[v*3+1]-py, sdz = cam[v*3+2]-pz;
    float snv = sqrtf(sdx*sdx + sdy*sdy + sdz*sdz);
    sdx /= snv; sdy /= snv; sdz /= snv;

    // ---- write X row: dwords 0..17 = vals, 18..21 = sd/rd/bias, 22..23 = 0 ----
    {
        unsigned int d[24];
        #pragma unroll
        for (int i = 0; i < 18; ++i) d[i] = __builtin_bit_cast(unsigned int, vals[i]);
        d[18] = pk2hf(sdx, sdy);
        d[19] = pk2hf(sdz, rdx);
        d[20] = pk2hf(rdy, rdz);
        d[21] = pk2hf(1.0f, 0.f);
        d[22] = 0u; d[23] = 0u;
        #pragma unroll
        for (int o = 0; o < 6; ++o)
            *(uint4*)(Xw + o * 1024 + lane * 16) =
                make_uint4(d[o*4], d[o*4+1], d[o*4+2], d[o*4+3]);
    }

    // ---- preload layer-1 weight A-frags (layer-2 loaded lazily per nt) ----
    h8v aw1[6];
    #pragma unroll
    for (int i = 0; i < 6; ++i)
        aw1[i] = __builtin_bit_cast(h8v, ((const uint4*)FR)[i * 64 + lane]);
    const float4* PL4 = (const float4*)(FR + 3584);
    const float bdv = bd[0], bbv = bb[0];

    float hs = vsum8(msample);
    float hssw  = __shfl_xor(hs, 32, 64);
    float rv0sw = __shfl_xor(rv0, 32, 64);
    float rv1sw = __shfl_xor(rv1, 32, 64);
    float rv2sw = __shfl_xor(rv2, 32, 64);

    #pragma unroll
    for (int nt = 0; nt < 2; ++nt) {
        const int n = nt * 32 + l31;
        // ---- layer 1: H1^T = W1T @ X^T ----
        f32x16 acc1[2];
        #pragma unroll
        for (int mt = 0; mt < 2; ++mt)
            #pragma unroll
            for (int q = 0; q < 16; ++q) acc1[mt][q] = 0.f;
        #pragma unroll
        for (int kt = 0; kt < 3; ++kt) {
            uint4 bu = *(const uint4*)(Xw + (2*kt + hi) * 1024 + n * 16);
            h8v b = __builtin_bit_cast(h8v, bu);
            acc1[0] = __builtin_amdgcn_mfma_f32_32x32x16_f16(aw1[kt],     b, acc1[0], 0, 0, 0);
            acc1[1] = __builtin_amdgcn_mfma_f32_32x32x16_f16(aw1[3 + kt], b, acc1[1], 0, 0, 0);
        }
        #pragma unroll
        for (int mt = 0; mt < 2; ++mt)
            #pragma unroll
            for (int q = 0; q < 4; ++q) {
                unsigned int w0 = pk2hf(fmaxf(acc1[mt][4*q+0], 0.f),
                                        fmaxf(acc1[mt][4*q+1], 0.f));
                unsigned int w1 = pk2hf(fmaxf(acc1[mt][4*q+2], 0.f),
                                        fmaxf(acc1[mt][4*q+3], 0.f));
                *(uint2*)(H1w + (q + 4*mt) * 512 + l31 * 16 + hi * 8) = make_uint2(w0, w1);
            }
        // ---- layer 2 (lazy A-frag load; bias via C-init) ----
        h8v aw2[8];
        #pragma unroll
        for (int i = 0; i < 8; ++i)
            aw2[i] = __builtin_bit_cast(h8v, ((const uint4*)(FR + 1536))[i * 64 + lane]);
        f32x16 acc2[2];
        #pragma unroll
        for (int mt = 0; mt < 2; ++mt)
            #pragma unroll
            for (int q4 = 0; q4 < 4; ++q4) {
                float4 c = PL4[(mt*2 + hi)*4 + q4];
                acc2[mt][4*q4+0] = c.x; acc2[mt][4*q4+1] = c.y;
                acc2[mt][4*q4+2] = c.z; acc2[mt][4*q4+3] = c.w;
            }
        #pragma unroll
        for (int kt = 0; kt < 4; ++kt) {
            uint4 bu = *(const uint4*)(H1w + (2*kt + hi) * 512 + l31 * 16);
            h8v b = __builtin_bit_cast(h8v, bu);
            acc2[0] = __builtin_amdgcn_mfma_f32_32x32x16_f16(aw2[kt],     b, acc2[0], 0, 0, 0);
            acc2[1] = __builtin_amdgcn_mfma_f32_32x32x16_f16(aw2[4 + kt], b, acc2[1], 0, 0, 0);
        }

        // ---- pooling ----
        float lgp = 0.f, dacc = 0.f, cacc = 0.f;
        #pragma unroll
        for (int mt = 0; mt < 2; ++mt)
            #pragma unroll
            for (int q4 = 0; q4 < 4; ++q4) {
                float4 wb4 = PL4[16 + (mt*2 + hi)*4 + q4];
                float4 wd4 = PL4[32 + (mt*2 + hi)*4 + q4];
                float4 w24 = PL4[48 + (mt*2 + hi)*4 + q4];
                #pragma unroll
                for (int e = 0; e < 4; ++e) {
                    float hv = fmaxf(acc2[mt][4*q4+e], 0.f);
                    float wbv = (e==0)?wb4.x:(e==1)?wb4.y:(e==2)?wb4.z:wb4.w;
                    float wdv = (e==0)?wd4.x:(e==1)?wd4.y:(e==2)?wd4.z:wd4.w;
                    float w2v = (e==0)?w24.x:(e==1)?w24.y:(e==2)?w24.z:w24.w;
                    lgp  += hv * wbv;
                    dacc += hv * wdv + hv * hv * w2v;
                    float sj = vsum8(hv);
                    cacc += sj * sj * w2v;
                }
            }
        float lg = lgp + __shfl_xor(lgp, 32, 64) + bbv;
        dacc += __shfl_xor(dacc, 32, 64);
        dacc  = vsum8(dacc);
        cacc += __shfl_xor(cacc, 32, 64);
        float density = dacc * 0.125f - cacc * (1.0f / 64.0f) + bdv;

        float mx = vmax8(lg);
        float e  = expf(lg - mx);
        float es = vsum8(e);
        float r0c = (hi == nt) ? rv0 : rv0sw;
        float r1c = (hi == nt) ? rv1 : rv1sw;
        float r2c = (hi == nt) ? rv2 : rv2sw;
        float br  = vsum8(e * r0c);
        float bg  = vsum8(e * r1c);
        float bbl = vsum8(e * r2c);
        float hn  = (nt == 0) ? hs : hssw;
        bool hull = hn > ((float)V_ - 0.001f);

        if ((lane & 0x27) == 0) {
            int PP = pbase + 4 * nt + (lane >> 3);
            float is = 1.0f / es;
            odens[PP]      = hull ? density  : 0.f;
            orgb[PP*3 + 0] = hull ? br  * is : 0.f;
            orgb[PP*3 + 1] = hull ? bg  * is : 0.f;
            orgb[PP*3 + 2] = hull ? bbl * is : 0.f;
        }
    }
}

// ---------------------- fallback (unpacked ws): scalar kernel ----------
template <int S, int FS, bool FINE>
__global__ __launch_bounds__(256, 2) void k_mlp_fb(
    const float* __restrict__ ray, const float* __restrict__ Pm,
    const float* __restrict__ cam, const float* __restrict__ shp,
    const float* __restrict__ msk, const float* __restrict__ img,
    const float* __restrict__ fea,
    const float* __restrict__ W1, const float* __restrict__ b1,
    const float* __restrict__ W2, const float* __restrict__ b2,
    const float* __restrict__ Wd, const float* __restrict__ bd,
    const float* __restrict__ Wb, const float* __restrict__ bb,
    const float* __restrict__ deptharr,
    float* __restrict__ odens, float* __restrict__ orgb) {

    const int tid = blockIdx.x * 256 + threadIdx.x;
    const int v   = tid & 7;
    const int P   = tid >> 3;
    const int r   = P / S, s = P - r * S;

    const float ox = ray[r*8+0], oy = ray[r*8+1], oz = ray[r*8+2];
    const float dx = ray[r*8+3], dy = ray[r*8+4], dz = ray[r*8+5];
    const float nv = ray[r*8+6], fv = ray[r*8+7];
    float depth;
    if (FINE) depth = deptharr[P];
    else      depth = nv + (fv - nv) * ((s + 0.5f) / (float)S);
    const float px = ox + dx*depth, py = oy + dy*depth, pz = oz + dz*depth;
    const float dn = sqrtf(dx*dx + dy*dy + dz*dz);
    const float rdx = -dx/dn, rdy = -dy/dn, rdz = -dz/dn;
    const float* Pv = Pm + v * 12;
    float q0 = Pv[0]*px + Pv[1]*py + Pv[2]*pz  + Pv[3];
    float q1 = Pv[4]*px + Pv[5]*py + Pv[6]*pz  + Pv[7];
    float q2 = Pv[8]*px + Pv[9]*py + Pv[10]*pz + Pv[11];
    float inv = 1.0f / (q2 + 1e-6f);
    float uu = q0 * inv, ww = q1 * inv;
    float gx = 2.0f * (uu / shp[v*2+1]) - 1.0f;
    float gy = 2.0f * (ww / shp[v*2+0]) - 1.0f;
    float sx = (gx + 1.0f) * ((float)W_ * 0.5f) - 0.5f;
    float sy = (gy + 1.0f) * ((float)H_ * 0.5f) - 0.5f;
    float x0f = floorf(sx), y0f = floorf(sy);
    float fx = sx - x0f, fy = sy - y0f;
    int offp[4]; float wt[4];
    {
        float xs[2] = {x0f, x0f + 1.f}, ys[2] = {y0f, y0f + 1.f};
        float wxs[2] = {1.f - fx, fx},  wys[2] = {1.f - fy, fy};
        #pragma unroll
        for (int t = 0; t < 4; ++t) {
            float xf = xs[t & 1], yf = ys[t >> 1];
            bool val = (xf >= 0.f) && (xf <= (float)(W_-1)) &&
                       (yf >= 0.f) && (yf <= (float)(H_-1));
            int xi = (int)fminf(fmaxf(xf, 0.f), (float)(W_-1));
            int yi = (int)fminf(fmaxf(yf, 0.f), (float)(H_-1));
            offp[t] = yi * W_ + xi;
            wt[t] = wxs[t & 1] * wys[t >> 1] * (val ? 1.f : 0.f);
        }
    }
    const float* mb = msk + v * HW_;
    float msample = wt[0]*mb[offp[0]] + wt[1]*mb[offp[1]]
                  + wt[2]*mb[offp[2]] + wt[3]*mb[offp[3]];
    float rv0 = 0.f, rv1 = 0.f, rv2 = 0.f;
    {
        const float* ib = img + (v * 3) * HW_;
        #pragma unroll
        for (int t = 0; t < 4; ++t) {
            rv0 += wt[t] * ib[offp[t]];
            rv1 += wt[t] * ib[HW_ + offp[t]];
            rv2 += wt[t] * ib[2 * HW_ + offp[t]];
        }
    }
    float sdx = cam[v*3+0]-px, sdy = cam[v*3+1]-py, sdz = cam[v*3+2]-pz;
    float snv = sqrtf(sdx*sdx + sdy*sdy + sdz*sdz);
    sdx /= snv; sdy /= snv; sdz /= snv;
    float xx[IND_];
    xx[0] = rv0; xx[1] = rv1; xx[2] = rv2;
    #pragma unroll
    for (int k = 0; k < 32; ++k) {
        const float* fb = fea + (size_t)(v * (2*L_) + FS + k) * HW_;
        xx[3+k] = wt[0]*fb[offp[0]] + wt[1]*fb[offp[1]]
                + wt[2]*fb[offp[2]] + wt[3]*fb[offp[3]];
    }
    xx[35] = sdx; xx[36] = sdy; xx[37] = sdz;
    xx[38] = rdx; xx[39] = rdy; xx[40] = rdz;
    float h1[HID_];
    #pragma unroll
    for (int j = 0; j < HID_; ++j) {
        float a0 = 0.f;
        #pragma unroll
        for (int k = 0; k < IND_; ++k) a0 += xx[k] * W1[k * HID_ + j];
        h1[j] = fmaxf(b1[j] + a0, 0.f);
    }
    float lg = bb[0];
    float A = 0.f, B = 0.f, C = 0.f;
    #pragma unroll 1
    for (int j = 0; j < HID_; j += 4) {
        float hh[4];
        #pragma unroll
        for (int jj = 0; jj < 4; ++jj) {
            float a0 = 0.f;
            #pragma unroll
            for (int k = 0; k < HID_; ++k) a0 += h1[k] * W2[k * HID_ + (j + jj)];
            hh[jj] = fmaxf(b2[j + jj] + a0, 0.f);
        }
        #pragma unroll
        for (int jj = 0; jj < 4; ++jj) {
            float h = hh[jj];
            lg += h * Wb[j + jj];
            A  += h * Wd[j + jj];
            B  += h * h * Wd[HID_ + j + jj];
            float sj = vsum8(h);
            C  += sj * sj * Wd[HID_ + j + jj];
        }
    }
    A = vsum8(A); B = vsum8(B);
    float density = A * 0.125f + B * 0.125f - C * (1.0f / 64.0f) + bd[0];
    float hsv = vsum8(msample);
    bool hull = hsv > ((float)V_ - 0.001f);
    float mx = vmax8(lg);
    float e = expf(lg - mx);
    float es = vsum8(e);
    float br  = vsum8(e * rv0);
    float bg  = vsum8(e * rv1);
    float bbl = vsum8(e * rv2);
    if (v == 0) {
        float is = 1.0f / es;
        odens[P]      = hull ? density  : 0.f;
        orgb[P*3 + 0] = hull ? br  * is : 0.f;
        orgb[P*3 + 1] = hull ? bg  * is : 0.f;
        orgb[P*3 + 2] = hull ? bbl * is : 0.f;
    }
}

// -------------- wave-per-ray coarse composite + sample_pdf + merge-path -------
__global__ __launch_bounds__(256) void k_comp_coarse(const float* __restrict__ ray,
                                                     const float* __restrict__ dens,
                                                     const float* __restrict__ rgb,
                                                     float* __restrict__ out,
                                                     float* __restrict__ fulld) {
    __shared__ float cdfS[4][64];
    __shared__ float fdS[4][64];
    const int wv = threadIdx.x >> 6, lane = threadIdx.x & 63;
    const int r = blockIdx.x * 4 + wv;
    const float nv = ray[r*8+6], fv = ray[r*8+7];
    const int s = lane;

    float d0 = nv + (fv - nv) * ((s + 0.5f) / NC_);
    float d1 = nv + (fv - nv) * ((s + 1.5f) / NC_);
    float delta = (s == NC_-1) ? 1e10f : (d1 - d0);
    float a = 1.f - expf(-fmaxf(dens[r*NC_ + s], 0.f) * delta);
    float qv = 1.f - a + 1e-10f;
    float inc = scan_mul64(qv, lane);
    float trans = __shfl_up(inc, 1, 64);
    if (lane == 0) trans = 1.f;
    float w = a * trans;

    float g0 = rgb[(r*NC_+s)*3+0], g1 = rgb[(r*NC_+s)*3+1], g2 = rgb[(r*NC_+s)*3+2];
    float c0 = redsum64(w * g0);
    float c1 = redsum64(w * g1);
    float c2 = redsum64(w * g2);
    float cd = redsum64(w * d0);
    float ca = redsum64(w);
    if (lane == 0) {
        out[r*3+0] = c0; out[r*3+1] = c1; out[r*3+2] = c2;
        out[3072 + r] = cd;
        out[4096 + r] = ca;
    }

    float pw = (s >= 1 && s <= 62) ? (w + 1e-5f) : 0.f;
    float tot = redsum64(pw);
    float p = pw / tot;
    float ic = scan_add64(p, lane);
    cdfS[wv][lane] = ic;
    __syncthreads();

    float u = (lane + 0.5f) / NF_;
    int lo = 0, hi = 63;
    while (lo < hi) {
        int mid = (lo + hi) >> 1;
        if (cdfS[wv][mid] <= u) lo = mid + 1; else hi = mid;
    }
    int below = lo - 1;
    int above = (lo > 62) ? 62 : lo;
    float cA = cdfS[wv][below], cB = cdfS[wv][above];
    float b0 = nv + (fv - nv) * ((below + 1.0f) / NC_);
    float b1 = nv + (fv - nv) * ((above + 1.0f) / NC_);
    float dnm = cB - cA;
    dnm = (dnm < 1e-5f) ? 1.f : dnm;
    float fdv = b0 + (u - cA) / dnm * (b1 - b0);
    fdS[wv][lane] = fdv;
    __syncthreads();

    lo = 0; hi = 64;
    while (lo < hi) {
        int mid = (lo + hi) >> 1;
        if (fdS[wv][mid] < d0) lo = mid + 1; else hi = mid;
    }
    fulld[r*128 + s + lo] = d0;

    lo = 0; hi = 64;
    while (lo < hi) {
        int mid = (lo + hi) >> 1;
        float daj = nv + (fv - nv) * ((mid + 0.5f) / NC_);
        if (daj <= fdv) lo = mid + 1; else hi = mid;
    }
    fulld[r*128 + lane + lo] = fdv;
}

// ------------------------- wave-per-ray fine composite (2 samples/lane) -------
__global__ __launch_bounds__(256) void k_comp_fine(const float* __restrict__ fulld,
                                                   const float* __restrict__ dens,
                                                   const float* __restrict__ rgb,
                                                   float* __restrict__ out) {
    const int wv = threadIdx.x >> 6, lane = threadIdx.x & 63;
    const int r = blockIdx.x * 4 + wv;
    const int S = NC_ + NF_;
    const float* fl = fulld + r * S;
    const int s0 = 2 * lane, s1 = 2 * lane + 1;

    float f0 = fl[s0], f1 = fl[s1];
    float nx = __shfl_down(f0, 1, 64);
    float dl0 = f1 - f0;
    float dl1 = (lane == 63) ? 1e10f : (nx - f1);
    float a0 = 1.f - expf(-fmaxf(dens[r*S + s0], 0.f) * dl0);
    float a1 = 1.f - expf(-fmaxf(dens[r*S + s1], 0.f) * dl1);
    float q0 = 1.f - a0 + 1e-10f, q1 = 1.f - a1 + 1e-10f;
    float inc = scan_mul64(q0 * q1, lane);
    float E = __shfl_up(inc, 1, 64);
    if (lane == 0) E = 1.f;
    float w0 = a0 * E, w1 = a1 * (E * q0);

    float g00 = rgb[(r*S+s0)*3+0], g01 = rgb[(r*S+s0)*3+1], g02 = rgb[(r*S+s0)*3+2];
    float g10 = rgb[(r*S+s1)*3+0], g11 = rgb[(r*S+s1)*3+1], g12 = rgb[(r*S+s1)*3+2];
    float c0 = redsum64(w0*g00 + w1*g10);
    float c1 = redsum64(w0*g01 + w1*g11);
    float c2 = redsum64(w0*g02 + w1*g12);
    float cd = redsum64(w0*f0 + w1*f1);
    float ca = redsum64(w0 + w1);
    if (lane == 0) {
        out[5120 + r*3+0] = c0; out[5120 + r*3+1] = c1; out[5120 + r*3+2] = c2;
        out[8192 + r] = cd;
        out[9216 + r] = ca;
    }
}

// ------------------------------------------------------------------ launch
extern "C" void kernel_launch(void* const* d_in, const int* in_sizes, int n_in,
                              void* d_out, int out_size, void* d_ws, size_t ws_size,
                              hipStream_t stream) {
    const float* ray = (const float*)d_in[0];
    const float* Kin = (const float*)d_in[1];
    const float* Ein = (const float*)d_in[2];
    const float* cam = (const float*)d_in[3];
    const float* shp = (const float*)d_in[4];
    const float* msk = (const float*)d_in[5];
    const float* img = (const float*)d_in[6];
    const float* fea = (const float*)d_in[7];
    const float* cw[8]; for (int i = 0; i < 8; ++i) cw[i] = (const float*)d_in[8+i];
    const float* fw[8]; for (int i = 0; i < 8; ++i) fw[i] = (const float*)d_in[16+i];

    float* ws    = (float*)d_ws;
    float* Pm    = ws;                        // 96
    unsigned int* FRc = (unsigned int*)(Pm + 96);   // 4096 dwords
    unsigned int* FRf = FRc + 4096;                 // 4096 dwords
    float* cdens = (float*)(FRf + 4096);      // 65536
    float* crgb  = cdens + R_ * NC_;          // 196608
    float* fulld = crgb + R_ * NC_ * 3;       // 131072
    float* fdens = fulld + R_ * (NC_+NF_);    // 131072
    float* frgb  = fdens + R_ * (NC_+NF_);    // 393216
    float* pk    = frgb + R_ * (NC_+NF_) * 3; // V*HW*40 floats (160B fp16 rows)

    size_t base_floats = (size_t)(pk - ws);
    size_t need = (base_floats + (size_t)V_ * HW_ * 40 + 64) * sizeof(float);
    bool packed = (ws_size >= need);

    float* outp  = (float*)d_out;

    if (packed) {
        k_init<<<31, 256, 0, stream>>>(Kin, Ein, Pm,
            cw[0], cw[1], cw[2], cw[3], cw[4], cw[6], FRc,
            fw[0], fw[1], fw[2], fw[3], fw[4], fw[6], FRf);
        k_packB2<<<dim3(W_/64, H_, V_), 256, 0, stream>>>(msk, img, fea, pk);

        k_mlp_mfma<NC_, false, 0><<<R_ * NC_ / 32, 256, 0, stream>>>(
            ray, Pm, cam, shp, pk, FRc, cw[5], cw[7],
            nullptr, cdens, crgb);

        k_comp_coarse<<<R_ / 4, 256, 0, stream>>>(ray, cdens, crgb, outp, fulld);

        k_mlp_mfma<NC_ + NF_, true, 5><<<R_ * (NC_+NF_) / 32, 256, 0, stream>>>(
            ray, Pm, cam, shp, pk, FRf, fw[5], fw[7],
            fulld, fdens, frgb);

        k_comp_fine<<<R_ / 4, 256, 0, stream>>>(fulld, fdens, frgb, outp);
    } else {
        k_init<<<1, 256, 0, stream>>>(Kin, Ein, Pm,
            cw[0], cw[1], cw[2], cw[3], cw[4], cw[6], FRc,
            fw[0], fw[1], fw[2], fw[3], fw[4], fw[6], FRf);
        k_mlp_fb<NC_, 0, false><<<R_ * NC_ * 8 / 256, 256, 0, stream>>>(
            ray, Pm, cam, shp, msk, img, fea,
            cw[0], cw[1], cw[2], cw[3], cw[4], cw[5], cw[6], cw[7],
            nullptr, cdens, crgb);

        k_comp_coarse<<<R_ / 4, 256, 0, stream>>>(ray, cdens, crgb, outp, fulld);

        k_mlp_fb<NC_ + NF_, L_, true><<<R_ * (NC_+NF_) * 8 / 256, 256, 0, stream>>>(
            ray, Pm, cam, shp, msk, img, fea,
            fw[0], fw[1], fw[2], fw[3], fw[4], fw[5], fw[6], fw[7],
            fulld, fdens, frgb);

        k_comp_fine<<<R_ / 4, 256, 0, stream>>>(fulld, fdens, frgb, outp);
    }
}

// Round 16
// 181.782 us; speedup vs baseline: 4.6167x; 1.0261x over previous
//
#include <hip/hip_runtime.h>
#include <hip/hip_bf16.h>
#include <math.h>

#define V_   8
#define H_   256
#define W_   256
#define L_   32
#define HID_ 64
#define NC_  64
#define NF_  64
#define R_   1024
#define IND_ 41
#define HW_  (H_*W_)

typedef _Float16 h2v __attribute__((ext_vector_type(2)));
typedef _Float16 h8v __attribute__((ext_vector_type(8)));
typedef __attribute__((ext_vector_type(16))) float f32x16;

// ---------------- fp16 helpers (RNE converts) ----------------
__device__ __forceinline__ unsigned int pk2hf(float a, float b) {
    h2v t; t[0] = (_Float16)a; t[1] = (_Float16)b;
    return __builtin_bit_cast(unsigned int, t);
}

// ---- cross-lane helpers ----
template<int CTRL>
__device__ __forceinline__ float dpp_add(float x) {
    int m = __builtin_amdgcn_mov_dpp(__builtin_bit_cast(int, x), CTRL, 0xF, 0xF, true);
    return x + __builtin_bit_cast(float, m);
}
template<int CTRL>
__device__ __forceinline__ float dpp_max(float x) {
    int m = __builtin_amdgcn_mov_dpp(__builtin_bit_cast(int, x), CTRL, 0xF, 0xF, true);
    return fmaxf(x, __builtin_bit_cast(float, m));
}
__device__ __forceinline__ float swz_xor4(float x) {
    int m = __builtin_amdgcn_ds_swizzle(__builtin_bit_cast(int, x), 0x101F);
    return __builtin_bit_cast(float, m);
}
// all-lanes butterfly sum/max over the 8-lane view group
__device__ __forceinline__ float vsum8(float x) {
    x = dpp_add<0xB1>(x);
    x = dpp_add<0x4E>(x);
    x += swz_xor4(x);
    return x;
}
__device__ __forceinline__ float vmax8(float x) {
    x = dpp_max<0xB1>(x);
    x = dpp_max<0x4E>(x);
    x = fmaxf(x, swz_xor4(x));
    return x;
}
// reduce-to-lane-0-of-each-8-group: 3 pure-VALU DPP hops (row_shl 1/2/4:
// dst[i] = src[i+n], bound_ctrl 0). Valid ONLY on lanes ≡ 0 (mod 8);
// same pairing as the butterfly -> bit-identical there.
__device__ __forceinline__ float rsum8(float x) {
    x = dpp_add<0x101>(x);   // row_shl:1  (lane i += lane i+1)
    x = dpp_add<0x102>(x);   // row_shl:2
    x = dpp_add<0x104>(x);   // row_shl:4
    return x;
}
__device__ __forceinline__ float redsum64(float x) {
    #pragma unroll
    for (int off = 32; off >= 1; off >>= 1) x += __shfl_xor(x, off, 64);
    return x;
}
__device__ __forceinline__ float scan_mul64(float x, int lane) {
    #pragma unroll
    for (int off = 1; off < 64; off <<= 1) {
        float y = __shfl_up(x, off, 64);
        x = (lane >= off) ? x * y : x;
    }
    return x;
}
__device__ __forceinline__ float scan_add64(float x, int lane) {
    #pragma unroll
    for (int off = 1; off < 64; off <<= 1) {
        float y = __shfl_up(x, off, 64);
        x = (lane >= off) ? x + y : x;
    }
    return x;
}

// ---------------- packMFMA body (fragment-order weights, fp16) ----------------
// X layout (48 inputs): x'[0]=mask(zero weight), x'[1..3]=rgb, x'[4..35]=feat,
// x'[36..38]=sd, x'[39..41]=rd, x'[42]=1 (bias row), x'[43..47]=0.
__device__ __forceinline__ void packMFMA_body(
    int t, const float* __restrict__ W1, const float* __restrict__ b1,
    const float* __restrict__ W2, const float* __restrict__ b2,
    const float* __restrict__ Wd, const float* __restrict__ Wb,
    unsigned int* __restrict__ out) {
    if (t < 1536) {
        int blk = t >> 8, idx = t & 255;
        int mt = blk / 3, kt = blk % 3;
        int l = idx >> 2, rg = idx & 3;
        int hi = l >> 5;
        int j  = 32 * mt + (l & 31);
        int k0 = 16 * kt + 8 * hi + 2 * rg;
        int k1 = k0 + 1;
        auto w1v = [&](int k) -> float {
            if (k == 0) return 0.f;
            if (k <= 41) return W1[(k - 1) * 64 + j];
            if (k == 42) return b1[j];
            return 0.f;
        };
        out[t] = pk2hf(w1v(k0), w1v(k1));
    } else if (t < 3584) {
        int u = t - 1536;
        int blk = u >> 8, idx = u & 255;
        int l = idx >> 2, rg = idx & 3;
        int hi = l >> 5;
        int j2 = 32 * (blk >> 2) + (l & 31);
        int k0 = 16 * (blk & 3) + 8 * hi + 2 * rg;
        out[t] = pk2hf(W2[k0 * 64 + j2], W2[(k0 + 1) * 64 + j2]);
    } else if (t < 3840) {
        int i = t - 3584;
        int w = i >> 6, mt = (i >> 5) & 1, hi = (i >> 4) & 1, rg = i & 15;
        int j2 = (rg & 3) + 8 * (rg >> 2) + 4 * hi + 32 * mt;
        float v = (w == 0) ? b2[j2] : (w == 1) ? Wb[j2] : (w == 2) ? Wd[j2] : Wd[64 + j2];
        ((float*)out)[t] = v;
    }
}

// ------------- merged init: P = K@E + coarse/fine weight fragment packs -------
__global__ __launch_bounds__(256) void k_init(
    const float* __restrict__ Km, const float* __restrict__ Em, float* __restrict__ Pm,
    const float* __restrict__ cW1, const float* __restrict__ cb1,
    const float* __restrict__ cW2, const float* __restrict__ cb2,
    const float* __restrict__ cWd, const float* __restrict__ cWb,
    unsigned int* __restrict__ FRc,
    const float* __restrict__ fW1, const float* __restrict__ fb1,
    const float* __restrict__ fW2, const float* __restrict__ fb2,
    const float* __restrict__ fWd, const float* __restrict__ fWb,
    unsigned int* __restrict__ FRf) {
    const int bid = blockIdx.x, tid = threadIdx.x;
    if (bid == 0) {
        if (tid >= V_ * 12) return;
        int v = tid / 12, e = tid - v * 12, row = e >> 2, col = e & 3;
        float acc = 0.f;
        #pragma unroll
        for (int k = 0; k < 3; ++k)
            acc += Km[v * 9 + row * 3 + k] * Em[v * 12 + k * 4 + col];
        Pm[v * 12 + row * 4 + col] = acc;
    } else if (bid <= 15) {
        packMFMA_body((bid - 1) * 256 + tid, cW1, cb1, cW2, cb2, cWd, cWb, FRc);
    } else if (bid <= 30) {
        packMFMA_body((bid - 16) * 256 + tid, fW1, fb1, fW2, fb2, fWd, fWb, FRf);
    }
}

// ------ pack BOTH passes: 160B rows [m,rgb,f0..31 | m,rgb,f32..63] fp16 -------
__global__ __launch_bounds__(256) void k_packB2(const float* __restrict__ msk,
                                                const float* __restrict__ img,
                                                const float* __restrict__ fea,
                                                float* __restrict__ pk) {
    __shared__ unsigned short tile[64][80];
    const int xb = blockIdx.x * 64, y = blockIdx.y, v = blockIdx.z;
    const int t = threadIdx.x;
    const int x = t & 63, cg = t >> 6;
    const size_t px = (size_t)y * W_ + xb + x;
    #pragma unroll
    for (int step = 0; step < 17; ++step) {
        int ch = step * 4 + cg;               // 0..67
        if (ch < 68) {
            float val;
            if (ch == 0)      val = msk[(size_t)v * HW_ + px];
            else if (ch < 4)  val = img[((size_t)(v * 3 + (ch - 1))) * HW_ + px];
            else              val = fea[((size_t)(v * 2 * L_ + (ch - 4))) * HW_ + px];
            unsigned short bf = __builtin_bit_cast(unsigned short, (_Float16)val);
            if (ch == 0)      { tile[x][0] = bf; tile[x][40] = bf; }
            else if (ch < 4)  { tile[x][ch] = bf; tile[x][40 + ch] = bf; }
            else if (ch < 36) { tile[x][ch] = bf; }
            else              { tile[x][ch + 8] = bf; }   // f32..63 -> 44..75
        }
    }
    if (t < 256) {
        int xi = t >> 2, c = t & 3;
        tile[xi][36 + c] = 0;
        tile[xi][76 + c] = 0;
    }
    __syncthreads();
    uint2* dst = (uint2*)(pk + ((size_t)v * HW_ + (size_t)y * W_ + xb) * 40);
    for (int j = t; j < 1280; j += 256) {
        int p = j / 20, sl = j % 20;
        dst[j] = *(const uint2*)&tile[p][sl * 4];
    }
}

// ------------------------------------------------------------- MFMA MLP kernel
// Wave = 8 points x 8 views. Gather accumulates bilinear taps in packed fp16
// (v_pk_fma_f16); mask accumulated in fp32. Writer-only reductions use the
// 3-DPP row_shl rsum8 (to lane 0 of each 8-group); all-lane reductions keep
// the butterfly.
template <int S, bool FINE, int GOFF>
__global__ __launch_bounds__(256) void k_mlp_mfma(
    const float* __restrict__ ray, const float* __restrict__ Pm,
    const float* __restrict__ cam, const float* __restrict__ shp,
    const float* __restrict__ pk,
    const unsigned int* __restrict__ FR,
    const float* __restrict__ bd, const float* __restrict__ bb,
    const float* __restrict__ deptharr,
    float* __restrict__ odens, float* __restrict__ orgb) {

    __shared__ __align__(16) char smem[40960];
    const int lane = threadIdx.x & 63;
    const int wv   = threadIdx.x >> 6;
    const int hi   = lane >> 5;
    const int l31  = lane & 31;
    char* Xw  = smem + wv * 10240;
    char* H1w = Xw + 6144;

    const int pbase = (blockIdx.x * 4 + wv) * 8;
    const int P0 = pbase + (lane >> 3);
    const int v  = lane & 7;
    const int r  = P0 / S, s = P0 - r * S;

    const float ox = ray[r*8+0], oy = ray[r*8+1], oz = ray[r*8+2];
    const float dx = ray[r*8+3], dy = ray[r*8+4], dz = ray[r*8+5];
    const float nv = ray[r*8+6], fv = ray[r*8+7];

    float depth;
    if (FINE) depth = deptharr[P0];
    else      depth = nv + (fv - nv) * ((s + 0.5f) / (float)S);

    const float px = ox + dx*depth, py = oy + dy*depth, pz = oz + dz*depth;
    const float dn = sqrtf(dx*dx + dy*dy + dz*dz);
    const float rdx = -dx/dn, rdy = -dy/dn, rdz = -dz/dn;

    const float* Pv = Pm + v * 12;
    float q0 = Pv[0]*px + Pv[1]*py + Pv[2]*pz  + Pv[3];
    float q1 = Pv[4]*px + Pv[5]*py + Pv[6]*pz  + Pv[7];
    float q2 = Pv[8]*px + Pv[9]*py + Pv[10]*pz + Pv[11];
    float inv = 1.0f / (q2 + 1e-6f);
    float uu = q0 * inv, ww = q1 * inv;
    float gx = 2.0f * (uu / shp[v*2+1]) - 1.0f;
    float gy = 2.0f * (ww / shp[v*2+0]) - 1.0f;
    float sx = (gx + 1.0f) * ((float)W_ * 0.5f) - 0.5f;
    float sy = (gy + 1.0f) * ((float)H_ * 0.5f) - 0.5f;
    float x0f = floorf(sx), y0f = floorf(sy);
    float fx = sx - x0f, fy = sy - y0f;

    int offp[4]; float wt[4];
    {
        float xs[2] = {x0f, x0f + 1.f}, ys[2] = {y0f, y0f + 1.f};
        float wxs[2] = {1.f - fx, fx},  wys[2] = {1.f - fy, fy};
        #pragma unroll
        for (int t = 0; t < 4; ++t) {
            float xf = xs[t & 1], yf = ys[t >> 1];
            bool val = (xf >= 0.f) && (xf <= (float)(W_-1)) &&
                       (yf >= 0.f) && (yf <= (float)(H_-1));
            int xi = (int)fminf(fmaxf(xf, 0.f), (float)(W_-1));
            int yi = (int)fminf(fmaxf(yf, 0.f), (float)(H_-1));
            offp[t] = yi * W_ + xi;
            wt[t] = wxs[t & 1] * wys[t >> 1] * (val ? 1.f : 0.f);
        }
    }

    // ---- gather: 4 taps x 5 uint4; bilinear in packed fp16; mask in fp32 ----
    h2v vals[18];
    #pragma unroll
    for (int i = 0; i < 18; ++i) vals[i] = (h2v){(_Float16)0.f, (_Float16)0.f};
    float msample = 0.f;
    #pragma unroll
    for (int t = 0; t < 4; ++t) {
        const uint4* fp = (const uint4*)pk + ((size_t)v * HW_ + offp[t]) * 10 + GOFF;
        float wf = wt[t];
        _Float16 wh = (_Float16)wf;
        h2v w2 = (h2v){wh, wh};
        #pragma unroll
        for (int s5 = 0; s5 < 5; ++s5) {
            uint4 q = fp[s5];
            unsigned int dw[4] = {q.x, q.y, q.z, q.w};
            if (s5 == 0) {
                h2v m2 = __builtin_bit_cast(h2v, dw[0]);
                msample += wf * (float)m2[0];      // fp32 mask accumulate
            }
            #pragma unroll
            for (int e = 0; e < 4; ++e) {
                int i = s5 * 4 + e;
                if (i < 18) vals[i] += w2 * __builtin_bit_cast(h2v, dw[e]);
            }
        }
    }
    float rv0 = (float)vals[0][1], rv1 = (float)vals[1][0], rv2 = (float)vals[1][1];
    float sdx = cam[v*3+0]-px, sdy = cam[v*3+1]-py, sdz = cam[v*3+2]-pz;
    float snv = sqrtf(sdx*sdx + sdy*sdy + sdz*sdz);
    sdx /= snv; sdy /= snv; sdz /= snv;

    // ---- write X row: dwords 0..17 = vals, 18..21 = sd/rd/bias, 22..23 = 0 ----
    {
        unsigned int d[24];
        #pragma unroll
        for (int i = 0; i < 18; ++i) d[i] = __builtin_bit_cast(unsigned int, vals[i]);
        d[18] = pk2hf(sdx, sdy);
        d[19] = pk2hf(sdz, rdx);
        d[20] = pk2hf(rdy, rdz);
        d[21] = pk2hf(1.0f, 0.f);
        d[22] = 0u; d[23] = 0u;
        #pragma unroll
        for (int o = 0; o < 6; ++o)
            *(uint4*)(Xw + o * 1024 + lane * 16) =
                make_uint4(d[o*4], d[o*4+1], d[o*4+2], d[o*4+3]);
    }

    // ---- preload layer-1 weight A-frags (layer-2 loaded lazily per nt) ----
    h8v aw1[6];
    #pragma unroll
    for (int i = 0; i < 6; ++i)
        aw1[i] = __builtin_bit_cast(h8v, ((const uint4*)FR)[i * 64 + lane]);
    const float4* PL4 = (const float4*)(FR + 3584);
    const float bdv = bd[0], bbv = bb[0];

    float hs = rsum8(msample);            // valid on lanes ≡0 mod 8
    float hssw  = __shfl_xor(hs, 32, 64);
    float rv0sw = __shfl_xor(rv0, 32, 64);
    float rv1sw = __shfl_xor(rv1, 32, 64);
    float rv2sw = __shfl_xor(rv2, 32, 64);

    #pragma unroll
    for (int nt = 0; nt < 2; ++nt) {
        const int n = nt * 32 + l31;
        // ---- layer 1: H1^T = W1T @ X^T ----
        f32x16 acc1[2];
        #pragma unroll
        for (int mt = 0; mt < 2; ++mt)
            #pragma unroll
            for (int q = 0; q < 16; ++q) acc1[mt][q] = 0.f;
        #pragma unroll
        for (int kt = 0; kt < 3; ++kt) {
            uint4 bu = *(const uint4*)(Xw + (2*kt + hi) * 1024 + n * 16);
            h8v b = __builtin_bit_cast(h8v, bu);
            acc1[0] = __builtin_amdgcn_mfma_f32_32x32x16_f16(aw1[kt],     b, acc1[0], 0, 0, 0);
            acc1[1] = __builtin_amdgcn_mfma_f32_32x32x16_f16(aw1[3 + kt], b, acc1[1], 0, 0, 0);
        }
        #pragma unroll
        for (int mt = 0; mt < 2; ++mt)
            #pragma unroll
            for (int q = 0; q < 4; ++q) {
                unsigned int w0 = pk2hf(fmaxf(acc1[mt][4*q+0], 0.f),
                                        fmaxf(acc1[mt][4*q+1], 0.f));
                unsigned int w1 = pk2hf(fmaxf(acc1[mt][4*q+2], 0.f),
                                        fmaxf(acc1[mt][4*q+3], 0.f));
                *(uint2*)(H1w + (q + 4*mt) * 512 + l31 * 16 + hi * 8) = make_uint2(w0, w1);
            }
        // ---- layer 2 (lazy A-frag load; bias via C-init) ----
        h8v aw2[8];
        #pragma unroll
        for (int i = 0; i < 8; ++i)
            aw2[i] = __builtin_bit_cast(h8v, ((const uint4*)(FR + 1536))[i * 64 + lane]);
        f32x16 acc2[2];
        #pragma unroll
        for (int mt = 0; mt < 2; ++mt)
            #pragma unroll
            for (int q4 = 0; q4 < 4; ++q4) {
                float4 c = PL4[(mt*2 + hi)*4 + q4];
                acc2[mt][4*q4+0] = c.x; acc2[mt][4*q4+1] = c.y;
                acc2[mt][4*q4+2] = c.z; acc2[mt][4*q4+3] = c.w;
            }
        #pragma unroll
        for (int kt = 0; kt < 4; ++kt) {
            uint4 bu = *(const uint4*)(H1w + (2*kt + hi) * 512 + l31 * 16);
            h8v b = __builtin_bit_cast(h8v, bu);
            acc2[0] = __builtin_amdgcn_mfma_f32_32x32x16_f16(aw2[kt],     b, acc2[0], 0, 0, 0);
            acc2[1] = __builtin_amdgcn_mfma_f32_32x32x16_f16(aw2[4 + kt], b, acc2[1], 0, 0, 0);
        }

        // ---- pooling (sj / final sums via rsum8: writer lanes only) ----
        float lgp = 0.f, dacc = 0.f, cacc = 0.f;
        #pragma unroll
        for (int mt = 0; mt < 2; ++mt)
            #pragma unroll
            for (int q4 = 0; q4 < 4; ++q4) {
                float4 wb4 = PL4[16 + (mt*2 + hi)*4 + q4];
                float4 wd4 = PL4[32 + (mt*2 + hi)*4 + q4];
                float4 w24 = PL4[48 + (mt*2 + hi)*4 + q4];
                #pragma unroll
                for (int e = 0; e < 4; ++e) {
                    float hv = fmaxf(acc2[mt][4*q4+e], 0.f);
                    float wbv = (e==0)?wb4.x:(e==1)?wb4.y:(e==2)?wb4.z:wb4.w;
                    float wdv = (e==0)?wd4.x:(e==1)?wd4.y:(e==2)?wd4.z:wd4.w;
                    float w2v = (e==0)?w24.x:(e==1)?w24.y:(e==2)?w24.z:w24.w;
                    lgp  += hv * wbv;
                    dacc += hv * wdv + hv * hv * w2v;
                    float sj = rsum8(hv);
                    cacc += sj * sj * w2v;
                }
            }
        float lg = lgp + __shfl_xor(lgp, 32, 64) + bbv;   // per-lane logit (all lanes)
        dacc += __shfl_xor(dacc, 32, 64);
        dacc  = rsum8(dacc);
        cacc += __shfl_xor(cacc, 32, 64);
        float density = dacc * 0.125f - cacc * (1.0f / 64.0f) + bdv;

        float mx = vmax8(lg);                 // all lanes need mx for expf
        float e  = expf(lg - mx);
        float es = rsum8(e);
        float r0c = (hi == nt) ? rv0 : rv0sw;
        float r1c = (hi == nt) ? rv1 : rv1sw;
        float r2c = (hi == nt) ? rv2 : rv2sw;
        float br  = rsum8(e * r0c);
        float bg  = rsum8(e * r1c);
        float bbl = rsum8(e * r2c);
        float hn  = (nt == 0) ? hs : hssw;
        bool hull = hn > ((float)V_ - 0.001f);

        if ((lane & 0x27) == 0) {             // lanes 0,8,16,24 — rsum8-valid
            int PP = pbase + 4 * nt + (lane >> 3);
            float is = 1.0f / es;
            odens[PP]      = hull ? density  : 0.f;
            orgb[PP*3 + 0] = hull ? br  * is : 0.f;
            orgb[PP*3 + 1] = hull ? bg  * is : 0.f;
            orgb[PP*3 + 2] = hull ? bbl * is : 0.f;
        }
    }
}

// ---------------------- fallback (unpacked ws): scalar kernel ----------
template <int S, int FS, bool FINE>
__global__ __launch_bounds__(256, 2) void k_mlp_fb(
    const float* __restrict__ ray, const float* __restrict__ Pm,
    const float* __restrict__ cam, const float* __restrict__ shp,
    const float* __restrict__ msk, const float* __restrict__ img,
    const float* __restrict__ fea,
    const float* __restrict__ W1, const float* __restrict__ b1,
    const float* __restrict__ W2, const float* __restrict__ b2,
    const float* __restrict__ Wd, const float* __restrict__ bd,
    const float* __restrict__ Wb, const float* __restrict__ bb,
    const float* __restrict__ deptharr,
    float* __restrict__ odens, float* __restrict__ orgb) {

    const int tid = blockIdx.x * 256 + threadIdx.x;
    const int v   = tid & 7;
    const int P   = tid >> 3;
    const int r   = P / S, s = P - r * S;

    const float ox = ray[r*8+0], oy = ray[r*8+1], oz = ray[r*8+2];
    const float dx = ray[r*8+3], dy = ray[r*8+4], dz = ray[r*8+5];
    const float nv = ray[r*8+6], fv = ray[r*8+7];
    float depth;
    if (FINE) depth = deptharr[P];
    else      depth = nv + (fv - nv) * ((s + 0.5f) / (float)S);
    const float px = ox + dx*depth, py = oy + dy*depth, pz = oz + dz*depth;
    const float dn = sqrtf(dx*dx + dy*dy + dz*dz);
    const float rdx = -dx/dn, rdy = -dy/dn, rdz = -dz/dn;
    const float* Pv = Pm + v * 12;
    float q0 = Pv[0]*px + Pv[1]*py + Pv[2]*pz  + Pv[3];
    float q1 = Pv[4]*px + Pv[5]*py + Pv[6]*pz  + Pv[7];
    float q2 = Pv[8]*px + Pv[9]*py + Pv[10]*pz + Pv[11];
    float inv = 1.0f / (q2 + 1e-6f);
    float uu = q0 * inv, ww = q1 * inv;
    float gx = 2.0f * (uu / shp[v*2+1]) - 1.0f;
    float gy = 2.0f * (ww / shp[v*2+0]) - 1.0f;
    float sx = (gx + 1.0f) * ((float)W_ * 0.5f) - 0.5f;
    float sy = (gy + 1.0f) * ((float)H_ * 0.5f) - 0.5f;
    float x0f = floorf(sx), y0f = floorf(sy);
    float fx = sx - x0f, fy = sy - y0f;
    int offp[4]; float wt[4];
    {
        float xs[2] = {x0f, x0f + 1.f}, ys[2] = {y0f, y0f + 1.f};
        float wxs[2] = {1.f - fx, fx},  wys[2] = {1.f - fy, fy};
        #pragma unroll
        for (int t = 0; t < 4; ++t) {
            float xf = xs[t & 1], yf = ys[t >> 1];
            bool val = (xf >= 0.f) && (xf <= (float)(W_-1)) &&
                       (yf >= 0.f) && (yf <= (float)(H_-1));
            int xi = (int)fminf(fmaxf(xf, 0.f), (float)(W_-1));
            int yi = (int)fminf(fmaxf(yf, 0.f), (float)(H_-1));
            offp[t] = yi * W_ + xi;
            wt[t] = wxs[t & 1] * wys[t >> 1] * (val ? 1.f : 0.f);
        }
    }
    const float* mb = msk + v * HW_;
    float msample = wt[0]*mb[offp[0]] + wt[1]*mb[offp[1]]
                  + wt[2]*mb[offp[2]] + wt[3]*mb[offp[3]];
    float rv0 = 0.f, rv1 = 0.f, rv2 = 0.f;
    {
        const float* ib = img + (v * 3) * HW_;
        #pragma unroll
        for (int t = 0; t < 4; ++t) {
            rv0 += wt[t] * ib[offp[t]];
            rv1 += wt[t] * ib[HW_ + offp[t]];
            rv2 += wt[t] * ib[2 * HW_ + offp[t]];
        }
    }
    float sdx = cam[v*3+0]-px, sdy = cam[v*3+1]-py, sdz = cam[v*3+2]-pz;
    float snv = sqrtf(sdx*sdx + sdy*sdy + sdz*sdz);
    sdx /= snv; sdy /= snv; sdz /= snv;
    float xx[IND_];
    xx[0] = rv0; xx[1] = rv1; xx[2] = rv2;
    #pragma unroll
    for (int k = 0; k < 32; ++k) {
        const float* fb = fea + (size_t)(v * (2*L_) + FS + k) * HW_;
        xx[3+k] = wt[0]*fb[offp[0]] + wt[1]*fb[offp[1]]
                + wt[2]*fb[offp[2]] + wt[3]*fb[offp[3]];
    }
    xx[35] = sdx; xx[36] = sdy; xx[37] = sdz;
    xx[38] = rdx; xx[39] = rdy; xx[40] = rdz;
    float h1[HID_];
    #pragma unroll
    for (int j = 0; j < HID_; ++j) {
        float a0 = 0.f;
        #pragma unroll
        for (int k = 0; k < IND_; ++k) a0 += xx[k] * W1[k * HID_ + j];
        h1[j] = fmaxf(b1[j] + a0, 0.f);
    }
    float lg = bb[0];
    float A = 0.f, B = 0.f, C = 0.f;
    #pragma unroll 1
    for (int j = 0; j < HID_; j += 4) {
        float hh[4];
        #pragma unroll
        for (int jj = 0; jj < 4; ++jj) {
            float a0 = 0.f;
            #pragma unroll
            for (int k = 0; k < HID_; ++k) a0 += h1[k] * W2[k * HID_ + (j + jj)];
            hh[jj] = fmaxf(b2[j + jj] + a0, 0.f);
        }
        #pragma unroll
        for (int jj = 0; jj < 4; ++jj) {
            float h = hh[jj];
            lg += h * Wb[j + jj];
            A  += h * Wd[j + jj];
            B  += h * h * Wd[HID_ + j + jj];
            float sj = vsum8(h);
            C  += sj * sj * Wd[HID_ + j + jj];
        }
    }
    A = vsum8(A); B = vsum8(B);
    float density = A * 0.125f + B * 0.125f - C * (1.0f / 64.0f) + bd[0];
    float hsv = vsum8(msample);
    bool hull = hsv > ((float)V_ - 0.001f);
    float mx = vmax8(lg);
    float e = expf(lg - mx);
    float es = vsum8(e);
    float br  = vsum8(e * rv0);
    float bg  = vsum8(e * rv1);
    float bbl = vsum8(e * rv2);
    if (v == 0) {
        float is = 1.0f / es;
        odens[P]      = hull ? density  : 0.f;
        orgb[P*3 + 0] = hull ? br  * is : 0.f;
        orgb[P*3 + 1] = hull ? bg  * is : 0.f;
        orgb[P*3 + 2] = hull ? bbl * is : 0.f;
    }
}

// -------------- wave-per-ray coarse composite + sample_pdf + merge-path -------
__global__ __launch_bounds__(256) void k_comp_coarse(const float* __restrict__ ray,
                                                     const float* __restrict__ dens,
                                                     const float* __restrict__ rgb,
                                                     float* __restrict__ out,
                                                     float* __restrict__ fulld) {
    __shared__ float cdfS[4][64];
    __shared__ float fdS[4][64];
    const int wv = threadIdx.x >> 6, lane = threadIdx.x & 63;
    const int r = blockIdx.x * 4 + wv;
    const float nv = ray[r*8+6], fv = ray[r*8+7];
    const int s = lane;

    float d0 = nv + (fv - nv) * ((s + 0.5f) / NC_);
    float d1 = nv + (fv - nv) * ((s + 1.5f) / NC_);
    float delta = (s == NC_-1) ? 1e10f : (d1 - d0);
    float a = 1.f - expf(-fmaxf(dens[r*NC_ + s], 0.f) * delta);
    float qv = 1.f - a + 1e-10f;
    float inc = scan_mul64(qv, lane);
    float trans = __shfl_up(inc, 1, 64);
    if (lane == 0) trans = 1.f;
    float w = a * trans;

    float g0 = rgb[(r*NC_+s)*3+0], g1 = rgb[(r*NC_+s)*3+1], g2 = rgb[(r*NC_+s)*3+2];
    float c0 = redsum64(w * g0);
    float c1 = redsum64(w * g1);
    float c2 = redsum64(w * g2);
    float cd = redsum64(w * d0);
    float ca = redsum64(w);
    if (lane == 0) {
        out[r*3+0] = c0; out[r*3+1] = c1; out[r*3+2] = c2;
        out[3072 + r] = cd;
        out[4096 + r] = ca;
    }

    float pw = (s >= 1 && s <= 62) ? (w + 1e-5f) : 0.f;
    float tot = redsum64(pw);
    float p = pw / tot;
    float ic = scan_add64(p, lane);
    cdfS[wv][lane] = ic;
    __syncthreads();

    float u = (lane + 0.5f) / NF_;
    int lo = 0, hi = 63;
    while (lo < hi) {
        int mid = (lo + hi) >> 1;
        if (cdfS[wv][mid] <= u) lo = mid + 1; else hi = mid;
    }
    int below = lo - 1;
    int above = (lo > 62) ? 62 : lo;
    float cA = cdfS[wv][below], cB = cdfS[wv][above];
    float b0 = nv + (fv - nv) * ((below + 1.0f) / NC_);
    float b1 = nv + (fv - nv) * ((above + 1.0f) / NC_);
    float dnm = cB - cA;
    dnm = (dnm < 1e-5f) ? 1.f : dnm;
    float fdv = b0 + (u - cA) / dnm * (b1 - b0);
    fdS[wv][lane] = fdv;
    __syncthreads();

    lo = 0; hi = 64;
    while (lo < hi) {
        int mid = (lo + hi) >> 1;
        if (fdS[wv][mid] < d0) lo = mid + 1; else hi = mid;
    }
    fulld[r*128 + s + lo] = d0;

    lo = 0; hi = 64;
    while (lo < hi) {
        int mid = (lo + hi) >> 1;
        float daj = nv + (fv - nv) * ((mid + 0.5f) / NC_);
        if (daj <= fdv) lo = mid + 1; else hi = mid;
    }
    fulld[r*128 + lane + lo] = fdv;
}

// ------------------------- wave-per-ray fine composite (2 samples/lane) -------
__global__ __launch_bounds__(256) void k_comp_fine(const float* __restrict__ fulld,
                                                   const float* __restrict__ dens,
                                                   const float* __restrict__ rgb,
                                                   float* __restrict__ out) {
    const int wv = threadIdx.x >> 6, lane = threadIdx.x & 63;
    const int r = blockIdx.x * 4 + wv;
    const int S = NC_ + NF_;
    const float* fl = fulld + r * S;
    const int s0 = 2 * lane, s1 = 2 * lane + 1;

    float f0 = fl[s0], f1 = fl[s1];
    float nx = __shfl_down(f0, 1, 64);
    float dl0 = f1 - f0;
    float dl1 = (lane == 63) ? 1e10f : (nx - f1);
    float a0 = 1.f - expf(-fmaxf(dens[r*S + s0], 0.f) * dl0);
    float a1 = 1.f - expf(-fmaxf(dens[r*S + s1], 0.f) * dl1);
    float q0 = 1.f - a0 + 1e-10f, q1 = 1.f - a1 + 1e-10f;
    float inc = scan_mul64(q0 * q1, lane);
    float E = __shfl_up(inc, 1, 64);
    if (lane == 0) E = 1.f;
    float w0 = a0 * E, w1 = a1 * (E * q0);

    float g00 = rgb[(r*S+s0)*3+0], g01 = rgb[(r*S+s0)*3+1], g02 = rgb[(r*S+s0)*3+2];
    float g10 = rgb[(r*S+s1)*3+0], g11 = rgb[(r*S+s1)*3+1], g12 = rgb[(r*S+s1)*3+2];
    float c0 = redsum64(w0*g00 + w1*g10);
    float c1 = redsum64(w0*g01 + w1*g11);
    float c2 = redsum64(w0*g02 + w1*g12);
    float cd = redsum64(w0*f0 + w1*f1);
    float ca = redsum64(w0 + w1);
    if (lane == 0) {
        out[5120 + r*3+0] = c0; out[5120 + r*3+1] = c1; out[5120 + r*3+2] = c2;
        out[8192 + r] = cd;
        out[9216 + r] = ca;
    }
}

// ------------------------------------------------------------------ launch
extern "C" void kernel_launch(void* const* d_in, const int* in_sizes, int n_in,
                              void* d_out, int out_size, void* d_ws, size_t ws_size,
                              hipStream_t stream) {
    const float* ray = (const float*)d_in[0];
    const float* Kin = (const float*)d_in[1];
    const float* Ein = (const float*)d_in[2];
    const float* cam = (const float*)d_in[3];
    const float* shp = (const float*)d_in[4];
    const float* msk = (const float*)d_in[5];
    const float* img = (const float*)d_in[6];
    const float* fea = (const float*)d_in[7];
    const float* cw[8]; for (int i = 0; i < 8; ++i) cw[i] = (const float*)d_in[8+i];
    const float* fw[8]; for (int i = 0; i < 8; ++i) fw[i] = (const float*)d_in[16+i];

    float* ws    = (float*)d_ws;
    float* Pm    = ws;                        // 96
    unsigned int* FRc = (unsigned int*)(Pm + 96);   // 4096 dwords
    unsigned int* FRf = FRc + 4096;                 // 4096 dwords
    float* cdens = (float*)(FRf + 4096);      // 65536
    float* crgb  = cdens + R_ * NC_;          // 196608
    float* fulld = crgb + R_ * NC_ * 3;       // 131072
    float* fdens = fulld + R_ * (NC_+NF_);    // 131072
    float* frgb  = fdens + R_ * (NC_+NF_);    // 393216
    float* pk    = frgb + R_ * (NC_+NF_) * 3; // V*HW*40 floats (160B fp16 rows)

    size_t base_floats = (size_t)(pk - ws);
    size_t need = (base_floats + (size_t)V_ * HW_ * 40 + 64) * sizeof(float);
    bool packed = (ws_size >= need);

    float* outp  = (float*)d_out;

    if (packed) {
        k_init<<<31, 256, 0, stream>>>(Kin, Ein, Pm,
            cw[0], cw[1], cw[2], cw[3], cw[4], cw[6], FRc,
            fw[0], fw[1], fw[2], fw[3], fw[4], fw[6], FRf);
        k_packB2<<<dim3(W_/64, H_, V_), 256, 0, stream>>>(msk, img, fea, pk);

        k_mlp_mfma<NC_, false, 0><<<R_ * NC_ / 32, 256, 0, stream>>>(
            ray, Pm, cam, shp, pk, FRc, cw[5], cw[7],
            nullptr, cdens, crgb);

        k_comp_coarse<<<R_ / 4, 256, 0, stream>>>(ray, cdens, crgb, outp, fulld);

        k_mlp_mfma<NC_ + NF_, true, 5><<<R_ * (NC_+NF_) / 32, 256, 0, stream>>>(
            ray, Pm, cam, shp, pk, FRf, fw[5], fw[7],
            fulld, fdens, frgb);

        k_comp_fine<<<R_ / 4, 256, 0, stream>>>(fulld, fdens, frgb, outp);
    } else {
        k_init<<<1, 256, 0, stream>>>(Kin, Ein, Pm,
            cw[0], cw[1], cw[2], cw[3], cw[4], cw[6], FRc,
            fw[0], fw[1], fw[2], fw[3], fw[4], fw[6], FRf);
        k_mlp_fb<NC_, 0, false><<<R_ * NC_ * 8 / 256, 256, 0, stream>>>(
            ray, Pm, cam, shp, msk, img, fea,
            cw[0], cw[1], cw[2], cw[3], cw[4], cw[5], cw[6], cw[7],
            nullptr, cdens, crgb);

        k_comp_coarse<<<R_ / 4, 256, 0, stream>>>(ray, cdens, crgb, outp, fulld);

        k_mlp_fb<NC_ + NF_, L_, true><<<R_ * (NC_+NF_) * 8 / 256, 256, 0, stream>>>(
            ray, Pm, cam, shp, msk, img, fea,
            fw[0], fw[1], fw[2], fw[3], fw[4], fw[5], fw[6], fw[7],
            fulld, fdens, frgb);

        k_comp_fine<<<R_ / 4, 256, 0, stream>>>(fulld, fdens, frgb, outp);
    }
}